// Round 10
// baseline (1031.868 us; speedup 1.0000x reference)
//
#include <hip/hip_runtime.h>
#include <hip/hip_bf16.h>
#include <math.h>

// Problem constants (fixed by setup_inputs)
#define BB 2
#define TT 1024
#define DD 2048
#define HH 16
#define DK 128
#define DV 128
#define NG 8
#define GG 16
#define SCALE_Q 0.08838834764831845f  // 128^-0.5

typedef __attribute__((ext_vector_type(8))) short bf16x8;
typedef __attribute__((ext_vector_type(4))) float f32x4;

// bf16 split helpers (RNE)
__device__ __forceinline__ unsigned short f2bf(float v) {
    unsigned u = __float_as_uint(v);
    return (unsigned short)((u + 0x7FFFu + ((u >> 16) & 1u)) >> 16);
}
__device__ __forceinline__ float bf2f(unsigned short h) {
    return __uint_as_float(((unsigned)h) << 16);
}
__device__ __forceinline__ void bsplit(float v, unsigned short& h, unsigned short& l) {
    h = f2bf(v);
    l = f2bf(v - bf2f(h));
}

// ---------------------------------------------------------------------------
// DPP sums. sum64: full-wave (lane63 holds sum). sum32: per-32-half
// (lane31 holds sum of lanes 0-31, lane63 holds sum of lanes 32-63).
// ---------------------------------------------------------------------------
__device__ __forceinline__ float dpp_sum64(float x) {
    x += __int_as_float(__builtin_amdgcn_update_dpp(0, __float_as_int(x), 0x111, 0xf, 0xf, true));  // row_shr:1
    x += __int_as_float(__builtin_amdgcn_update_dpp(0, __float_as_int(x), 0x112, 0xf, 0xf, true));  // row_shr:2
    x += __int_as_float(__builtin_amdgcn_update_dpp(0, __float_as_int(x), 0x114, 0xf, 0xf, true));  // row_shr:4
    x += __int_as_float(__builtin_amdgcn_update_dpp(0, __float_as_int(x), 0x118, 0xf, 0xf, true));  // row_shr:8
    x += __int_as_float(__builtin_amdgcn_update_dpp(0, __float_as_int(x), 0x142, 0xa, 0xf, false)); // row_bcast:15
    x += __int_as_float(__builtin_amdgcn_update_dpp(0, __float_as_int(x), 0x143, 0xc, 0xf, false)); // row_bcast:31
    return x;
}
__device__ __forceinline__ float dpp_sum32(float x) {
    x += __int_as_float(__builtin_amdgcn_update_dpp(0, __float_as_int(x), 0x111, 0xf, 0xf, true));  // row_shr:1
    x += __int_as_float(__builtin_amdgcn_update_dpp(0, __float_as_int(x), 0x112, 0xf, 0xf, true));  // row_shr:2
    x += __int_as_float(__builtin_amdgcn_update_dpp(0, __float_as_int(x), 0x114, 0xf, 0xf, true));  // row_shr:4
    x += __int_as_float(__builtin_amdgcn_update_dpp(0, __float_as_int(x), 0x118, 0xf, 0xf, true));  // row_shr:8
    x += __int_as_float(__builtin_amdgcn_update_dpp(0, __float_as_int(x), 0x142, 0xa, 0xf, false)); // row_bcast:15
    return x;
}
__device__ __forceinline__ float readlanef(float x, int l) {
    return __int_as_float(__builtin_amdgcn_readlane(__float_as_int(x), l));
}
__device__ __forceinline__ float f4get(const float4 f, int c) {
    return c == 0 ? f.x : c == 1 ? f.y : c == 2 ? f.z : f.w;
}

// ---------------------------------------------------------------------------
// split: fp32 [n] -> bf16 hi/lo
// ---------------------------------------------------------------------------
__global__ void split_mat(const float* __restrict__ in, unsigned short* __restrict__ oh,
                          unsigned short* __restrict__ ol) {
    const int i0 = (blockIdx.x * 256 + threadIdx.x) * 16;
#pragma unroll
    for (int r = 0; r < 4; ++r) {
        const float4 v = *(const float4*)(in + i0 + r * 4);
        unsigned short h0, l0, h1, l1, h2, l2, h3, l3;
        bsplit(v.x, h0, l0); bsplit(v.y, h1, l1);
        bsplit(v.z, h2, l2); bsplit(v.w, h3, l3);
        short4 hh; hh.x = (short)h0; hh.y = (short)h1; hh.z = (short)h2; hh.w = (short)h3;
        short4 ll; ll.x = (short)l0; ll.y = (short)l1; ll.z = (short)l2; ll.w = (short)l3;
        *(short4*)(oh + i0 + r * 4) = hh;
        *(short4*)(ol + i0 + r * 4) = ll;
    }
}

// ---------------------------------------------------------------------------
// transpose + split: in fp32 [Kin][Nin] -> out bf16 hi/lo [Nin][Kin]
// ---------------------------------------------------------------------------
__global__ void transpose_split(const float* __restrict__ in, unsigned short* __restrict__ oh,
                                unsigned short* __restrict__ ol, int Nin, int Kin) {
    __shared__ float t[64][65];
    const int bx = blockIdx.x, by = blockIdx.y;
    const int tid = threadIdx.x;
    const int c4 = (tid & 15) * 4, r0 = tid >> 4;
#pragma unroll
    for (int rep = 0; rep < 4; ++rep) {
        const int r = r0 + rep * 16;
        const float4 v = *(const float4*)(in + (size_t)(by * 64 + r) * Nin + bx * 64 + c4);
        t[r][c4] = v.x; t[r][c4 + 1] = v.y; t[r][c4 + 2] = v.z; t[r][c4 + 3] = v.w;
    }
    __syncthreads();
#pragma unroll
    for (int rep = 0; rep < 4; ++rep) {
        const int n = r0 + rep * 16;
        short4 hh, ll;
        unsigned short h, l;
        bsplit(t[c4 + 0][n], h, l); hh.x = (short)h; ll.x = (short)l;
        bsplit(t[c4 + 1][n], h, l); hh.y = (short)h; ll.y = (short)l;
        bsplit(t[c4 + 2][n], h, l); hh.z = (short)h; ll.z = (short)l;
        bsplit(t[c4 + 3][n], h, l); hh.w = (short)h; ll.w = (short)l;
        const size_t o = (size_t)(bx * 64 + n) * Kin + by * 64 + c4;
        *(short4*)(oh + o) = hh;
        *(short4*)(ol + o) = ll;
    }
}

// ---------------------------------------------------------------------------
// t-tile transpose: in [B][1024][2048] -> out tiled [bh][tblk][cl][8]
// ---------------------------------------------------------------------------
__global__ void transpose_tile(const float* __restrict__ in, float* __restrict__ out) {
    __shared__ float tl[8][128];
    const int blk = blockIdx.x;
    const int bh = blk >> 7, tblk = blk & 127;
    const int b = bh >> 4, h = bh & 15;
    const int tid = threadIdx.x;

    const int tt = tid >> 5, c4 = (tid & 31) * 4;
    const float4 v = *(const float4*)(in + ((size_t)(b * 1024 + tblk * 8 + tt)) * 2048 + h * 128 + c4);
    tl[tt][c4] = v.x; tl[tt][c4 + 1] = v.y; tl[tt][c4 + 2] = v.z; tl[tt][c4 + 3] = v.w;
    __syncthreads();

    const int cl = tid >> 1, tj0 = (tid & 1) * 4;
    float4 w4;
    w4.x = tl[tj0 + 0][cl]; w4.y = tl[tj0 + 1][cl];
    w4.z = tl[tj0 + 2][cl]; w4.w = tl[tj0 + 3][cl];
    *(float4*)(out + ((size_t)blk * 128 + cl) * 8 + tj0) = w4;
}

// ---------------------------------------------------------------------------
// Split-precision bf16 MFMA GEMM (verified round 4).
// ---------------------------------------------------------------------------
struct GemmArgs {
    const unsigned short* Ah; const unsigned short* Al;
    const unsigned short* Bh[5]; const unsigned short* Bl[5];
    float* C[5];
};

#define AHI 0
#define ALO 8192
#define BHI 16384
#define BLO 24576

#define GL2LDS(g, s) __builtin_amdgcn_global_load_lds( \
    (const __attribute__((address_space(1))) void*)(g), \
    (__attribute__((address_space(3))) void*)(s), 16, 0, 0)

__launch_bounds__(256, 2)
__global__ void gemm_split(GemmArgs p, int fused) {
    __shared__ __attribute__((aligned(16))) char lds[32768];
    const int tid = threadIdx.x;
    const int bx = blockIdx.x, by = blockIdx.y;

    int sel, nloc, ldc;
    if (fused) {
        if (bx < 64) { sel = bx >> 4; nloc = (bx & 15) * 128; ldc = 2048; }
        else         { sel = 4;       nloc = 0;               ldc = 128;  }
    } else { sel = 0; nloc = bx * 128; ldc = 2048; }

    const unsigned short* Asrc_h = p.Ah + (size_t)(by * 128) * 2048;
    const unsigned short* Asrc_l = p.Al + (size_t)(by * 128) * 2048;
    const unsigned short* Bsrc_h = p.Bh[sel] + (size_t)nloc * 2048;
    const unsigned short* Bsrc_l = p.Bl[sel] + (size_t)nloc * 2048;

    const int r0 = tid >> 2, ps0 = tid & 3;
    const int r1 = (tid + 256) >> 2, ps1 = tid & 3;
    const size_t ga0 = (size_t)r0 * 2048 + (size_t)((ps0 ^ ((r0 >> 1) & 3)) * 8);
    const size_t ga1 = (size_t)r1 * 2048 + (size_t)((ps1 ^ ((r1 >> 1) & 3)) * 8);
    const int lb0 = (tid & 192) * 16;
    const int lb1 = (256 + (tid & 192)) * 16;

    const int lane = tid & 63;
    const int l15 = lane & 15, kgrp = lane >> 4;
    const int w = tid >> 6, wm = w >> 1, wn = w & 1;
    const int swz = kgrp ^ ((l15 >> 1) & 3);
    const int fro = l15 * 64 + swz * 16;
    const int aoff = wm * 4096, boff = wn * 4096;

    f32x4 acc[4][4];
#pragma unroll
    for (int i = 0; i < 4; ++i)
#pragma unroll
        for (int j = 0; j < 4; ++j) acc[i][j] = (f32x4){0.f, 0.f, 0.f, 0.f};

    for (int k0 = 0; k0 < 2048; k0 += 32) {
        __syncthreads();
        GL2LDS(Asrc_h + k0 + ga0, lds + AHI + lb0);
        GL2LDS(Asrc_h + k0 + ga1, lds + AHI + lb1);
        GL2LDS(Asrc_l + k0 + ga0, lds + ALO + lb0);
        GL2LDS(Asrc_l + k0 + ga1, lds + ALO + lb1);
        GL2LDS(Bsrc_h + k0 + ga0, lds + BHI + lb0);
        GL2LDS(Bsrc_h + k0 + ga1, lds + BHI + lb1);
        GL2LDS(Bsrc_l + k0 + ga0, lds + BLO + lb0);
        GL2LDS(Bsrc_l + k0 + ga1, lds + BLO + lb1);
        __syncthreads();

        bf16x8 ah[4], al4[4], bh4[4], bl4[4];
#pragma unroll
        for (int f = 0; f < 4; ++f) {
            ah[f]  = *(const bf16x8*)(lds + AHI + aoff + f * 1024 + fro);
            al4[f] = *(const bf16x8*)(lds + ALO + aoff + f * 1024 + fro);
            bh4[f] = *(const bf16x8*)(lds + BHI + boff + f * 1024 + fro);
            bl4[f] = *(const bf16x8*)(lds + BLO + boff + f * 1024 + fro);
        }
#pragma unroll
        for (int i = 0; i < 4; ++i)
#pragma unroll
            for (int j = 0; j < 4; ++j) {
                acc[i][j] = __builtin_amdgcn_mfma_f32_16x16x32_bf16(ah[i],  bh4[j], acc[i][j], 0, 0, 0);
                acc[i][j] = __builtin_amdgcn_mfma_f32_16x16x32_bf16(ah[i],  bl4[j], acc[i][j], 0, 0, 0);
                acc[i][j] = __builtin_amdgcn_mfma_f32_16x16x32_bf16(al4[i], bh4[j], acc[i][j], 0, 0, 0);
            }
    }

    float* cb = p.C[sel];
    const int m0 = by * 128 + wm * 64 + kgrp * 4;
    const int n0 = nloc + wn * 64 + l15;
#pragma unroll
    for (int i = 0; i < 4; ++i)
#pragma unroll
        for (int t = 0; t < 4; ++t) {
            float* cp = cb + (size_t)(m0 + i * 16 + t) * ldc + n0;
#pragma unroll
            for (int j = 0; j < 4; ++j) cp[j * 16] = acc[i][j][t];
        }
}

// ---------------------------------------------------------------------------
// Generic fp32 SGEMM (kept for g1@Wf2 and as full fallback path).
// ---------------------------------------------------------------------------
#define GBM 128
#define GBN 128
#define GBK 16

__launch_bounds__(256)
__global__ void sgemm128(const float* __restrict__ A, const float* __restrict__ B,
                         float* __restrict__ C, int M, int N, int K) {
    __shared__ float As[GBK][GBM + 4];
    __shared__ float Bs[GBK][GBN + 4];

    const int tid = threadIdx.x;
    const int bm = blockIdx.y * GBM;
    const int bn = blockIdx.x * GBN;

    const int arow = tid >> 2;
    const int acol = (tid & 3) << 2;
    const int brow = tid >> 5;
    const int bcol = (tid & 31) << 2;
    const int ty = tid >> 4;
    const int tx = tid & 15;

    float acc[8][8];
#pragma unroll
    for (int i = 0; i < 8; ++i)
#pragma unroll
        for (int j = 0; j < 8; ++j) acc[i][j] = 0.f;

    for (int k0 = 0; k0 < K; k0 += GBK) {
#pragma unroll
        for (int r = 0; r < 2; ++r) {
            const int m = arow + r * 64;
            const float4 av = *(const float4*)(A + (size_t)(bm + m) * K + k0 + acol);
            As[acol + 0][m] = av.x;
            As[acol + 1][m] = av.y;
            As[acol + 2][m] = av.z;
            As[acol + 3][m] = av.w;
        }
#pragma unroll
        for (int r = 0; r < 2; ++r) {
            const int kk = brow + r * 8;
            *(float4*)(&Bs[kk][bcol]) =
                *(const float4*)(B + (size_t)(k0 + kk) * N + bn + bcol);
        }
        __syncthreads();

#pragma unroll
        for (int kk = 0; kk < GBK; ++kk) {
            float a[8], bf[8];
#pragma unroll
            for (int i = 0; i < 8; ++i) a[i] = As[kk][ty * 8 + i];
#pragma unroll
            for (int j = 0; j < 8; ++j) bf[j] = Bs[kk][tx * 8 + j];
#pragma unroll
            for (int i = 0; i < 8; ++i)
#pragma unroll
                for (int j = 0; j < 8; ++j)
                    acc[i][j] = fmaf(a[i], bf[j], acc[i][j]);
        }
        __syncthreads();
    }

#pragma unroll
    for (int i = 0; i < 8; ++i) {
        float* cp = C + (size_t)(bm + ty * 8 + i) * N + bn + tx * 8;
        *(float4*)(cp + 0) = make_float4(acc[i][0], acc[i][1], acc[i][2], acc[i][3]);
        *(float4*)(cp + 4) = make_float4(acc[i][4], acc[i][5], acc[i][6], acc[i][7]);
    }
}

// ---------------------------------------------------------------------------
// Causal depthwise conv1d (K=4) + silu, optional per-head l2norm * scale.
// ---------------------------------------------------------------------------
__global__ void conv_silu_norm(const float* __restrict__ pre, const float* __restrict__ w,
                               float* __restrict__ out, float scale, int do_norm) {
    const int blk = blockIdx.x;
    const int h = blk & 15;
    const int bt = blk >> 4;
    const int t = bt & (TT - 1);
    const int b = bt >> 10;
    const int dk = threadIdx.x;
    const int c = h * 128 + dk;

    const size_t off = ((size_t)(b * TT + t)) * DD + c;
    float acc = 0.f;
#pragma unroll
    for (int j = 0; j < 4; ++j) {
        const int tt = t - 3 + j;
        const float x = (tt >= 0) ? pre[off + (size_t)(j - 3) * DD] : 0.f;
        acc = fmaf(x, w[c * 4 + j], acc);
    }
    float x = acc / (1.f + expf(-acc));  // silu

    if (do_norm) {
        float ss = x * x;
#pragma unroll
        for (int s = 1; s < 64; s <<= 1) ss += __shfl_xor(ss, s, 64);
        __shared__ float red[2];
        if ((threadIdx.x & 63) == 0) red[threadIdx.x >> 6] = ss;
        __syncthreads();
        const float tot = red[0] + red[1];
        x = x * rsqrtf(tot + 1e-6f) * scale;
    }
    out[off] = x;
}

// ---------------------------------------------------------------------------
__global__ void beta_kernel(const float* __restrict__ hid, const float* __restrict__ Wb,
                            float* __restrict__ beta) {
    const int m = blockIdx.x;
    const int t = threadIdx.x;
    const int h = t & 15;
    const int sl = t >> 4;

    const float* hp = hid + (size_t)m * DD + sl * 128;
    const float* wp = Wb + (size_t)sl * 128 * HH + h;
    float p = 0.f;
#pragma unroll 8
    for (int i = 0; i < 128; ++i) p = fmaf(hp[i], wp[i * HH], p);

    __shared__ float red[256];
    red[t] = p;
    __syncthreads();
    if (t < HH) {
        float s = 0.f;
#pragma unroll
        for (int i = 0; i < 16; ++i) s += red[i * 16 + t];
        beta[(size_t)m * HH + t] = 1.f / (1.f + expf(-s));
    }
}

// ---------------------------------------------------------------------------
// decay (fallback layout [b,t,h,g])
// ---------------------------------------------------------------------------
__global__ void decay_kernel(const float* __restrict__ g2, const float* __restrict__ A_log,
                             const float* __restrict__ dt_bias, float* __restrict__ decay) {
    const int idx = blockIdx.x * 256 + threadIdx.x;
    const int g = idx & (NG - 1);
    const int h = (idx >> 3) & (HH - 1);
    const float x = g2[idx] + dt_bias[h * NG + g];
    const float sp = (x > 20.f) ? x : log1pf(expf(x));
    decay[idx] = expf(-expf(A_log[h]) * sp);
}

// ---------------------------------------------------------------------------
// decay, t-tiled output [bh][tblk][g][8]
// ---------------------------------------------------------------------------
__global__ void decay_kernel_t(const float* __restrict__ g2, const float* __restrict__ A_log,
                               const float* __restrict__ dt_bias, float* __restrict__ dtr) {
    const int idx = blockIdx.x * 256 + threadIdx.x;   // (b,t,h,g)
    const int g = idx & 7, h = (idx >> 3) & 15;
    const int t = (idx >> 7) & 1023, b = idx >> 17;
    const float x = g2[idx] + dt_bias[h * NG + g];
    const float sp = (x > 20.f) ? x : log1pf(expf(x));
    const float d = expf(-expf(A_log[h]) * sp);
    const int bh = b * 16 + h, tblk = t >> 3, tj = t & 7;
    dtr[((size_t)(bh * 128 + tblk)) * 64 + g * 8 + tj] = d;
}

// ---------------------------------------------------------------------------
// Gated delta-rule recurrence, t-tiled inputs, split-wave (2 v-cols/wave).
// Lanes 0-31 own column c0, lanes 32-63 own c1. Lane li owns k=4li..4li+3
// (4 S elems) -> its chunk k/q data (4 rows x 8 t) is 128B contiguous.
// err reduction: 5-op DPP tree per 32-half (both columns reduced by the
// SAME instruction stream); err returned via 2 readlane + select; v is
// per-lane loaded for its own column (no broadcast); beta via readlane
// (SGPR operand). 512 blocks x 4 waves; XCD swizzle groups each bh.
// ---------------------------------------------------------------------------
#define CLD2(K, Q, D, V, Bf, T0) do {                                          \
    const float* kpt = kp0 + (size_t)(T0) * 128;                               \
    const float* qpt = qp0 + (size_t)(T0) * 128;                               \
    _Pragma("unroll")                                                          \
    for (int r = 0; r < 8; ++r) K[r] = *(const float4*)(kpt + r * 4);          \
    _Pragma("unroll")                                                          \
    for (int r = 0; r < 8; ++r) Q[r] = *(const float4*)(qpt + r * 4);          \
    D[0] = *(const float4*)(dpg + (size_t)(T0) * 8);                           \
    D[1] = *(const float4*)(dpg + (size_t)(T0) * 8 + 4);                       \
    V[0] = *(const float4*)(vp + (size_t)(T0) * 128);                          \
    V[1] = *(const float4*)(vp + (size_t)(T0) * 128 + 4);                      \
    Bf = bp[(size_t)(T0) * 16];                                                \
} while (0)

#define CSTEP2(K, Q, D, V, Bf, T0) do {                                        \
    _Pragma("unroll")                                                          \
    for (int j = 0; j < 8; ++j) {                                              \
        const float dj = f4get(D[j >> 2], j & 3);                              \
        S0 *= dj; S1 *= dj; S2 *= dj; S3 *= dj;                                \
        const float k0 = f4get(K[0 + (j >> 2)], j & 3);                        \
        const float k1 = f4get(K[2 + (j >> 2)], j & 3);                        \
        const float k2 = f4get(K[4 + (j >> 2)], j & 3);                        \
        const float k3 = f4get(K[6 + (j >> 2)], j & 3);                        \
        float e = fmaf(k0, S0, k1 * S1) + fmaf(k2, S2, k3 * S3);               \
        e = dpp_sum32(e);                                                      \
        const float e0 = readlanef(e, 31);                                     \
        const float e1 = readlanef(e, 63);                                     \
        const float errv = lowhalf ? e0 : e1;                                  \
        const float vj = f4get(V[j >> 2], j & 3);                              \
        const float bj = readlanef(Bf, j);                                     \
        const float delta = (vj - errv) * bj;                                  \
        S0 = fmaf(k0, delta, S0); S1 = fmaf(k1, delta, S1);                    \
        S2 = fmaf(k2, delta, S2); S3 = fmaf(k3, delta, S3);                    \
        const float q0 = f4get(Q[0 + (j >> 2)], j & 3);                        \
        const float q1 = f4get(Q[2 + (j >> 2)], j & 3);                        \
        const float q2 = f4get(Q[4 + (j >> 2)], j & 3);                        \
        const float q3 = f4get(Q[6 + (j >> 2)], j & 3);                        \
        float oo = fmaf(q0, S0, q1 * S1) + fmaf(q2, S2, q3 * S3);              \
        oo = dpp_sum32(oo);                                                    \
        if ((lane & 31) == 31) o[obase + (size_t)((T0) + j) * 2048 + colH] = oo; \
    }                                                                          \
} while (0)

__launch_bounds__(256, 2)
__global__ void recur_kernel_t(const float* __restrict__ qt, const float* __restrict__ kt,
                               const float* __restrict__ vt, const float* __restrict__ dtr,
                               const float* __restrict__ beta, float* __restrict__ o) {
    const int bid = blockIdx.x;            // 512 blocks
    const int xcd = bid & 7, idx = bid >> 3;
    const int bh = xcd * 4 + (idx >> 4);   // 16 blocks of a bh share an XCD
    const int vblk16 = idx & 15;
    const int b = bh >> 4, h = bh & 15;
    const int w = threadIdx.x >> 6;
    const int lane = threadIdx.x & 63;
    const int li = lane & 31;
    const bool lowhalf = lane < 32;
    const int colH = vblk16 * 8 + w * 2 + (lane >> 5);
    const int jl = lane & 7;

    // tiled bases: per-bh block = 128 tblk * 128 c * 8 t = 131072 floats
    const float* kp0 = kt + (size_t)bh * 131072 + (size_t)(4 * li) * 8;
    const float* qp0 = qt + (size_t)bh * 131072 + (size_t)(4 * li) * 8;
    const float* vp  = vt + (size_t)bh * 131072 + (size_t)colH * 8;
    const float* dpg = dtr + (size_t)bh * 8192 + (size_t)(li >> 2) * 8;
    const float* bp  = beta + ((size_t)b * 1024 + jl) * HH + h;
    const size_t obase = ((size_t)b * 1024 * HH + h) * 128;

    float S0 = 0.f, S1 = 0.f, S2 = 0.f, S3 = 0.f;
    float4 Ka[8], Qa[8], Da[2], Va[2], Kb[8], Qb[8], Db[2], Vb[2];
    float Bfa, Bfb;

    CLD2(Ka, Qa, Da, Va, Bfa, 0);

#pragma unroll 1
    for (int t0 = 0; t0 < TT; t0 += 16) {
        CLD2(Kb, Qb, Db, Vb, Bfb, t0 + 8);
        CSTEP2(Ka, Qa, Da, Va, Bfa, t0);
        const int tA = (t0 + 16 < TT) ? (t0 + 16) : t0;  // clamped dummy at end
        CLD2(Ka, Qa, Da, Va, Bfa, tA);
        CSTEP2(Kb, Qb, Db, Vb, Bfb, t0 + 8);
    }
}

// ---------------------------------------------------------------------------
// Old-layout recurrence (fallback path only).
// ---------------------------------------------------------------------------
__launch_bounds__(256, 4)
__global__ void recur_kernel(const float* __restrict__ q, const float* __restrict__ k,
                             const float* __restrict__ vv, const float* __restrict__ decay,
                             const float* __restrict__ beta, float* __restrict__ o) {
    const int blk = blockIdx.x;
    const int vblk = blk & 31;
    const int bh = blk >> 5;
    const int b = bh >> 4, h = bh & 15;
    const int w = threadIdx.x >> 6;
    const int lane = threadIdx.x & 63;
    const int vi = vblk * 4 + w;

    float S0 = 0.f, S1 = 0.f;
    const size_t strideT = (size_t)HH * DV;
    const size_t strideT2 = strideT >> 1;
    const size_t base = ((size_t)b * TT * HH + h) * DV;

    const float2* kp = (const float2*)(k + base) + lane;
    const float2* qp = (const float2*)(q + base) + lane;
    const float* vp = vv + base + vi;
    const float* bp = beta + (size_t)b * TT * HH + h;
    const float* dp = decay + ((size_t)b * TT * HH + h) * NG + (lane >> 3);

    float2 kv = kp[0], qv = qp[0];
    float vtv = vp[0], bt = bp[0], dt = dp[0];

    for (int t = 0; t < TT; ++t) {
        const float2 kc = kv, qc = qv;
        const float vc = vtv, bc = bt, dc = dt;

        const int tn = (t + 1 < TT) ? (t + 1) : t;
        kv = kp[(size_t)tn * strideT2];
        qv = qp[(size_t)tn * strideT2];
        vtv = vp[(size_t)tn * strideT];
        bt = bp[(size_t)tn * HH];
        dt = dp[(size_t)tn * HH * NG];

        S0 *= dc;
        S1 *= dc;
        float e = fmaf(kc.x, S0, kc.y * S1);
        e = dpp_sum64(e);
        const float err = readlanef(e, 63);
        const float delta = bc * (vc - err);
        S0 = fmaf(kc.x, delta, S0);
        S1 = fmaf(kc.y, delta, S1);
        float oo = fmaf(qc.x, S0, qc.y * S1);
        oo = dpp_sum64(oo);
        if (lane == 63) o[base + (size_t)t * strideT + vi] = oo;
    }
}

// ---------------------------------------------------------------------------
// Gated RMSNorm -> fp32 y (fallback path)
// ---------------------------------------------------------------------------
__global__ void gated_rmsnorm(const float* __restrict__ o,
                              const float* __restrict__ gpre, const float* __restrict__ bg,
                              const float* __restrict__ norm_w, float* __restrict__ y) {
    const int blk = blockIdx.x;
    const int h = blk & 15;
    const int dv = threadIdx.x;
    const size_t off = (size_t)blk * DV + dv;

    const float ov = o[off];
    const float g = gpre[off] + bg[h * 128 + dv];
    const float yv = ov * (g / (1.f + expf(-g)));

    float ss = yv * yv;
#pragma unroll
    for (int s = 1; s < 64; s <<= 1) ss += __shfl_xor(ss, s, 64);
    __shared__ float red[2];
    if ((threadIdx.x & 63) == 0) red[threadIdx.x >> 6] = ss;
    __syncthreads();
    const float mean = (red[0] + red[1]) * (1.f / 128.f);
    y[off] = yv * rsqrtf(mean + 1e-5f) * norm_w[dv];
}

// ---------------------------------------------------------------------------
// Gated RMSNorm -> bf16 hi/lo split y
// ---------------------------------------------------------------------------
__global__ void gated_rmsnorm_split(const float* __restrict__ o,
                                    const float* __restrict__ gpre, const float* __restrict__ bg,
                                    const float* __restrict__ norm_w,
                                    unsigned short* __restrict__ yh,
                                    unsigned short* __restrict__ yl) {
    const int blk = blockIdx.x;
    const int h = blk & 15;
    const int dv = threadIdx.x;
    const size_t off = (size_t)blk * DV + dv;

    const float ov = o[off];
    const float g = gpre[off] + bg[h * 128 + dv];
    const float yv = ov * (g / (1.f + expf(-g)));

    float ss = yv * yv;
#pragma unroll
    for (int s = 1; s < 64; s <<= 1) ss += __shfl_xor(ss, s, 64);
    __shared__ float red[2];
    if ((threadIdx.x & 63) == 0) red[threadIdx.x >> 6] = ss;
    __syncthreads();
    const float mean = (red[0] + red[1]) * (1.f / 128.f);
    const float y = yv * rsqrtf(mean + 1e-5f) * norm_w[dv];
    unsigned short hh, ll;
    bsplit(y, hh, ll);
    yh[off] = hh;
    yl[off] = ll;
}

// ---------------------------------------------------------------------------
extern "C" void kernel_launch(void* const* d_in, const int* in_sizes, int n_in,
                              void* d_out, int out_size, void* d_ws, size_t ws_size,
                              hipStream_t stream) {
    const float* hid    = (const float*)d_in[0];
    const float* Wq     = (const float*)d_in[1];
    const float* Wk     = (const float*)d_in[2];
    const float* Wv     = (const float*)d_in[3];
    const float* conv_q = (const float*)d_in[4];
    const float* conv_k = (const float*)d_in[5];
    const float* conv_v = (const float*)d_in[6];
    const float* Wf1    = (const float*)d_in[7];
    const float* Wf2    = (const float*)d_in[8];
    const float* Wb     = (const float*)d_in[9];
    const float* A_log  = (const float*)d_in[10];
    const float* dt_bias= (const float*)d_in[11];
    const float* Wg     = (const float*)d_in[12];
    const float* bg     = (const float*)d_in[13];
    const float* norm_w = (const float*)d_in[14];
    const float* Wo     = (const float*)d_in[15];
    float* out = (float*)d_out;

    const size_t N1  = (size_t)2048 * 2048;   // 4,194,304 elems
    const size_t N1B = N1 * 4;                 // bytes of one fp32 matrix
    const int M = BB * TT;                     // 2048

    const size_t NEED_NEW = 9 * N1B + 4325376; // ~155.3 MB

    if (ws_size >= NEED_NEW) {
        // ---------------- MFMA split-precision path ----------------
        char* W = (char*)d_ws;
        // region A [0, N1B): hid split; later o (recurrence output)
        unsigned short* hidh = (unsigned short*)W;
        unsigned short* hidl = hidh + N1;
        float* o = (float*)W;
        // region B [N1B, 5*N1B): 8 transposed-weight bf16 arrays;
        // later qn/kn/vn (3*N1B) overlay Wq/Wk/Wv-transposes.
        char* RB = W + N1B;
        unsigned short* Wqth = (unsigned short*)RB;
        unsigned short* Wqtl = Wqth + N1;
        unsigned short* Wkth = Wqtl + N1;
        unsigned short* Wktl = Wkth + N1;
        unsigned short* Wvth = Wktl + N1;
        unsigned short* Wvtl = Wvth + N1;
        unsigned short* Wgth = Wvtl + N1;
        unsigned short* Wgtl = Wgth + N1;
        float* qn = (float*)RB;
        float* kn = qn + N1;
        float* vn = kn + N1;
        // region C [5*N1B, 9*N1B): q/k/v/g pre-activations.
        // Timeline per 16MB slot:
        //   qpre: conv-q input -> qn_t (recur) -> Woth/Wotl (out-gemm)
        //   kpre: conv-k input -> kn_t (recur) -> yh/yl (rmsnorm out)
        //   vpre: conv-v input -> vn_t (recur)
        //   gpre: live until rmsnorm
        char* RC = W + 5 * N1B;
        float* qpre = (float*)RC;
        float* kpre = qpre + N1;
        float* vpre = kpre + N1;
        float* gpre = vpre + N1;
        float* qn_t = qpre;
        float* kn_t = kpre;
        float* vn_t = vpre;
        unsigned short* Woth = (unsigned short*)RC;
        unsigned short* Wotl = Woth + N1;
        unsigned short* yh = (unsigned short*)(RC + N1B);
        unsigned short* yl = yh + N1;
        // region D [9*N1B, ...): small buffers
        char* RD = W + 9 * N1B;
        float* g1b   = (float*)RD;                    // 262144
        float* g2b   = g1b + 262144;                  // 262144
        float* betab = g2b + 262144;                  // 32768
        float* decayb= betab + 32768;                 // 262144 (tiled)
        unsigned short* wf1th = (unsigned short*)(decayb + 262144);
        unsigned short* wf1tl = wf1th + 262144;

        // 1. splits / transposes
        split_mat<<<1024, 256, 0, stream>>>(hid, hidh, hidl);
        transpose_split<<<dim3(32, 32), 256, 0, stream>>>(Wq, Wqth, Wqtl, 2048, 2048);
        transpose_split<<<dim3(32, 32), 256, 0, stream>>>(Wk, Wkth, Wktl, 2048, 2048);
        transpose_split<<<dim3(32, 32), 256, 0, stream>>>(Wv, Wvth, Wvtl, 2048, 2048);
        transpose_split<<<dim3(32, 32), 256, 0, stream>>>(Wg, Wgth, Wgtl, 2048, 2048);
        transpose_split<<<dim3(2, 32), 256, 0, stream>>>(Wf1, wf1th, wf1tl, 128, 2048);

        // 2. fused input projections (q,k,v,g, f1)
        GemmArgs fa;
        fa.Ah = hidh; fa.Al = hidl;
        fa.Bh[0] = Wqth; fa.Bl[0] = Wqtl; fa.C[0] = qpre;
        fa.Bh[1] = Wkth; fa.Bl[1] = Wktl; fa.C[1] = kpre;
        fa.Bh[2] = Wvth; fa.Bl[2] = Wvtl; fa.C[2] = vpre;
        fa.Bh[3] = Wgth; fa.Bl[3] = Wgtl; fa.C[3] = gpre;
        fa.Bh[4] = wf1th; fa.Bl[4] = wf1tl; fa.C[4] = g1b;
        gemm_split<<<dim3(65, 16), 256, 0, stream>>>(fa, 1);

        // 3. beta, g2, decay (t-tiled)
        beta_kernel<<<M, 256, 0, stream>>>(hid, Wb, betab);
        sgemm128<<<dim3(1, 16), 256, 0, stream>>>(g1b, Wf2, g2b, M, 128, 128);
        decay_kernel_t<<<(M * HH * NG) / 256, 256, 0, stream>>>(g2b, A_log, dt_bias, decayb);

        // 4. conv + silu (+ l2norm)  [b,t,c]
        conv_silu_norm<<<M * HH, 128, 0, stream>>>(qpre, conv_q, qn, SCALE_Q, 1);
        conv_silu_norm<<<M * HH, 128, 0, stream>>>(kpre, conv_k, kn, 1.f, 1);
        conv_silu_norm<<<M * HH, 128, 0, stream>>>(vpre, conv_v, vn, 1.f, 0);

        // 5. t-tile transpose (into dead pre-activation slots)
        transpose_tile<<<4096, 256, 0, stream>>>(qn, qn_t);
        transpose_tile<<<4096, 256, 0, stream>>>(kn, kn_t);
        transpose_tile<<<4096, 256, 0, stream>>>(vn, vn_t);

        // 6. recurrence, split-wave (o over dead hid split)
        recur_kernel_t<<<BB * HH * 16, 256, 0, stream>>>(qn_t, kn_t, vn_t, decayb, betab, o);

        // 7. transpose Wo (over dead qn_t)
        transpose_split<<<dim3(32, 32), 256, 0, stream>>>(Wo, Woth, Wotl, 2048, 2048);

        // 8. gated rmsnorm -> y split (over dead kn_t)
        gated_rmsnorm_split<<<M * HH, 128, 0, stream>>>(o, gpre, bg, norm_w, yh, yl);

        // 9. output projection
        GemmArgs oa;
        oa.Ah = yh; oa.Al = yl;
        for (int i = 0; i < 5; ++i) { oa.Bh[i] = Woth; oa.Bl[i] = Wotl; oa.C[i] = out; }
        gemm_split<<<dim3(16, 16), 256, 0, stream>>>(oa, 0);
    } else {
        // ---------------- fallback: fp32 path (round-2 proven) ----------------
        float* ws = (float*)d_ws;
        float* qpre = ws + 0 * N1;
        float* kpre = ws + 1 * N1;
        float* vpre = ws + 2 * N1;
        float* gpre = ws + 3 * N1;
        float* qn   = ws + 4 * N1;
        float* kn   = ws + 5 * N1;
        float* vn   = ws + 6 * N1;
        float* g1b  = ws + 7 * N1;
        float* g2b  = g1b + (size_t)BB * TT * DV;
        float* betab= g2b + (size_t)BB * TT * HH * NG;
        float* decayb = betab + (size_t)BB * TT * HH;
        float* o = qpre;
        float* y = vpre;

        sgemm128<<<dim3(16, 16), 256, 0, stream>>>(hid, Wq, qpre, M, 2048, 2048);
        sgemm128<<<dim3(16, 16), 256, 0, stream>>>(hid, Wk, kpre, M, 2048, 2048);
        sgemm128<<<dim3(16, 16), 256, 0, stream>>>(hid, Wv, vpre, M, 2048, 2048);
        sgemm128<<<dim3(16, 16), 256, 0, stream>>>(hid, Wg, gpre, M, 2048, 2048);
        sgemm128<<<dim3(1, 16), 256, 0, stream>>>(hid, Wf1, g1b, M, 128, 2048);
        sgemm128<<<dim3(1, 16), 256, 0, stream>>>(g1b, Wf2, g2b, M, 128, 128);
        beta_kernel<<<M, 256, 0, stream>>>(hid, Wb, betab);

        conv_silu_norm<<<M * HH, 128, 0, stream>>>(qpre, conv_q, qn, SCALE_Q, 1);
        conv_silu_norm<<<M * HH, 128, 0, stream>>>(kpre, conv_k, kn, 1.f, 1);
        conv_silu_norm<<<M * HH, 128, 0, stream>>>(vpre, conv_v, vn, 1.f, 0);

        decay_kernel<<<(M * HH * NG) / 256, 256, 0, stream>>>(g2b, A_log, dt_bias, decayb);

        recur_kernel<<<BB * HH * (DV / 4), 256, 0, stream>>>(qn, kn, vn, decayb, betab, o);

        gated_rmsnorm<<<M * HH, 128, 0, stream>>>(o, gpre, bg, norm_w, y);

        sgemm128<<<dim3(16, 16), 256, 0, stream>>>(y, Wo, out, M, 2048, 2048);
    }
}

// Round 11
// 866.878 us; speedup vs baseline: 1.1903x; 1.1903x over previous
//
#include <hip/hip_runtime.h>
#include <hip/hip_bf16.h>
#include <math.h>

// Problem constants (fixed by setup_inputs)
#define BB 2
#define TT 1024
#define DD 2048
#define HH 16
#define DK 128
#define DV 128
#define NG 8
#define GG 16
#define SCALE_Q 0.08838834764831845f  // 128^-0.5

typedef __attribute__((ext_vector_type(8))) short bf16x8;
typedef __attribute__((ext_vector_type(4))) float f32x4;

// bf16 split helpers (RNE)
__device__ __forceinline__ unsigned short f2bf(float v) {
    unsigned u = __float_as_uint(v);
    return (unsigned short)((u + 0x7FFFu + ((u >> 16) & 1u)) >> 16);
}
__device__ __forceinline__ float bf2f(unsigned short h) {
    return __uint_as_float(((unsigned)h) << 16);
}
__device__ __forceinline__ void bsplit(float v, unsigned short& h, unsigned short& l) {
    h = f2bf(v);
    l = f2bf(v - bf2f(h));
}

// ---------------------------------------------------------------------------
// DPP wave64 sum (row_shr 1/2/4/8 + row_bcast 15/31). Lane 63 holds full sum.
// ---------------------------------------------------------------------------
__device__ __forceinline__ float dpp_sum64(float x) {
    x += __int_as_float(__builtin_amdgcn_update_dpp(0, __float_as_int(x), 0x111, 0xf, 0xf, true));  // row_shr:1
    x += __int_as_float(__builtin_amdgcn_update_dpp(0, __float_as_int(x), 0x112, 0xf, 0xf, true));  // row_shr:2
    x += __int_as_float(__builtin_amdgcn_update_dpp(0, __float_as_int(x), 0x114, 0xf, 0xf, true));  // row_shr:4
    x += __int_as_float(__builtin_amdgcn_update_dpp(0, __float_as_int(x), 0x118, 0xf, 0xf, true));  // row_shr:8
    x += __int_as_float(__builtin_amdgcn_update_dpp(0, __float_as_int(x), 0x142, 0xa, 0xf, false)); // row_bcast:15
    x += __int_as_float(__builtin_amdgcn_update_dpp(0, __float_as_int(x), 0x143, 0xc, 0xf, false)); // row_bcast:31
    return x;
}
__device__ __forceinline__ float readlanef(float x, int l) {
    return __int_as_float(__builtin_amdgcn_readlane(__float_as_int(x), l));
}
__device__ __forceinline__ float f4get(const float4 f, int c) {
    return c == 0 ? f.x : c == 1 ? f.y : c == 2 ? f.z : f.w;
}

// ---------------------------------------------------------------------------
// split: fp32 [n] -> bf16 hi/lo
// ---------------------------------------------------------------------------
__global__ void split_mat(const float* __restrict__ in, unsigned short* __restrict__ oh,
                          unsigned short* __restrict__ ol) {
    const int i0 = (blockIdx.x * 256 + threadIdx.x) * 16;
#pragma unroll
    for (int r = 0; r < 4; ++r) {
        const float4 v = *(const float4*)(in + i0 + r * 4);
        unsigned short h0, l0, h1, l1, h2, l2, h3, l3;
        bsplit(v.x, h0, l0); bsplit(v.y, h1, l1);
        bsplit(v.z, h2, l2); bsplit(v.w, h3, l3);
        short4 hh; hh.x = (short)h0; hh.y = (short)h1; hh.z = (short)h2; hh.w = (short)h3;
        short4 ll; ll.x = (short)l0; ll.y = (short)l1; ll.z = (short)l2; ll.w = (short)l3;
        *(short4*)(oh + i0 + r * 4) = hh;
        *(short4*)(ol + i0 + r * 4) = ll;
    }
}

// ---------------------------------------------------------------------------
// transpose + split: in fp32 [Kin][Nin] -> out bf16 hi/lo [Nin][Kin]
// ---------------------------------------------------------------------------
__global__ void transpose_split(const float* __restrict__ in, unsigned short* __restrict__ oh,
                                unsigned short* __restrict__ ol, int Nin, int Kin) {
    __shared__ float t[64][65];
    const int bx = blockIdx.x, by = blockIdx.y;
    const int tid = threadIdx.x;
    const int c4 = (tid & 15) * 4, r0 = tid >> 4;
#pragma unroll
    for (int rep = 0; rep < 4; ++rep) {
        const int r = r0 + rep * 16;
        const float4 v = *(const float4*)(in + (size_t)(by * 64 + r) * Nin + bx * 64 + c4);
        t[r][c4] = v.x; t[r][c4 + 1] = v.y; t[r][c4 + 2] = v.z; t[r][c4 + 3] = v.w;
    }
    __syncthreads();
#pragma unroll
    for (int rep = 0; rep < 4; ++rep) {
        const int n = r0 + rep * 16;
        short4 hh, ll;
        unsigned short h, l;
        bsplit(t[c4 + 0][n], h, l); hh.x = (short)h; ll.x = (short)l;
        bsplit(t[c4 + 1][n], h, l); hh.y = (short)h; ll.y = (short)l;
        bsplit(t[c4 + 2][n], h, l); hh.z = (short)h; ll.z = (short)l;
        bsplit(t[c4 + 3][n], h, l); hh.w = (short)h; ll.w = (short)l;
        const size_t o = (size_t)(bx * 64 + n) * Kin + by * 64 + c4;
        *(short4*)(oh + o) = hh;
        *(short4*)(ol + o) = ll;
    }
}

// ---------------------------------------------------------------------------
// t-tile transpose: in [B][1024][2048] -> out tiled [bh][tblk][cl][8]
// ---------------------------------------------------------------------------
__global__ void transpose_tile(const float* __restrict__ in, float* __restrict__ out) {
    __shared__ float tl[8][128];
    const int blk = blockIdx.x;
    const int bh = blk >> 7, tblk = blk & 127;
    const int b = bh >> 4, h = bh & 15;
    const int tid = threadIdx.x;

    const int tt = tid >> 5, c4 = (tid & 31) * 4;
    const float4 v = *(const float4*)(in + ((size_t)(b * 1024 + tblk * 8 + tt)) * 2048 + h * 128 + c4);
    tl[tt][c4] = v.x; tl[tt][c4 + 1] = v.y; tl[tt][c4 + 2] = v.z; tl[tt][c4 + 3] = v.w;
    __syncthreads();

    const int cl = tid >> 1, tj0 = (tid & 1) * 4;
    float4 w4;
    w4.x = tl[tj0 + 0][cl]; w4.y = tl[tj0 + 1][cl];
    w4.z = tl[tj0 + 2][cl]; w4.w = tl[tj0 + 3][cl];
    *(float4*)(out + ((size_t)blk * 128 + cl) * 8 + tj0) = w4;
}

// ---------------------------------------------------------------------------
// Split-precision bf16 MFMA GEMM (verified round 4).
// ---------------------------------------------------------------------------
struct GemmArgs {
    const unsigned short* Ah; const unsigned short* Al;
    const unsigned short* Bh[5]; const unsigned short* Bl[5];
    float* C[5];
};

#define AHI 0
#define ALO 8192
#define BHI 16384
#define BLO 24576

#define GL2LDS(g, s) __builtin_amdgcn_global_load_lds( \
    (const __attribute__((address_space(1))) void*)(g), \
    (__attribute__((address_space(3))) void*)(s), 16, 0, 0)

__launch_bounds__(256, 2)
__global__ void gemm_split(GemmArgs p, int fused) {
    __shared__ __attribute__((aligned(16))) char lds[32768];
    const int tid = threadIdx.x;
    const int bx = blockIdx.x, by = blockIdx.y;

    int sel, nloc, ldc;
    if (fused) {
        if (bx < 64) { sel = bx >> 4; nloc = (bx & 15) * 128; ldc = 2048; }
        else         { sel = 4;       nloc = 0;               ldc = 128;  }
    } else { sel = 0; nloc = bx * 128; ldc = 2048; }

    const unsigned short* Asrc_h = p.Ah + (size_t)(by * 128) * 2048;
    const unsigned short* Asrc_l = p.Al + (size_t)(by * 128) * 2048;
    const unsigned short* Bsrc_h = p.Bh[sel] + (size_t)nloc * 2048;
    const unsigned short* Bsrc_l = p.Bl[sel] + (size_t)nloc * 2048;

    const int r0 = tid >> 2, ps0 = tid & 3;
    const int r1 = (tid + 256) >> 2, ps1 = tid & 3;
    const size_t ga0 = (size_t)r0 * 2048 + (size_t)((ps0 ^ ((r0 >> 1) & 3)) * 8);
    const size_t ga1 = (size_t)r1 * 2048 + (size_t)((ps1 ^ ((r1 >> 1) & 3)) * 8);
    const int lb0 = (tid & 192) * 16;
    const int lb1 = (256 + (tid & 192)) * 16;

    const int lane = tid & 63;
    const int l15 = lane & 15, kgrp = lane >> 4;
    const int w = tid >> 6, wm = w >> 1, wn = w & 1;
    const int swz = kgrp ^ ((l15 >> 1) & 3);
    const int fro = l15 * 64 + swz * 16;
    const int aoff = wm * 4096, boff = wn * 4096;

    f32x4 acc[4][4];
#pragma unroll
    for (int i = 0; i < 4; ++i)
#pragma unroll
        for (int j = 0; j < 4; ++j) acc[i][j] = (f32x4){0.f, 0.f, 0.f, 0.f};

    for (int k0 = 0; k0 < 2048; k0 += 32) {
        __syncthreads();
        GL2LDS(Asrc_h + k0 + ga0, lds + AHI + lb0);
        GL2LDS(Asrc_h + k0 + ga1, lds + AHI + lb1);
        GL2LDS(Asrc_l + k0 + ga0, lds + ALO + lb0);
        GL2LDS(Asrc_l + k0 + ga1, lds + ALO + lb1);
        GL2LDS(Bsrc_h + k0 + ga0, lds + BHI + lb0);
        GL2LDS(Bsrc_h + k0 + ga1, lds + BHI + lb1);
        GL2LDS(Bsrc_l + k0 + ga0, lds + BLO + lb0);
        GL2LDS(Bsrc_l + k0 + ga1, lds + BLO + lb1);
        __syncthreads();

        bf16x8 ah[4], al4[4], bh4[4], bl4[4];
#pragma unroll
        for (int f = 0; f < 4; ++f) {
            ah[f]  = *(const bf16x8*)(lds + AHI + aoff + f * 1024 + fro);
            al4[f] = *(const bf16x8*)(lds + ALO + aoff + f * 1024 + fro);
            bh4[f] = *(const bf16x8*)(lds + BHI + boff + f * 1024 + fro);
            bl4[f] = *(const bf16x8*)(lds + BLO + boff + f * 1024 + fro);
        }
#pragma unroll
        for (int i = 0; i < 4; ++i)
#pragma unroll
            for (int j = 0; j < 4; ++j) {
                acc[i][j] = __builtin_amdgcn_mfma_f32_16x16x32_bf16(ah[i],  bh4[j], acc[i][j], 0, 0, 0);
                acc[i][j] = __builtin_amdgcn_mfma_f32_16x16x32_bf16(ah[i],  bl4[j], acc[i][j], 0, 0, 0);
                acc[i][j] = __builtin_amdgcn_mfma_f32_16x16x32_bf16(al4[i], bh4[j], acc[i][j], 0, 0, 0);
            }
    }

    float* cb = p.C[sel];
    const int m0 = by * 128 + wm * 64 + kgrp * 4;
    const int n0 = nloc + wn * 64 + l15;
#pragma unroll
    for (int i = 0; i < 4; ++i)
#pragma unroll
        for (int t = 0; t < 4; ++t) {
            float* cp = cb + (size_t)(m0 + i * 16 + t) * ldc + n0;
#pragma unroll
            for (int j = 0; j < 4; ++j) cp[j * 16] = acc[i][j][t];
        }
}

// ---------------------------------------------------------------------------
// Generic fp32 SGEMM (kept for g1@Wf2 and as full fallback path).
// ---------------------------------------------------------------------------
#define GBM 128
#define GBN 128
#define GBK 16

__launch_bounds__(256)
__global__ void sgemm128(const float* __restrict__ A, const float* __restrict__ B,
                         float* __restrict__ C, int M, int N, int K) {
    __shared__ float As[GBK][GBM + 4];
    __shared__ float Bs[GBK][GBN + 4];

    const int tid = threadIdx.x;
    const int bm = blockIdx.y * GBM;
    const int bn = blockIdx.x * GBN;

    const int arow = tid >> 2;
    const int acol = (tid & 3) << 2;
    const int brow = tid >> 5;
    const int bcol = (tid & 31) << 2;
    const int ty = tid >> 4;
    const int tx = tid & 15;

    float acc[8][8];
#pragma unroll
    for (int i = 0; i < 8; ++i)
#pragma unroll
        for (int j = 0; j < 8; ++j) acc[i][j] = 0.f;

    for (int k0 = 0; k0 < K; k0 += GBK) {
#pragma unroll
        for (int r = 0; r < 2; ++r) {
            const int m = arow + r * 64;
            const float4 av = *(const float4*)(A + (size_t)(bm + m) * K + k0 + acol);
            As[acol + 0][m] = av.x;
            As[acol + 1][m] = av.y;
            As[acol + 2][m] = av.z;
            As[acol + 3][m] = av.w;
        }
#pragma unroll
        for (int r = 0; r < 2; ++r) {
            const int kk = brow + r * 8;
            *(float4*)(&Bs[kk][bcol]) =
                *(const float4*)(B + (size_t)(k0 + kk) * N + bn + bcol);
        }
        __syncthreads();

#pragma unroll
        for (int kk = 0; kk < GBK; ++kk) {
            float a[8], bf[8];
#pragma unroll
            for (int i = 0; i < 8; ++i) a[i] = As[kk][ty * 8 + i];
#pragma unroll
            for (int j = 0; j < 8; ++j) bf[j] = Bs[kk][tx * 8 + j];
#pragma unroll
            for (int i = 0; i < 8; ++i)
#pragma unroll
                for (int j = 0; j < 8; ++j)
                    acc[i][j] = fmaf(a[i], bf[j], acc[i][j]);
        }
        __syncthreads();
    }

#pragma unroll
    for (int i = 0; i < 8; ++i) {
        float* cp = C + (size_t)(bm + ty * 8 + i) * N + bn + tx * 8;
        *(float4*)(cp + 0) = make_float4(acc[i][0], acc[i][1], acc[i][2], acc[i][3]);
        *(float4*)(cp + 4) = make_float4(acc[i][4], acc[i][5], acc[i][6], acc[i][7]);
    }
}

// ---------------------------------------------------------------------------
// Causal depthwise conv1d (K=4) + silu, optional per-head l2norm * scale.
// ---------------------------------------------------------------------------
__global__ void conv_silu_norm(const float* __restrict__ pre, const float* __restrict__ w,
                               float* __restrict__ out, float scale, int do_norm) {
    const int blk = blockIdx.x;
    const int h = blk & 15;
    const int bt = blk >> 4;
    const int t = bt & (TT - 1);
    const int b = bt >> 10;
    const int dk = threadIdx.x;
    const int c = h * 128 + dk;

    const size_t off = ((size_t)(b * TT + t)) * DD + c;
    float acc = 0.f;
#pragma unroll
    for (int j = 0; j < 4; ++j) {
        const int tt = t - 3 + j;
        const float x = (tt >= 0) ? pre[off + (size_t)(j - 3) * DD] : 0.f;
        acc = fmaf(x, w[c * 4 + j], acc);
    }
    float x = acc / (1.f + expf(-acc));  // silu

    if (do_norm) {
        float ss = x * x;
#pragma unroll
        for (int s = 1; s < 64; s <<= 1) ss += __shfl_xor(ss, s, 64);
        __shared__ float red[2];
        if ((threadIdx.x & 63) == 0) red[threadIdx.x >> 6] = ss;
        __syncthreads();
        const float tot = red[0] + red[1];
        x = x * rsqrtf(tot + 1e-6f) * scale;
    }
    out[off] = x;
}

// ---------------------------------------------------------------------------
__global__ void beta_kernel(const float* __restrict__ hid, const float* __restrict__ Wb,
                            float* __restrict__ beta) {
    const int m = blockIdx.x;
    const int t = threadIdx.x;
    const int h = t & 15;
    const int sl = t >> 4;

    const float* hp = hid + (size_t)m * DD + sl * 128;
    const float* wp = Wb + (size_t)sl * 128 * HH + h;
    float p = 0.f;
#pragma unroll 8
    for (int i = 0; i < 128; ++i) p = fmaf(hp[i], wp[i * HH], p);

    __shared__ float red[256];
    red[t] = p;
    __syncthreads();
    if (t < HH) {
        float s = 0.f;
#pragma unroll
        for (int i = 0; i < 16; ++i) s += red[i * 16 + t];
        beta[(size_t)m * HH + t] = 1.f / (1.f + expf(-s));
    }
}

// ---------------------------------------------------------------------------
// decay (fallback layout [b,t,h,g])
// ---------------------------------------------------------------------------
__global__ void decay_kernel(const float* __restrict__ g2, const float* __restrict__ A_log,
                             const float* __restrict__ dt_bias, float* __restrict__ decay) {
    const int idx = blockIdx.x * 256 + threadIdx.x;
    const int g = idx & (NG - 1);
    const int h = (idx >> 3) & (HH - 1);
    const float x = g2[idx] + dt_bias[h * NG + g];
    const float sp = (x > 20.f) ? x : log1pf(expf(x));
    decay[idx] = expf(-expf(A_log[h]) * sp);
}

// ---------------------------------------------------------------------------
// decay, t-tiled output [bh][tblk][g][8]
// ---------------------------------------------------------------------------
__global__ void decay_kernel_t(const float* __restrict__ g2, const float* __restrict__ A_log,
                               const float* __restrict__ dt_bias, float* __restrict__ dtr) {
    const int idx = blockIdx.x * 256 + threadIdx.x;   // (b,t,h,g)
    const int g = idx & 7, h = (idx >> 3) & 15;
    const int t = (idx >> 7) & 1023, b = idx >> 17;
    const float x = g2[idx] + dt_bias[h * NG + g];
    const float sp = (x > 20.f) ? x : log1pf(expf(x));
    const float d = expf(-expf(A_log[h]) * sp);
    const int bh = b * 16 + h, tblk = t >> 3, tj = t & 7;
    dtr[((size_t)(bh * 128 + tblk)) * 64 + g * 8 + tj] = d;
}

// ---------------------------------------------------------------------------
// Pair-coupling precompute: c[bh][tblk][j] = sum_c k[c][2j+1]*d[g(c)][2j+1]*k[c][2j]
// (S-independent lookahead coefficient for the paired recurrence step).
// One wave per (bh,tblk): 4096 waves = 1024 blocks x 4.
// ---------------------------------------------------------------------------
__launch_bounds__(256, 4)
__global__ void pairc_kernel(const float* __restrict__ kt, const float* __restrict__ dtr,
                             float* __restrict__ cpair) {
    const int gw = blockIdx.x * 4 + (threadIdx.x >> 6);
    const int bh = gw >> 7, tblk = gw & 127;
    const int lane = threadIdx.x & 63;

    const float* kp = kt + (size_t)bh * 131072 + (size_t)tblk * 1024 + (size_t)(2 * lane) * 8;
    const float* dp = dtr + (size_t)bh * 8192 + (size_t)tblk * 64 + (size_t)(lane >> 3) * 8;

    float4 K0a = *(const float4*)(kp);      // ch 2l, t0..3
    float4 K0b = *(const float4*)(kp + 4);  // ch 2l, t4..7
    float4 K1a = *(const float4*)(kp + 8);  // ch 2l+1, t0..3
    float4 K1b = *(const float4*)(kp + 12);
    float4 Da = *(const float4*)(dp);       // d t0..3 (group of both channels)
    float4 Db = *(const float4*)(dp + 4);

    // pairs (0,1),(2,3) from a-halves; (4,5),(6,7) from b-halves
    float c0 = K0a.y * Da.y * K0a.x + K1a.y * Da.y * K1a.x;
    float c1 = K0a.w * Da.w * K0a.z + K1a.w * Da.w * K1a.z;
    float c2 = K0b.y * Db.y * K0b.x + K1b.y * Db.y * K1b.x;
    float c3 = K0b.w * Db.w * K0b.z + K1b.w * Db.w * K1b.z;

    c0 = dpp_sum64(c0);
    c1 = dpp_sum64(c1);
    c2 = dpp_sum64(c2);
    c3 = dpp_sum64(c3);

    if (lane == 63) {
        float4 out = make_float4(c0, c1, c2, c3);
        *(float4*)(cpair + (size_t)bh * 512 + (size_t)tblk * 4) = out;
    }
}

// ---------------------------------------------------------------------------
// Gated delta-rule recurrence, t-tiled inputs, PAIRED steps (2-step lookahead).
// Structure identical to the proven round-9 kernel (1 v-col/wave, 4096 waves,
// chunked double-buffer, XCD swizzle); the inner loop processes steps in
// pairs: both err-reduction trees are issued before the first readlane, so
// their latencies overlap.  err2 = k2.(d2 d1 S) + c*delta1 with precomputed
// c = k2.(d2 k1) (pairc_kernel).  o-trees likewise pair.
// ---------------------------------------------------------------------------
#define CLD(K, Q, D, V, Bf, C4, T0) do {                                       \
    const float* kpt = kp0 + (size_t)(T0) * 128;                               \
    const float* qpt = qp0 + (size_t)(T0) * 128;                               \
    K[0] = *(const float4*)(kpt);      K[1] = *(const float4*)(kpt + 4);       \
    K[2] = *(const float4*)(kpt + 8);  K[3] = *(const float4*)(kpt + 12);      \
    Q[0] = *(const float4*)(qpt);      Q[1] = *(const float4*)(qpt + 4);       \
    Q[2] = *(const float4*)(qpt + 8);  Q[3] = *(const float4*)(qpt + 12);      \
    D[0] = *(const float4*)(dp + (size_t)(T0) * 8);                            \
    D[1] = *(const float4*)(dp + (size_t)(T0) * 8 + 4);                        \
    C4 = *(const float4*)(cp + (size_t)(T0) / 2);                              \
    V = vp[(size_t)(T0) * 128];                                                \
    Bf = bp[(size_t)(T0) * 16];                                                \
} while (0)

#define CSTEP(K, Q, D, V, Bf, C4, T0) do {                                     \
    _Pragma("unroll")                                                          \
    for (int jp = 0; jp < 4; ++jp) {                                           \
        const int j0 = 2 * jp, j1 = 2 * jp + 1;                                \
        const float d0 = f4get(D[j0 >> 2], j0 & 3);                            \
        const float d1 = f4get(D[j1 >> 2], j1 & 3);                            \
        const float k00 = f4get(K[j0 >> 2], j0 & 3);                           \
        const float k01 = f4get(K[2 + (j0 >> 2)], j0 & 3);                     \
        const float k10 = f4get(K[j1 >> 2], j1 & 3);                           \
        const float k11 = f4get(K[2 + (j1 >> 2)], j1 & 3);                     \
        const float t10 = S0 * d0, t11 = S1 * d0;                              \
        const float t20 = t10 * d1, t21 = t11 * d1;                            \
        float e1 = fmaf(k00, t10, k01 * t11);                                  \
        float e2 = fmaf(k10, t20, k11 * t21);                                  \
        e1 = dpp_sum64(e1);                                                    \
        e2 = dpp_sum64(e2);                                                    \
        const float err1 = readlanef(e1, 63);                                  \
        const float v0 = readlanef(V, j0), b0 = readlanef(Bf, j0);             \
        const float dl1 = b0 * (v0 - err1);                                    \
        const float cj = f4get(C4, jp);                                        \
        const float err2 = fmaf(cj, dl1, readlanef(e2, 63));                   \
        const float v1 = readlanef(V, j1), b1 = readlanef(Bf, j1);             \
        const float dl2 = b1 * (v1 - err2);                                    \
        const float s10 = fmaf(k00, dl1, t10);                                 \
        const float s11 = fmaf(k01, dl1, t11);                                 \
        S0 = fmaf(k10, dl2, d1 * s10);                                         \
        S1 = fmaf(k11, dl2, d1 * s11);                                         \
        const float q00 = f4get(Q[j0 >> 2], j0 & 3);                           \
        const float q01 = f4get(Q[2 + (j0 >> 2)], j0 & 3);                     \
        const float q10 = f4get(Q[j1 >> 2], j1 & 3);                           \
        const float q11 = f4get(Q[2 + (j1 >> 2)], j1 & 3);                     \
        float o1 = fmaf(q00, s10, q01 * s11);                                  \
        float o2 = fmaf(q10, S0, q11 * S1);                                    \
        o1 = dpp_sum64(o1);                                                    \
        o2 = dpp_sum64(o2);                                                    \
        if (lane == 63) {                                                      \
            o[obase + (size_t)((T0) + j0) * 2048 + vi] = o1;                   \
            o[obase + (size_t)((T0) + j1) * 2048 + vi] = o2;                   \
        }                                                                      \
    }                                                                          \
} while (0)

__launch_bounds__(256, 4)
__global__ void recur_kernel_t(const float* __restrict__ qt, const float* __restrict__ kt,
                               const float* __restrict__ vt, const float* __restrict__ dtr,
                               const float* __restrict__ beta, const float* __restrict__ cpair,
                               float* __restrict__ o) {
    const int bid = blockIdx.x;
    const int xcd = bid & 7, idx = bid >> 3;
    const int bh = xcd * 4 + (idx >> 5);   // all 32 v-blocks of a bh share an XCD
    const int vblk = idx & 31;
    const int b = bh >> 4, h = bh & 15;
    const int w = threadIdx.x >> 6;
    const int lane = threadIdx.x & 63;
    const int jl = lane & 7;
    const int vi = vblk * 4 + w;

    // tiled bases: per-bh block = 128 tblk * 128 c * 8 t = 131072 floats
    const float* kp0 = kt + (size_t)bh * 131072 + (size_t)(2 * lane) * 8;
    const float* qp0 = qt + (size_t)bh * 131072 + (size_t)(2 * lane) * 8;
    const float* vp  = vt + (size_t)bh * 131072 + (size_t)vi * 8 + jl;
    const float* dp  = dtr + (size_t)bh * 8192 + (size_t)(lane >> 3) * 8;
    const float* cp  = cpair + (size_t)bh * 512;
    const float* bp  = beta + ((size_t)b * 1024 + jl) * HH + h;
    const size_t obase = ((size_t)b * 1024 * HH + h) * 128;

    float S0 = 0.f, S1 = 0.f;
    float4 Ka[4], Qa[4], Da[2], Kb[4], Qb[4], Db[2], Ca, Cb;
    float Va, Bfa, Vb, Bfb;

    CLD(Ka, Qa, Da, Va, Bfa, Ca, 0);

#pragma unroll 1
    for (int t0 = 0; t0 < TT; t0 += 16) {
        CLD(Kb, Qb, Db, Vb, Bfb, Cb, t0 + 8);
        CSTEP(Ka, Qa, Da, Va, Bfa, Ca, t0);
        const int tA = (t0 + 16 < TT) ? (t0 + 16) : t0;  // clamped dummy at end
        CLD(Ka, Qa, Da, Va, Bfa, Ca, tA);
        CSTEP(Kb, Qb, Db, Vb, Bfb, Cb, t0 + 8);
    }
}

// ---------------------------------------------------------------------------
// Old-layout recurrence (fallback path only).
// ---------------------------------------------------------------------------
__launch_bounds__(256, 4)
__global__ void recur_kernel(const float* __restrict__ q, const float* __restrict__ k,
                             const float* __restrict__ vv, const float* __restrict__ decay,
                             const float* __restrict__ beta, float* __restrict__ o) {
    const int blk = blockIdx.x;
    const int vblk = blk & 31;
    const int bh = blk >> 5;
    const int b = bh >> 4, h = bh & 15;
    const int w = threadIdx.x >> 6;
    const int lane = threadIdx.x & 63;
    const int vi = vblk * 4 + w;

    float S0 = 0.f, S1 = 0.f;
    const size_t strideT = (size_t)HH * DV;
    const size_t strideT2 = strideT >> 1;
    const size_t base = ((size_t)b * TT * HH + h) * DV;

    const float2* kp = (const float2*)(k + base) + lane;
    const float2* qp = (const float2*)(q + base) + lane;
    const float* vp = vv + base + vi;
    const float* bp = beta + (size_t)b * TT * HH + h;
    const float* dp = decay + ((size_t)b * TT * HH + h) * NG + (lane >> 3);

    float2 kv = kp[0], qv = qp[0];
    float vtv = vp[0], bt = bp[0], dt = dp[0];

    for (int t = 0; t < TT; ++t) {
        const float2 kc = kv, qc = qv;
        const float vc = vtv, bc = bt, dc = dt;

        const int tn = (t + 1 < TT) ? (t + 1) : t;
        kv = kp[(size_t)tn * strideT2];
        qv = qp[(size_t)tn * strideT2];
        vtv = vp[(size_t)tn * strideT];
        bt = bp[(size_t)tn * HH];
        dt = dp[(size_t)tn * HH * NG];

        S0 *= dc;
        S1 *= dc;
        float e = fmaf(kc.x, S0, kc.y * S1);
        e = dpp_sum64(e);
        const float err = readlanef(e, 63);
        const float delta = bc * (vc - err);
        S0 = fmaf(kc.x, delta, S0);
        S1 = fmaf(kc.y, delta, S1);
        float oo = fmaf(qc.x, S0, qc.y * S1);
        oo = dpp_sum64(oo);
        if (lane == 63) o[base + (size_t)t * strideT + vi] = oo;
    }
}

// ---------------------------------------------------------------------------
// Gated RMSNorm -> fp32 y (fallback path)
// ---------------------------------------------------------------------------
__global__ void gated_rmsnorm(const float* __restrict__ o,
                              const float* __restrict__ gpre, const float* __restrict__ bg,
                              const float* __restrict__ norm_w, float* __restrict__ y) {
    const int blk = blockIdx.x;
    const int h = blk & 15;
    const int dv = threadIdx.x;
    const size_t off = (size_t)blk * DV + dv;

    const float ov = o[off];
    const float g = gpre[off] + bg[h * 128 + dv];
    const float yv = ov * (g / (1.f + expf(-g)));

    float ss = yv * yv;
#pragma unroll
    for (int s = 1; s < 64; s <<= 1) ss += __shfl_xor(ss, s, 64);
    __shared__ float red[2];
    if ((threadIdx.x & 63) == 0) red[threadIdx.x >> 6] = ss;
    __syncthreads();
    const float mean = (red[0] + red[1]) * (1.f / 128.f);
    y[off] = yv * rsqrtf(mean + 1e-5f) * norm_w[dv];
}

// ---------------------------------------------------------------------------
// Gated RMSNorm -> bf16 hi/lo split y
// ---------------------------------------------------------------------------
__global__ void gated_rmsnorm_split(const float* __restrict__ o,
                                    const float* __restrict__ gpre, const float* __restrict__ bg,
                                    const float* __restrict__ norm_w,
                                    unsigned short* __restrict__ yh,
                                    unsigned short* __restrict__ yl) {
    const int blk = blockIdx.x;
    const int h = blk & 15;
    const int dv = threadIdx.x;
    const size_t off = (size_t)blk * DV + dv;

    const float ov = o[off];
    const float g = gpre[off] + bg[h * 128 + dv];
    const float yv = ov * (g / (1.f + expf(-g)));

    float ss = yv * yv;
#pragma unroll
    for (int s = 1; s < 64; s <<= 1) ss += __shfl_xor(ss, s, 64);
    __shared__ float red[2];
    if ((threadIdx.x & 63) == 0) red[threadIdx.x >> 6] = ss;
    __syncthreads();
    const float mean = (red[0] + red[1]) * (1.f / 128.f);
    const float y = yv * rsqrtf(mean + 1e-5f) * norm_w[dv];
    unsigned short hh, ll;
    bsplit(y, hh, ll);
    yh[off] = hh;
    yl[off] = ll;
}

// ---------------------------------------------------------------------------
extern "C" void kernel_launch(void* const* d_in, const int* in_sizes, int n_in,
                              void* d_out, int out_size, void* d_ws, size_t ws_size,
                              hipStream_t stream) {
    const float* hid    = (const float*)d_in[0];
    const float* Wq     = (const float*)d_in[1];
    const float* Wk     = (const float*)d_in[2];
    const float* Wv     = (const float*)d_in[3];
    const float* conv_q = (const float*)d_in[4];
    const float* conv_k = (const float*)d_in[5];
    const float* conv_v = (const float*)d_in[6];
    const float* Wf1    = (const float*)d_in[7];
    const float* Wf2    = (const float*)d_in[8];
    const float* Wb     = (const float*)d_in[9];
    const float* A_log  = (const float*)d_in[10];
    const float* dt_bias= (const float*)d_in[11];
    const float* Wg     = (const float*)d_in[12];
    const float* bg     = (const float*)d_in[13];
    const float* norm_w = (const float*)d_in[14];
    const float* Wo     = (const float*)d_in[15];
    float* out = (float*)d_out;

    const size_t N1  = (size_t)2048 * 2048;   // 4,194,304 elems
    const size_t N1B = N1 * 4;                 // bytes of one fp32 matrix
    const int M = BB * TT;                     // 2048

    const size_t NEED_NEW = 9 * N1B + 4390912; // +64KB cpair

    if (ws_size >= NEED_NEW) {
        // ---------------- MFMA split-precision path ----------------
        char* W = (char*)d_ws;
        // region A [0, N1B): hid split; later o (recurrence output)
        unsigned short* hidh = (unsigned short*)W;
        unsigned short* hidl = hidh + N1;
        float* o = (float*)W;
        // region B [N1B, 5*N1B): 8 transposed-weight bf16 arrays;
        // later qn/kn/vn (3*N1B) overlay Wq/Wk/Wv-transposes.
        char* RB = W + N1B;
        unsigned short* Wqth = (unsigned short*)RB;
        unsigned short* Wqtl = Wqth + N1;
        unsigned short* Wkth = Wqtl + N1;
        unsigned short* Wktl = Wkth + N1;
        unsigned short* Wvth = Wktl + N1;
        unsigned short* Wvtl = Wvth + N1;
        unsigned short* Wgth = Wvtl + N1;
        unsigned short* Wgtl = Wgth + N1;
        float* qn = (float*)RB;
        float* kn = qn + N1;
        float* vn = kn + N1;
        // region C [5*N1B, 9*N1B): q/k/v/g pre-activations.
        //   qpre: conv-q input -> qn_t (recur) -> Woth/Wotl (out-gemm)
        //   kpre: conv-k input -> kn_t (recur) -> yh/yl (rmsnorm out)
        //   vpre: conv-v input -> vn_t (recur)
        //   gpre: live until rmsnorm
        char* RC = W + 5 * N1B;
        float* qpre = (float*)RC;
        float* kpre = qpre + N1;
        float* vpre = kpre + N1;
        float* gpre = vpre + N1;
        float* qn_t = qpre;
        float* kn_t = kpre;
        float* vn_t = vpre;
        unsigned short* Woth = (unsigned short*)RC;
        unsigned short* Wotl = Woth + N1;
        unsigned short* yh = (unsigned short*)(RC + N1B);
        unsigned short* yl = yh + N1;
        // region D [9*N1B, ...): small buffers
        char* RD = W + 9 * N1B;
        float* g1b   = (float*)RD;                    // 262144
        float* g2b   = g1b + 262144;                  // 262144
        float* betab = g2b + 262144;                  // 32768
        float* decayb= betab + 32768;                 // 262144 (tiled)
        unsigned short* wf1th = (unsigned short*)(decayb + 262144);
        unsigned short* wf1tl = wf1th + 262144;
        float* cpb   = (float*)(wf1tl + 262144);      // 16384

        // 1. splits / transposes
        split_mat<<<1024, 256, 0, stream>>>(hid, hidh, hidl);
        transpose_split<<<dim3(32, 32), 256, 0, stream>>>(Wq, Wqth, Wqtl, 2048, 2048);
        transpose_split<<<dim3(32, 32), 256, 0, stream>>>(Wk, Wkth, Wktl, 2048, 2048);
        transpose_split<<<dim3(32, 32), 256, 0, stream>>>(Wv, Wvth, Wvtl, 2048, 2048);
        transpose_split<<<dim3(32, 32), 256, 0, stream>>>(Wg, Wgth, Wgtl, 2048, 2048);
        transpose_split<<<dim3(2, 32), 256, 0, stream>>>(Wf1, wf1th, wf1tl, 128, 2048);

        // 2. fused input projections (q,k,v,g, f1)
        GemmArgs fa;
        fa.Ah = hidh; fa.Al = hidl;
        fa.Bh[0] = Wqth; fa.Bl[0] = Wqtl; fa.C[0] = qpre;
        fa.Bh[1] = Wkth; fa.Bl[1] = Wktl; fa.C[1] = kpre;
        fa.Bh[2] = Wvth; fa.Bl[2] = Wvtl; fa.C[2] = vpre;
        fa.Bh[3] = Wgth; fa.Bl[3] = Wgtl; fa.C[3] = gpre;
        fa.Bh[4] = wf1th; fa.Bl[4] = wf1tl; fa.C[4] = g1b;
        gemm_split<<<dim3(65, 16), 256, 0, stream>>>(fa, 1);

        // 3. beta, g2, decay (t-tiled)
        beta_kernel<<<M, 256, 0, stream>>>(hid, Wb, betab);
        sgemm128<<<dim3(1, 16), 256, 0, stream>>>(g1b, Wf2, g2b, M, 128, 128);
        decay_kernel_t<<<(M * HH * NG) / 256, 256, 0, stream>>>(g2b, A_log, dt_bias, decayb);

        // 4. conv + silu (+ l2norm)  [b,t,c]
        conv_silu_norm<<<M * HH, 128, 0, stream>>>(qpre, conv_q, qn, SCALE_Q, 1);
        conv_silu_norm<<<M * HH, 128, 0, stream>>>(kpre, conv_k, kn, 1.f, 1);
        conv_silu_norm<<<M * HH, 128, 0, stream>>>(vpre, conv_v, vn, 1.f, 0);

        // 5. t-tile transpose (into dead pre-activation slots)
        transpose_tile<<<4096, 256, 0, stream>>>(qn, qn_t);
        transpose_tile<<<4096, 256, 0, stream>>>(kn, kn_t);
        transpose_tile<<<4096, 256, 0, stream>>>(vn, vn_t);

        // 6. pair coefficients + recurrence (o over dead hid split)
        pairc_kernel<<<1024, 256, 0, stream>>>(kn_t, decayb, cpb);
        recur_kernel_t<<<BB * HH * (DV / 4), 256, 0, stream>>>(qn_t, kn_t, vn_t, decayb, betab, cpb, o);

        // 7. transpose Wo (over dead qn_t)
        transpose_split<<<dim3(32, 32), 256, 0, stream>>>(Wo, Woth, Wotl, 2048, 2048);

        // 8. gated rmsnorm -> y split (over dead kn_t)
        gated_rmsnorm_split<<<M * HH, 128, 0, stream>>>(o, gpre, bg, norm_w, yh, yl);

        // 9. output projection
        GemmArgs oa;
        oa.Ah = yh; oa.Al = yl;
        for (int i = 0; i < 5; ++i) { oa.Bh[i] = Woth; oa.Bl[i] = Wotl; oa.C[i] = out; }
        gemm_split<<<dim3(16, 16), 256, 0, stream>>>(oa, 0);
    } else {
        // ---------------- fallback: fp32 path (round-2 proven) ----------------
        float* ws = (float*)d_ws;
        float* qpre = ws + 0 * N1;
        float* kpre = ws + 1 * N1;
        float* vpre = ws + 2 * N1;
        float* gpre = ws + 3 * N1;
        float* qn   = ws + 4 * N1;
        float* kn   = ws + 5 * N1;
        float* vn   = ws + 6 * N1;
        float* g1b  = ws + 7 * N1;
        float* g2b  = g1b + (size_t)BB * TT * DV;
        float* betab= g2b + (size_t)BB * TT * HH * NG;
        float* decayb = betab + (size_t)BB * TT * HH;
        float* o = qpre;
        float* y = vpre;

        sgemm128<<<dim3(16, 16), 256, 0, stream>>>(hid, Wq, qpre, M, 2048, 2048);
        sgemm128<<<dim3(16, 16), 256, 0, stream>>>(hid, Wk, kpre, M, 2048, 2048);
        sgemm128<<<dim3(16, 16), 256, 0, stream>>>(hid, Wv, vpre, M, 2048, 2048);
        sgemm128<<<dim3(16, 16), 256, 0, stream>>>(hid, Wg, gpre, M, 2048, 2048);
        sgemm128<<<dim3(1, 16), 256, 0, stream>>>(hid, Wf1, g1b, M, 128, 2048);
        sgemm128<<<dim3(1, 16), 256, 0, stream>>>(g1b, Wf2, g2b, M, 128, 128);
        beta_kernel<<<M, 256, 0, stream>>>(hid, Wb, betab);

        conv_silu_norm<<<M * HH, 128, 0, stream>>>(qpre, conv_q, qn, SCALE_Q, 1);
        conv_silu_norm<<<M * HH, 128, 0, stream>>>(kpre, conv_k, kn, 1.f, 1);
        conv_silu_norm<<<M * HH, 128, 0, stream>>>(vpre, conv_v, vn, 1.f, 0);

        decay_kernel<<<(M * HH * NG) / 256, 256, 0, stream>>>(g2b, A_log, dt_bias, decayb);

        recur_kernel<<<BB * HH * (DV / 4), 256, 0, stream>>>(qn, kn, vn, decayb, betab, o);

        gated_rmsnorm<<<M * HH, 128, 0, stream>>>(o, gpre, bg, norm_w, y);

        sgemm128<<<dim3(16, 16), 256, 0, stream>>>(y, Wo, out, M, 2048, 2048);
    }
}

// Round 12
// 846.839 us; speedup vs baseline: 1.2185x; 1.0237x over previous
//
#include <hip/hip_runtime.h>
#include <hip/hip_bf16.h>
#include <math.h>

// Problem constants (fixed by setup_inputs)
#define BB 2
#define TT 1024
#define DD 2048
#define HH 16
#define DK 128
#define DV 128
#define NG 8
#define GG 16
#define SCALE_Q 0.08838834764831845f  // 128^-0.5

typedef __attribute__((ext_vector_type(8))) short bf16x8;
typedef __attribute__((ext_vector_type(4))) float f32x4;

// bf16 split helpers (RNE)
__device__ __forceinline__ unsigned short f2bf(float v) {
    unsigned u = __float_as_uint(v);
    return (unsigned short)((u + 0x7FFFu + ((u >> 16) & 1u)) >> 16);
}
__device__ __forceinline__ float bf2f(unsigned short h) {
    return __uint_as_float(((unsigned)h) << 16);
}
__device__ __forceinline__ void bsplit(float v, unsigned short& h, unsigned short& l) {
    h = f2bf(v);
    l = f2bf(v - bf2f(h));
}

// ---------------------------------------------------------------------------
// DPP wave64 sum (row_shr 1/2/4/8 + row_bcast 15/31). Lane 63 holds full sum.
// ---------------------------------------------------------------------------
__device__ __forceinline__ float dpp_sum64(float x) {
    x += __int_as_float(__builtin_amdgcn_update_dpp(0, __float_as_int(x), 0x111, 0xf, 0xf, true));  // row_shr:1
    x += __int_as_float(__builtin_amdgcn_update_dpp(0, __float_as_int(x), 0x112, 0xf, 0xf, true));  // row_shr:2
    x += __int_as_float(__builtin_amdgcn_update_dpp(0, __float_as_int(x), 0x114, 0xf, 0xf, true));  // row_shr:4
    x += __int_as_float(__builtin_amdgcn_update_dpp(0, __float_as_int(x), 0x118, 0xf, 0xf, true));  // row_shr:8
    x += __int_as_float(__builtin_amdgcn_update_dpp(0, __float_as_int(x), 0x142, 0xa, 0xf, false)); // row_bcast:15
    x += __int_as_float(__builtin_amdgcn_update_dpp(0, __float_as_int(x), 0x143, 0xc, 0xf, false)); // row_bcast:31
    return x;
}
__device__ __forceinline__ float readlanef(float x, int l) {
    return __int_as_float(__builtin_amdgcn_readlane(__float_as_int(x), l));
}
__device__ __forceinline__ float f4get(const float4 f, int c) {
    return c == 0 ? f.x : c == 1 ? f.y : c == 2 ? f.z : f.w;
}

// ---------------------------------------------------------------------------
// split: fp32 [n] -> bf16 hi/lo
// ---------------------------------------------------------------------------
__global__ void split_mat(const float* __restrict__ in, unsigned short* __restrict__ oh,
                          unsigned short* __restrict__ ol) {
    const int i0 = (blockIdx.x * 256 + threadIdx.x) * 16;
#pragma unroll
    for (int r = 0; r < 4; ++r) {
        const float4 v = *(const float4*)(in + i0 + r * 4);
        unsigned short h0, l0, h1, l1, h2, l2, h3, l3;
        bsplit(v.x, h0, l0); bsplit(v.y, h1, l1);
        bsplit(v.z, h2, l2); bsplit(v.w, h3, l3);
        short4 hh; hh.x = (short)h0; hh.y = (short)h1; hh.z = (short)h2; hh.w = (short)h3;
        short4 ll; ll.x = (short)l0; ll.y = (short)l1; ll.z = (short)l2; ll.w = (short)l3;
        *(short4*)(oh + i0 + r * 4) = hh;
        *(short4*)(ol + i0 + r * 4) = ll;
    }
}

// ---------------------------------------------------------------------------
// transpose + split: in fp32 [Kin][Nin] -> out bf16 hi/lo [Nin][Kin]
// ---------------------------------------------------------------------------
__device__ __forceinline__ void tsplit_body(const float* __restrict__ in,
                                            unsigned short* __restrict__ oh,
                                            unsigned short* __restrict__ ol,
                                            int Nin, int Kin, int bx, int by, int tid) {
    __shared__ float t[64][65];
    const int c4 = (tid & 15) * 4, r0 = tid >> 4;
#pragma unroll
    for (int rep = 0; rep < 4; ++rep) {
        const int r = r0 + rep * 16;
        const float4 v = *(const float4*)(in + (size_t)(by * 64 + r) * Nin + bx * 64 + c4);
        t[r][c4] = v.x; t[r][c4 + 1] = v.y; t[r][c4 + 2] = v.z; t[r][c4 + 3] = v.w;
    }
    __syncthreads();
#pragma unroll
    for (int rep = 0; rep < 4; ++rep) {
        const int n = r0 + rep * 16;
        short4 hh, ll;
        unsigned short h, l;
        bsplit(t[c4 + 0][n], h, l); hh.x = (short)h; ll.x = (short)l;
        bsplit(t[c4 + 1][n], h, l); hh.y = (short)h; ll.y = (short)l;
        bsplit(t[c4 + 2][n], h, l); hh.z = (short)h; ll.z = (short)l;
        bsplit(t[c4 + 3][n], h, l); hh.w = (short)h; ll.w = (short)l;
        const size_t o = (size_t)(bx * 64 + n) * Kin + by * 64 + c4;
        *(short4*)(oh + o) = hh;
        *(short4*)(ol + o) = ll;
    }
}

__global__ void transpose_split(const float* __restrict__ in, unsigned short* __restrict__ oh,
                                unsigned short* __restrict__ ol, int Nin, int Kin) {
    tsplit_body(in, oh, ol, Nin, Kin, blockIdx.x, blockIdx.y, threadIdx.x);
}

// 4 big (2048x2048) weight transposes in one launch; z selects the weight.
struct TS4 { const float* in[4]; unsigned short* oh[4]; unsigned short* ol[4]; };
__global__ void transpose_split4(TS4 p) {
    const int z = blockIdx.z;
    tsplit_body(p.in[z], p.oh[z], p.ol[z], 2048, 2048, blockIdx.x, blockIdx.y, threadIdx.x);
}

// ---------------------------------------------------------------------------
// t-tile transpose x3: in [B][1024][2048] -> out tiled [bh][tblk][cl][8]
// ---------------------------------------------------------------------------
struct T3 { const float* in[3]; float* out[3]; };
__global__ void transpose_tile3(T3 p) {
    __shared__ float tl[8][128];
    const int z = blockIdx.y;
    const float* __restrict__ in = p.in[z];
    float* __restrict__ out = p.out[z];
    const int blk = blockIdx.x;
    const int bh = blk >> 7, tblk = blk & 127;
    const int b = bh >> 4, h = bh & 15;
    const int tid = threadIdx.x;

    const int tt = tid >> 5, c4 = (tid & 31) * 4;
    const float4 v = *(const float4*)(in + ((size_t)(b * 1024 + tblk * 8 + tt)) * 2048 + h * 128 + c4);
    tl[tt][c4] = v.x; tl[tt][c4 + 1] = v.y; tl[tt][c4 + 2] = v.z; tl[tt][c4 + 3] = v.w;
    __syncthreads();

    const int cl = tid >> 1, tj0 = (tid & 1) * 4;
    float4 w4;
    w4.x = tl[tj0 + 0][cl]; w4.y = tl[tj0 + 1][cl];
    w4.z = tl[tj0 + 2][cl]; w4.w = tl[tj0 + 3][cl];
    *(float4*)(out + ((size_t)blk * 128 + cl) * 8 + tj0) = w4;
}

// ---------------------------------------------------------------------------
// Split-precision bf16 MFMA GEMM (verified round 4); occupancy raised to
// 3 blocks/CU via launch_bounds (VGPR cap ~168; est. need ~150).
// ---------------------------------------------------------------------------
struct GemmArgs {
    const unsigned short* Ah; const unsigned short* Al;
    const unsigned short* Bh[5]; const unsigned short* Bl[5];
    float* C[5];
};

#define AHI 0
#define ALO 8192
#define BHI 16384
#define BLO 24576

#define GL2LDS(g, s) __builtin_amdgcn_global_load_lds( \
    (const __attribute__((address_space(1))) void*)(g), \
    (__attribute__((address_space(3))) void*)(s), 16, 0, 0)

__launch_bounds__(256, 3)
__global__ void gemm_split(GemmArgs p, int fused) {
    __shared__ __attribute__((aligned(16))) char lds[32768];
    const int tid = threadIdx.x;
    const int bx = blockIdx.x, by = blockIdx.y;

    int sel, nloc, ldc;
    if (fused) {
        if (bx < 64) { sel = bx >> 4; nloc = (bx & 15) * 128; ldc = 2048; }
        else         { sel = 4;       nloc = 0;               ldc = 128;  }
    } else { sel = 0; nloc = bx * 128; ldc = 2048; }

    const unsigned short* Asrc_h = p.Ah + (size_t)(by * 128) * 2048;
    const unsigned short* Asrc_l = p.Al + (size_t)(by * 128) * 2048;
    const unsigned short* Bsrc_h = p.Bh[sel] + (size_t)nloc * 2048;
    const unsigned short* Bsrc_l = p.Bl[sel] + (size_t)nloc * 2048;

    const int r0 = tid >> 2, ps0 = tid & 3;
    const int r1 = (tid + 256) >> 2, ps1 = tid & 3;
    const size_t ga0 = (size_t)r0 * 2048 + (size_t)((ps0 ^ ((r0 >> 1) & 3)) * 8);
    const size_t ga1 = (size_t)r1 * 2048 + (size_t)((ps1 ^ ((r1 >> 1) & 3)) * 8);
    const int lb0 = (tid & 192) * 16;
    const int lb1 = (256 + (tid & 192)) * 16;

    const int lane = tid & 63;
    const int l15 = lane & 15, kgrp = lane >> 4;
    const int w = tid >> 6, wm = w >> 1, wn = w & 1;
    const int swz = kgrp ^ ((l15 >> 1) & 3);
    const int fro = l15 * 64 + swz * 16;
    const int aoff = wm * 4096, boff = wn * 4096;

    f32x4 acc[4][4];
#pragma unroll
    for (int i = 0; i < 4; ++i)
#pragma unroll
        for (int j = 0; j < 4; ++j) acc[i][j] = (f32x4){0.f, 0.f, 0.f, 0.f};

    for (int k0 = 0; k0 < 2048; k0 += 32) {
        __syncthreads();
        GL2LDS(Asrc_h + k0 + ga0, lds + AHI + lb0);
        GL2LDS(Asrc_h + k0 + ga1, lds + AHI + lb1);
        GL2LDS(Asrc_l + k0 + ga0, lds + ALO + lb0);
        GL2LDS(Asrc_l + k0 + ga1, lds + ALO + lb1);
        GL2LDS(Bsrc_h + k0 + ga0, lds + BHI + lb0);
        GL2LDS(Bsrc_h + k0 + ga1, lds + BHI + lb1);
        GL2LDS(Bsrc_l + k0 + ga0, lds + BLO + lb0);
        GL2LDS(Bsrc_l + k0 + ga1, lds + BLO + lb1);
        __syncthreads();

        bf16x8 ah[4], al4[4], bh4[4], bl4[4];
#pragma unroll
        for (int f = 0; f < 4; ++f) {
            ah[f]  = *(const bf16x8*)(lds + AHI + aoff + f * 1024 + fro);
            al4[f] = *(const bf16x8*)(lds + ALO + aoff + f * 1024 + fro);
            bh4[f] = *(const bf16x8*)(lds + BHI + boff + f * 1024 + fro);
            bl4[f] = *(const bf16x8*)(lds + BLO + boff + f * 1024 + fro);
        }
#pragma unroll
        for (int i = 0; i < 4; ++i)
#pragma unroll
            for (int j = 0; j < 4; ++j) {
                acc[i][j] = __builtin_amdgcn_mfma_f32_16x16x32_bf16(ah[i],  bh4[j], acc[i][j], 0, 0, 0);
                acc[i][j] = __builtin_amdgcn_mfma_f32_16x16x32_bf16(ah[i],  bl4[j], acc[i][j], 0, 0, 0);
                acc[i][j] = __builtin_amdgcn_mfma_f32_16x16x32_bf16(al4[i], bh4[j], acc[i][j], 0, 0, 0);
            }
    }

    float* cb = p.C[sel];
    const int m0 = by * 128 + wm * 64 + kgrp * 4;
    const int n0 = nloc + wn * 64 + l15;
#pragma unroll
    for (int i = 0; i < 4; ++i)
#pragma unroll
        for (int t = 0; t < 4; ++t) {
            float* cp = cb + (size_t)(m0 + i * 16 + t) * ldc + n0;
#pragma unroll
            for (int j = 0; j < 4; ++j) cp[j * 16] = acc[i][j][t];
        }
}

// ---------------------------------------------------------------------------
// Generic fp32 SGEMM (kept for g1@Wf2 and as full fallback path).
// ---------------------------------------------------------------------------
#define GBM 128
#define GBN 128
#define GBK 16

__launch_bounds__(256)
__global__ void sgemm128(const float* __restrict__ A, const float* __restrict__ B,
                         float* __restrict__ C, int M, int N, int K) {
    __shared__ float As[GBK][GBM + 4];
    __shared__ float Bs[GBK][GBN + 4];

    const int tid = threadIdx.x;
    const int bm = blockIdx.y * GBM;
    const int bn = blockIdx.x * GBN;

    const int arow = tid >> 2;
    const int acol = (tid & 3) << 2;
    const int brow = tid >> 5;
    const int bcol = (tid & 31) << 2;
    const int ty = tid >> 4;
    const int tx = tid & 15;

    float acc[8][8];
#pragma unroll
    for (int i = 0; i < 8; ++i)
#pragma unroll
        for (int j = 0; j < 8; ++j) acc[i][j] = 0.f;

    for (int k0 = 0; k0 < K; k0 += GBK) {
#pragma unroll
        for (int r = 0; r < 2; ++r) {
            const int m = arow + r * 64;
            const float4 av = *(const float4*)(A + (size_t)(bm + m) * K + k0 + acol);
            As[acol + 0][m] = av.x;
            As[acol + 1][m] = av.y;
            As[acol + 2][m] = av.z;
            As[acol + 3][m] = av.w;
        }
#pragma unroll
        for (int r = 0; r < 2; ++r) {
            const int kk = brow + r * 8;
            *(float4*)(&Bs[kk][bcol]) =
                *(const float4*)(B + (size_t)(k0 + kk) * N + bn + bcol);
        }
        __syncthreads();

#pragma unroll
        for (int kk = 0; kk < GBK; ++kk) {
            float a[8], bf[8];
#pragma unroll
            for (int i = 0; i < 8; ++i) a[i] = As[kk][ty * 8 + i];
#pragma unroll
            for (int j = 0; j < 8; ++j) bf[j] = Bs[kk][tx * 8 + j];
#pragma unroll
            for (int i = 0; i < 8; ++i)
#pragma unroll
                for (int j = 0; j < 8; ++j)
                    acc[i][j] = fmaf(a[i], bf[j], acc[i][j]);
        }
        __syncthreads();
    }

#pragma unroll
    for (int i = 0; i < 8; ++i) {
        float* cp = C + (size_t)(bm + ty * 8 + i) * N + bn + tx * 8;
        *(float4*)(cp + 0) = make_float4(acc[i][0], acc[i][1], acc[i][2], acc[i][3]);
        *(float4*)(cp + 4) = make_float4(acc[i][4], acc[i][5], acc[i][6], acc[i][7]);
    }
}

// ---------------------------------------------------------------------------
// Causal depthwise conv1d (K=4) + silu, optional per-head l2norm * scale.
// 3 tensors (q,k,v) in one launch; blockIdx.y selects.
// ---------------------------------------------------------------------------
struct ConvArgs {
    const float* pre[3]; const float* w[3]; float* out[3];
    float scale[3]; int do_norm[3];
};
__global__ void conv_silu_norm3(ConvArgs p) {
    const int z = blockIdx.y;
    const float* __restrict__ pre = p.pre[z];
    const float* __restrict__ wv = p.w[z];
    float* __restrict__ out = p.out[z];
    const float scale = p.scale[z];
    const int do_norm = p.do_norm[z];

    const int blk = blockIdx.x;
    const int h = blk & 15;
    const int bt = blk >> 4;
    const int t = bt & (TT - 1);
    const int b = bt >> 10;
    const int dk = threadIdx.x;
    const int c = h * 128 + dk;

    const size_t off = ((size_t)(b * TT + t)) * DD + c;
    float acc = 0.f;
#pragma unroll
    for (int j = 0; j < 4; ++j) {
        const int tt = t - 3 + j;
        const float x = (tt >= 0) ? pre[off + (size_t)(j - 3) * DD] : 0.f;
        acc = fmaf(x, wv[c * 4 + j], acc);
    }
    float x = acc / (1.f + expf(-acc));  // silu

    if (do_norm) {
        float ss = x * x;
#pragma unroll
        for (int s = 1; s < 64; s <<= 1) ss += __shfl_xor(ss, s, 64);
        __shared__ float red[2];
        if ((threadIdx.x & 63) == 0) red[threadIdx.x >> 6] = ss;
        __syncthreads();
        const float tot = red[0] + red[1];
        x = x * rsqrtf(tot + 1e-6f) * scale;
    }
    out[off] = x;
}

// fallback single-tensor conv
__global__ void conv_silu_norm(const float* __restrict__ pre, const float* __restrict__ w,
                               float* __restrict__ out, float scale, int do_norm) {
    const int blk = blockIdx.x;
    const int h = blk & 15;
    const int bt = blk >> 4;
    const int t = bt & (TT - 1);
    const int b = bt >> 10;
    const int dk = threadIdx.x;
    const int c = h * 128 + dk;

    const size_t off = ((size_t)(b * TT + t)) * DD + c;
    float acc = 0.f;
#pragma unroll
    for (int j = 0; j < 4; ++j) {
        const int tt = t - 3 + j;
        const float x = (tt >= 0) ? pre[off + (size_t)(j - 3) * DD] : 0.f;
        acc = fmaf(x, w[c * 4 + j], acc);
    }
    float x = acc / (1.f + expf(-acc));  // silu

    if (do_norm) {
        float ss = x * x;
#pragma unroll
        for (int s = 1; s < 64; s <<= 1) ss += __shfl_xor(ss, s, 64);
        __shared__ float red[2];
        if ((threadIdx.x & 63) == 0) red[threadIdx.x >> 6] = ss;
        __syncthreads();
        const float tot = red[0] + red[1];
        x = x * rsqrtf(tot + 1e-6f) * scale;
    }
    out[off] = x;
}

// ---------------------------------------------------------------------------
__global__ void beta_kernel(const float* __restrict__ hid, const float* __restrict__ Wb,
                            float* __restrict__ beta) {
    const int m = blockIdx.x;
    const int t = threadIdx.x;
    const int h = t & 15;
    const int sl = t >> 4;

    const float* hp = hid + (size_t)m * DD + sl * 128;
    const float* wp = Wb + (size_t)sl * 128 * HH + h;
    float p = 0.f;
#pragma unroll 8
    for (int i = 0; i < 128; ++i) p = fmaf(hp[i], wp[i * HH], p);

    __shared__ float red[256];
    red[t] = p;
    __syncthreads();
    if (t < HH) {
        float s = 0.f;
#pragma unroll
        for (int i = 0; i < 16; ++i) s += red[i * 16 + t];
        beta[(size_t)m * HH + t] = 1.f / (1.f + expf(-s));
    }
}

// ---------------------------------------------------------------------------
// decay (fallback layout [b,t,h,g])
// ---------------------------------------------------------------------------
__global__ void decay_kernel(const float* __restrict__ g2, const float* __restrict__ A_log,
                             const float* __restrict__ dt_bias, float* __restrict__ decay) {
    const int idx = blockIdx.x * 256 + threadIdx.x;
    const int g = idx & (NG - 1);
    const int h = (idx >> 3) & (HH - 1);
    const float x = g2[idx] + dt_bias[h * NG + g];
    const float sp = (x > 20.f) ? x : log1pf(expf(x));
    decay[idx] = expf(-expf(A_log[h]) * sp);
}

// ---------------------------------------------------------------------------
// decay, t-tiled output [bh][tblk][g][8]
// ---------------------------------------------------------------------------
__global__ void decay_kernel_t(const float* __restrict__ g2, const float* __restrict__ A_log,
                               const float* __restrict__ dt_bias, float* __restrict__ dtr) {
    const int idx = blockIdx.x * 256 + threadIdx.x;   // (b,t,h,g)
    const int g = idx & 7, h = (idx >> 3) & 15;
    const int t = (idx >> 7) & 1023, b = idx >> 17;
    const float x = g2[idx] + dt_bias[h * NG + g];
    const float sp = (x > 20.f) ? x : log1pf(expf(x));
    const float d = expf(-expf(A_log[h]) * sp);
    const int bh = b * 16 + h, tblk = t >> 3, tj = t & 7;
    dtr[((size_t)(bh * 128 + tblk)) * 64 + g * 8 + tj] = d;
}

// ---------------------------------------------------------------------------
// Pair-coupling precompute: c[bh][tblk][j] = sum_c k[c][2j+1]*d[g(c)][2j+1]*k[c][2j]
// ---------------------------------------------------------------------------
__launch_bounds__(256, 4)
__global__ void pairc_kernel(const float* __restrict__ kt, const float* __restrict__ dtr,
                             float* __restrict__ cpair) {
    const int gw = blockIdx.x * 4 + (threadIdx.x >> 6);
    const int bh = gw >> 7, tblk = gw & 127;
    const int lane = threadIdx.x & 63;

    const float* kp = kt + (size_t)bh * 131072 + (size_t)tblk * 1024 + (size_t)(2 * lane) * 8;
    const float* dp = dtr + (size_t)bh * 8192 + (size_t)tblk * 64 + (size_t)(lane >> 3) * 8;

    float4 K0a = *(const float4*)(kp);      // ch 2l, t0..3
    float4 K0b = *(const float4*)(kp + 4);  // ch 2l, t4..7
    float4 K1a = *(const float4*)(kp + 8);  // ch 2l+1, t0..3
    float4 K1b = *(const float4*)(kp + 12);
    float4 Da = *(const float4*)(dp);       // d t0..3 (group of both channels)
    float4 Db = *(const float4*)(dp + 4);

    float c0 = K0a.y * Da.y * K0a.x + K1a.y * Da.y * K1a.x;
    float c1 = K0a.w * Da.w * K0a.z + K1a.w * Da.w * K1a.z;
    float c2 = K0b.y * Db.y * K0b.x + K1b.y * Db.y * K1b.x;
    float c3 = K0b.w * Db.w * K0b.z + K1b.w * Db.w * K1b.z;

    c0 = dpp_sum64(c0);
    c1 = dpp_sum64(c1);
    c2 = dpp_sum64(c2);
    c3 = dpp_sum64(c3);

    if (lane == 63) {
        float4 out = make_float4(c0, c1, c2, c3);
        *(float4*)(cpair + (size_t)bh * 512 + (size_t)tblk * 4) = out;
    }
}

// ---------------------------------------------------------------------------
// Gated delta-rule recurrence, t-tiled inputs, PAIRED steps (round-11 proven).
// ---------------------------------------------------------------------------
#define CLD(K, Q, D, V, Bf, C4, T0) do {                                       \
    const float* kpt = kp0 + (size_t)(T0) * 128;                               \
    const float* qpt = qp0 + (size_t)(T0) * 128;                               \
    K[0] = *(const float4*)(kpt);      K[1] = *(const float4*)(kpt + 4);       \
    K[2] = *(const float4*)(kpt + 8);  K[3] = *(const float4*)(kpt + 12);      \
    Q[0] = *(const float4*)(qpt);      Q[1] = *(const float4*)(qpt + 4);       \
    Q[2] = *(const float4*)(qpt + 8);  Q[3] = *(const float4*)(qpt + 12);      \
    D[0] = *(const float4*)(dp + (size_t)(T0) * 8);                            \
    D[1] = *(const float4*)(dp + (size_t)(T0) * 8 + 4);                        \
    C4 = *(const float4*)(cp + (size_t)(T0) / 2);                              \
    V = vp[(size_t)(T0) * 128];                                                \
    Bf = bp[(size_t)(T0) * 16];                                                \
} while (0)

#define CSTEP(K, Q, D, V, Bf, C4, T0) do {                                     \
    _Pragma("unroll")                                                          \
    for (int jp = 0; jp < 4; ++jp) {                                           \
        const int j0 = 2 * jp, j1 = 2 * jp + 1;                                \
        const float d0 = f4get(D[j0 >> 2], j0 & 3);                            \
        const float d1 = f4get(D[j1 >> 2], j1 & 3);                            \
        const float k00 = f4get(K[j0 >> 2], j0 & 3);                           \
        const float k01 = f4get(K[2 + (j0 >> 2)], j0 & 3);                     \
        const float k10 = f4get(K[j1 >> 2], j1 & 3);                           \
        const float k11 = f4get(K[2 + (j1 >> 2)], j1 & 3);                     \
        const float t10 = S0 * d0, t11 = S1 * d0;                              \
        const float t20 = t10 * d1, t21 = t11 * d1;                            \
        float e1 = fmaf(k00, t10, k01 * t11);                                  \
        float e2 = fmaf(k10, t20, k11 * t21);                                  \
        e1 = dpp_sum64(e1);                                                    \
        e2 = dpp_sum64(e2);                                                    \
        const float err1 = readlanef(e1, 63);                                  \
        const float v0 = readlanef(V, j0), b0 = readlanef(Bf, j0);             \
        const float dl1 = b0 * (v0 - err1);                                    \
        const float cj = f4get(C4, jp);                                        \
        const float err2 = fmaf(cj, dl1, readlanef(e2, 63));                   \
        const float v1 = readlanef(V, j1), b1 = readlanef(Bf, j1);             \
        const float dl2 = b1 * (v1 - err2);                                    \
        const float s10 = fmaf(k00, dl1, t10);                                 \
        const float s11 = fmaf(k01, dl1, t11);                                 \
        S0 = fmaf(k10, dl2, d1 * s10);                                         \
        S1 = fmaf(k11, dl2, d1 * s11);                                         \
        const float q00 = f4get(Q[j0 >> 2], j0 & 3);                           \
        const float q01 = f4get(Q[2 + (j0 >> 2)], j0 & 3);                     \
        const float q10 = f4get(Q[j1 >> 2], j1 & 3);                           \
        const float q11 = f4get(Q[2 + (j1 >> 2)], j1 & 3);                     \
        float o1 = fmaf(q00, s10, q01 * s11);                                  \
        float o2 = fmaf(q10, S0, q11 * S1);                                    \
        o1 = dpp_sum64(o1);                                                    \
        o2 = dpp_sum64(o2);                                                    \
        if (lane == 63) {                                                      \
            o[obase + (size_t)((T0) + j0) * 2048 + vi] = o1;                   \
            o[obase + (size_t)((T0) + j1) * 2048 + vi] = o2;                   \
        }                                                                      \
    }                                                                          \
} while (0)

__launch_bounds__(256, 4)
__global__ void recur_kernel_t(const float* __restrict__ qt, const float* __restrict__ kt,
                               const float* __restrict__ vt, const float* __restrict__ dtr,
                               const float* __restrict__ beta, const float* __restrict__ cpair,
                               float* __restrict__ o) {
    const int bid = blockIdx.x;
    const int xcd = bid & 7, idx = bid >> 3;
    const int bh = xcd * 4 + (idx >> 5);   // all 32 v-blocks of a bh share an XCD
    const int vblk = idx & 31;
    const int b = bh >> 4, h = bh & 15;
    const int w = threadIdx.x >> 6;
    const int lane = threadIdx.x & 63;
    const int jl = lane & 7;
    const int vi = vblk * 4 + w;

    const float* kp0 = kt + (size_t)bh * 131072 + (size_t)(2 * lane) * 8;
    const float* qp0 = qt + (size_t)bh * 131072 + (size_t)(2 * lane) * 8;
    const float* vp  = vt + (size_t)bh * 131072 + (size_t)vi * 8 + jl;
    const float* dp  = dtr + (size_t)bh * 8192 + (size_t)(lane >> 3) * 8;
    const float* cp  = cpair + (size_t)bh * 512;
    const float* bp  = beta + ((size_t)b * 1024 + jl) * HH + h;
    const size_t obase = ((size_t)b * 1024 * HH + h) * 128;

    float S0 = 0.f, S1 = 0.f;
    float4 Ka[4], Qa[4], Da[2], Kb[4], Qb[4], Db[2], Ca, Cb;
    float Va, Bfa, Vb, Bfb;

    CLD(Ka, Qa, Da, Va, Bfa, Ca, 0);

#pragma unroll 1
    for (int t0 = 0; t0 < TT; t0 += 16) {
        CLD(Kb, Qb, Db, Vb, Bfb, Cb, t0 + 8);
        CSTEP(Ka, Qa, Da, Va, Bfa, Ca, t0);
        const int tA = (t0 + 16 < TT) ? (t0 + 16) : t0;  // clamped dummy at end
        CLD(Ka, Qa, Da, Va, Bfa, Ca, tA);
        CSTEP(Kb, Qb, Db, Vb, Bfb, Cb, t0 + 8);
    }
}

// ---------------------------------------------------------------------------
// Old-layout recurrence (fallback path only).
// ---------------------------------------------------------------------------
__launch_bounds__(256, 4)
__global__ void recur_kernel(const float* __restrict__ q, const float* __restrict__ k,
                             const float* __restrict__ vv, const float* __restrict__ decay,
                             const float* __restrict__ beta, float* __restrict__ o) {
    const int blk = blockIdx.x;
    const int vblk = blk & 31;
    const int bh = blk >> 5;
    const int b = bh >> 4, h = bh & 15;
    const int w = threadIdx.x >> 6;
    const int lane = threadIdx.x & 63;
    const int vi = vblk * 4 + w;

    float S0 = 0.f, S1 = 0.f;
    const size_t strideT = (size_t)HH * DV;
    const size_t strideT2 = strideT >> 1;
    const size_t base = ((size_t)b * TT * HH + h) * DV;

    const float2* kp = (const float2*)(k + base) + lane;
    const float2* qp = (const float2*)(q + base) + lane;
    const float* vp = vv + base + vi;
    const float* bp = beta + (size_t)b * TT * HH + h;
    const float* dp = decay + ((size_t)b * TT * HH + h) * NG + (lane >> 3);

    float2 kv = kp[0], qv = qp[0];
    float vtv = vp[0], bt = bp[0], dt = dp[0];

    for (int t = 0; t < TT; ++t) {
        const float2 kc = kv, qc = qv;
        const float vc = vtv, bc = bt, dc = dt;

        const int tn = (t + 1 < TT) ? (t + 1) : t;
        kv = kp[(size_t)tn * strideT2];
        qv = qp[(size_t)tn * strideT2];
        vtv = vp[(size_t)tn * strideT];
        bt = bp[(size_t)tn * HH];
        dt = dp[(size_t)tn * HH * NG];

        S0 *= dc;
        S1 *= dc;
        float e = fmaf(kc.x, S0, kc.y * S1);
        e = dpp_sum64(e);
        const float err = readlanef(e, 63);
        const float delta = bc * (vc - err);
        S0 = fmaf(kc.x, delta, S0);
        S1 = fmaf(kc.y, delta, S1);
        float oo = fmaf(qc.x, S0, qc.y * S1);
        oo = dpp_sum64(oo);
        if (lane == 63) o[base + (size_t)t * strideT + vi] = oo;
    }
}

// ---------------------------------------------------------------------------
// Gated RMSNorm -> fp32 y (fallback path)
// ---------------------------------------------------------------------------
__global__ void gated_rmsnorm(const float* __restrict__ o,
                              const float* __restrict__ gpre, const float* __restrict__ bg,
                              const float* __restrict__ norm_w, float* __restrict__ y) {
    const int blk = blockIdx.x;
    const int h = blk & 15;
    const int dv = threadIdx.x;
    const size_t off = (size_t)blk * DV + dv;

    const float ov = o[off];
    const float g = gpre[off] + bg[h * 128 + dv];
    const float yv = ov * (g / (1.f + expf(-g)));

    float ss = yv * yv;
#pragma unroll
    for (int s = 1; s < 64; s <<= 1) ss += __shfl_xor(ss, s, 64);
    __shared__ float red[2];
    if ((threadIdx.x & 63) == 0) red[threadIdx.x >> 6] = ss;
    __syncthreads();
    const float mean = (red[0] + red[1]) * (1.f / 128.f);
    y[off] = yv * rsqrtf(mean + 1e-5f) * norm_w[dv];
}

// ---------------------------------------------------------------------------
// Gated RMSNorm -> bf16 hi/lo split y
// ---------------------------------------------------------------------------
__global__ void gated_rmsnorm_split(const float* __restrict__ o,
                                    const float* __restrict__ gpre, const float* __restrict__ bg,
                                    const float* __restrict__ norm_w,
                                    unsigned short* __restrict__ yh,
                                    unsigned short* __restrict__ yl) {
    const int blk = blockIdx.x;
    const int h = blk & 15;
    const int dv = threadIdx.x;
    const size_t off = (size_t)blk * DV + dv;

    const float ov = o[off];
    const float g = gpre[off] + bg[h * 128 + dv];
    const float yv = ov * (g / (1.f + expf(-g)));

    float ss = yv * yv;
#pragma unroll
    for (int s = 1; s < 64; s <<= 1) ss += __shfl_xor(ss, s, 64);
    __shared__ float red[2];
    if ((threadIdx.x & 63) == 0) red[threadIdx.x >> 6] = ss;
    __syncthreads();
    const float mean = (red[0] + red[1]) * (1.f / 128.f);
    const float y = yv * rsqrtf(mean + 1e-5f) * norm_w[dv];
    unsigned short hh, ll;
    bsplit(y, hh, ll);
    yh[off] = hh;
    yl[off] = ll;
}

// ---------------------------------------------------------------------------
extern "C" void kernel_launch(void* const* d_in, const int* in_sizes, int n_in,
                              void* d_out, int out_size, void* d_ws, size_t ws_size,
                              hipStream_t stream) {
    const float* hid    = (const float*)d_in[0];
    const float* Wq     = (const float*)d_in[1];
    const float* Wk     = (const float*)d_in[2];
    const float* Wv     = (const float*)d_in[3];
    const float* conv_q = (const float*)d_in[4];
    const float* conv_k = (const float*)d_in[5];
    const float* conv_v = (const float*)d_in[6];
    const float* Wf1    = (const float*)d_in[7];
    const float* Wf2    = (const float*)d_in[8];
    const float* Wb     = (const float*)d_in[9];
    const float* A_log  = (const float*)d_in[10];
    const float* dt_bias= (const float*)d_in[11];
    const float* Wg     = (const float*)d_in[12];
    const float* bg     = (const float*)d_in[13];
    const float* norm_w = (const float*)d_in[14];
    const float* Wo     = (const float*)d_in[15];
    float* out = (float*)d_out;

    const size_t N1  = (size_t)2048 * 2048;   // 4,194,304 elems
    const size_t N1B = N1 * 4;                 // bytes of one fp32 matrix
    const int M = BB * TT;                     // 2048

    const size_t NEED_NEW = 9 * N1B + 4390912; // +64KB cpair

    if (ws_size >= NEED_NEW) {
        // ---------------- MFMA split-precision path ----------------
        char* W = (char*)d_ws;
        // region A [0, N1B): hid split; later o (recurrence output)
        unsigned short* hidh = (unsigned short*)W;
        unsigned short* hidl = hidh + N1;
        float* o = (float*)W;
        // region B [N1B, 5*N1B): 8 transposed-weight bf16 arrays;
        // later qn/kn/vn (3*N1B) overlay Wq/Wk/Wv-transposes.
        char* RB = W + N1B;
        unsigned short* Wqth = (unsigned short*)RB;
        unsigned short* Wqtl = Wqth + N1;
        unsigned short* Wkth = Wqtl + N1;
        unsigned short* Wktl = Wkth + N1;
        unsigned short* Wvth = Wktl + N1;
        unsigned short* Wvtl = Wvth + N1;
        unsigned short* Wgth = Wvtl + N1;
        unsigned short* Wgtl = Wgth + N1;
        float* qn = (float*)RB;
        float* kn = qn + N1;
        float* vn = kn + N1;
        // region C [5*N1B, 9*N1B): q/k/v/g pre-activations.
        //   qpre: conv-q input -> qn_t (recur) -> Woth/Wotl (out-gemm)
        //   kpre: conv-k input -> kn_t (recur) -> yh/yl (rmsnorm out)
        //   vpre: conv-v input -> vn_t (recur)
        //   gpre: live until rmsnorm
        char* RC = W + 5 * N1B;
        float* qpre = (float*)RC;
        float* kpre = qpre + N1;
        float* vpre = kpre + N1;
        float* gpre = vpre + N1;
        float* qn_t = qpre;
        float* kn_t = kpre;
        float* vn_t = vpre;
        unsigned short* Woth = (unsigned short*)RC;
        unsigned short* Wotl = Woth + N1;
        unsigned short* yh = (unsigned short*)(RC + N1B);
        unsigned short* yl = yh + N1;
        // region D [9*N1B, ...): small buffers
        char* RD = W + 9 * N1B;
        float* g1b   = (float*)RD;                    // 262144
        float* g2b   = g1b + 262144;                  // 262144
        float* betab = g2b + 262144;                  // 32768
        float* decayb= betab + 32768;                 // 262144 (tiled)
        unsigned short* wf1th = (unsigned short*)(decayb + 262144);
        unsigned short* wf1tl = wf1th + 262144;
        float* cpb   = (float*)(wf1tl + 262144);      // 16384

        // 1. splits / transposes (4 big weights in ONE launch)
        split_mat<<<1024, 256, 0, stream>>>(hid, hidh, hidl);
        TS4 ts;
        ts.in[0] = Wq; ts.oh[0] = Wqth; ts.ol[0] = Wqtl;
        ts.in[1] = Wk; ts.oh[1] = Wkth; ts.ol[1] = Wktl;
        ts.in[2] = Wv; ts.oh[2] = Wvth; ts.ol[2] = Wvtl;
        ts.in[3] = Wg; ts.oh[3] = Wgth; ts.ol[3] = Wgtl;
        transpose_split4<<<dim3(32, 32, 4), 256, 0, stream>>>(ts);
        transpose_split<<<dim3(2, 32), 256, 0, stream>>>(Wf1, wf1th, wf1tl, 128, 2048);

        // 2. fused input projections (q,k,v,g, f1)
        GemmArgs fa;
        fa.Ah = hidh; fa.Al = hidl;
        fa.Bh[0] = Wqth; fa.Bl[0] = Wqtl; fa.C[0] = qpre;
        fa.Bh[1] = Wkth; fa.Bl[1] = Wktl; fa.C[1] = kpre;
        fa.Bh[2] = Wvth; fa.Bl[2] = Wvtl; fa.C[2] = vpre;
        fa.Bh[3] = Wgth; fa.Bl[3] = Wgtl; fa.C[3] = gpre;
        fa.Bh[4] = wf1th; fa.Bl[4] = wf1tl; fa.C[4] = g1b;
        gemm_split<<<dim3(65, 16), 256, 0, stream>>>(fa, 1);

        // 3. beta, g2, decay (t-tiled)
        beta_kernel<<<M, 256, 0, stream>>>(hid, Wb, betab);
        sgemm128<<<dim3(1, 16), 256, 0, stream>>>(g1b, Wf2, g2b, M, 128, 128);
        decay_kernel_t<<<(M * HH * NG) / 256, 256, 0, stream>>>(g2b, A_log, dt_bias, decayb);

        // 4. conv + silu (+ l2norm), all three tensors in one launch
        ConvArgs ca;
        ca.pre[0] = qpre; ca.w[0] = conv_q; ca.out[0] = qn; ca.scale[0] = SCALE_Q; ca.do_norm[0] = 1;
        ca.pre[1] = kpre; ca.w[1] = conv_k; ca.out[1] = kn; ca.scale[1] = 1.f;     ca.do_norm[1] = 1;
        ca.pre[2] = vpre; ca.w[2] = conv_v; ca.out[2] = vn; ca.scale[2] = 1.f;     ca.do_norm[2] = 0;
        conv_silu_norm3<<<dim3(M * HH, 3), 128, 0, stream>>>(ca);

        // 5. t-tile transpose, all three in one launch
        T3 tt;
        tt.in[0] = qn; tt.out[0] = qn_t;
        tt.in[1] = kn; tt.out[1] = kn_t;
        tt.in[2] = vn; tt.out[2] = vn_t;
        transpose_tile3<<<dim3(4096, 3), 256, 0, stream>>>(tt);

        // 6. pair coefficients + recurrence (o over dead hid split)
        pairc_kernel<<<1024, 256, 0, stream>>>(kn_t, decayb, cpb);
        recur_kernel_t<<<BB * HH * (DV / 4), 256, 0, stream>>>(qn_t, kn_t, vn_t, decayb, betab, cpb, o);

        // 7. transpose Wo (over dead qn_t)
        transpose_split<<<dim3(32, 32), 256, 0, stream>>>(Wo, Woth, Wotl, 2048, 2048);

        // 8. gated rmsnorm -> y split (over dead kn_t)
        gated_rmsnorm_split<<<M * HH, 128, 0, stream>>>(o, gpre, bg, norm_w, yh, yl);

        // 9. output projection
        GemmArgs oa;
        oa.Ah = yh; oa.Al = yl;
        for (int i = 0; i < 5; ++i) { oa.Bh[i] = Woth; oa.Bl[i] = Wotl; oa.C[i] = out; }
        gemm_split<<<dim3(16, 16), 256, 0, stream>>>(oa, 0);
    } else {
        // ---------------- fallback: fp32 path (round-2 proven) ----------------
        float* ws = (float*)d_ws;
        float* qpre = ws + 0 * N1;
        float* kpre = ws + 1 * N1;
        float* vpre = ws + 2 * N1;
        float* gpre = ws + 3 * N1;
        float* qn   = ws + 4 * N1;
        float* kn   = ws + 5 * N1;
        float* vn   = ws + 6 * N1;
        float* g1b  = ws + 7 * N1;
        float* g2b  = g1b + (size_t)BB * TT * DV;
        float* betab= g2b + (size_t)BB * TT * HH * NG;
        float* decayb = betab + (size_t)BB * TT * HH;
        float* o = qpre;
        float* y = vpre;

        sgemm128<<<dim3(16, 16), 256, 0, stream>>>(hid, Wq, qpre, M, 2048, 2048);
        sgemm128<<<dim3(16, 16), 256, 0, stream>>>(hid, Wk, kpre, M, 2048, 2048);
        sgemm128<<<dim3(16, 16), 256, 0, stream>>>(hid, Wv, vpre, M, 2048, 2048);
        sgemm128<<<dim3(16, 16), 256, 0, stream>>>(hid, Wg, gpre, M, 2048, 2048);
        sgemm128<<<dim3(1, 16), 256, 0, stream>>>(hid, Wf1, g1b, M, 128, 2048);
        sgemm128<<<dim3(1, 16), 256, 0, stream>>>(g1b, Wf2, g2b, M, 128, 128);
        beta_kernel<<<M, 256, 0, stream>>>(hid, Wb, betab);

        conv_silu_norm<<<M * HH, 128, 0, stream>>>(qpre, conv_q, qn, SCALE_Q, 1);
        conv_silu_norm<<<M * HH, 128, 0, stream>>>(kpre, conv_k, kn, 1.f, 1);
        conv_silu_norm<<<M * HH, 128, 0, stream>>>(vpre, conv_v, vn, 1.f, 0);

        decay_kernel<<<(M * HH * NG) / 256, 256, 0, stream>>>(g2b, A_log, dt_bias, decayb);

        recur_kernel<<<BB * HH * (DV / 4), 256, 0, stream>>>(qn, kn, vn, decayb, betab, o);

        gated_rmsnorm<<<M * HH, 128, 0, stream>>>(o, gpre, bg, norm_w, y);

        sgemm128<<<dim3(16, 16), 256, 0, stream>>>(y, Wo, out, M, 2048, 2048);
    }
}

// Round 13
// 831.163 us; speedup vs baseline: 1.2415x; 1.0189x over previous
//
#include <hip/hip_runtime.h>
#include <hip/hip_bf16.h>
#include <math.h>

// Problem constants (fixed by setup_inputs)
#define BB 2
#define TT 1024
#define DD 2048
#define HH 16
#define DK 128
#define DV 128
#define NG 8
#define GG 16
#define SCALE_Q 0.08838834764831845f  // 128^-0.5

typedef __attribute__((ext_vector_type(8))) short bf16x8;
typedef __attribute__((ext_vector_type(4))) float f32x4;

#define MFMA16(a, b, c) __builtin_amdgcn_mfma_f32_16x16x32_bf16((a), (b), (c), 0, 0, 0)

// bf16 split helpers (RNE)
__device__ __forceinline__ unsigned short f2bf(float v) {
    unsigned u = __float_as_uint(v);
    return (unsigned short)((u + 0x7FFFu + ((u >> 16) & 1u)) >> 16);
}
__device__ __forceinline__ float bf2f(unsigned short h) {
    return __uint_as_float(((unsigned)h) << 16);
}
__device__ __forceinline__ void bsplit(float v, unsigned short& h, unsigned short& l) {
    h = f2bf(v);
    l = f2bf(v - bf2f(h));
}
__device__ __forceinline__ void split8arr(const float* v, bf16x8& hi, bf16x8& lo) {
#pragma unroll
    for (int j = 0; j < 8; ++j) {
        unsigned short h, l;
        bsplit(v[j], h, l);
        hi[j] = (short)h;
        lo[j] = (short)l;
    }
}

// ---------------------------------------------------------------------------
// DPP wave64 sum (fallback recurrence only).
// ---------------------------------------------------------------------------
__device__ __forceinline__ float dpp_sum64(float x) {
    x += __int_as_float(__builtin_amdgcn_update_dpp(0, __float_as_int(x), 0x111, 0xf, 0xf, true));
    x += __int_as_float(__builtin_amdgcn_update_dpp(0, __float_as_int(x), 0x112, 0xf, 0xf, true));
    x += __int_as_float(__builtin_amdgcn_update_dpp(0, __float_as_int(x), 0x114, 0xf, 0xf, true));
    x += __int_as_float(__builtin_amdgcn_update_dpp(0, __float_as_int(x), 0x118, 0xf, 0xf, true));
    x += __int_as_float(__builtin_amdgcn_update_dpp(0, __float_as_int(x), 0x142, 0xa, 0xf, false));
    x += __int_as_float(__builtin_amdgcn_update_dpp(0, __float_as_int(x), 0x143, 0xc, 0xf, false));
    return x;
}
__device__ __forceinline__ float readlanef(float x, int l) {
    return __int_as_float(__builtin_amdgcn_readlane(__float_as_int(x), l));
}

// ---------------------------------------------------------------------------
// split: fp32 [n] -> bf16 hi/lo
// ---------------------------------------------------------------------------
__global__ void split_mat(const float* __restrict__ in, unsigned short* __restrict__ oh,
                          unsigned short* __restrict__ ol) {
    const int i0 = (blockIdx.x * 256 + threadIdx.x) * 16;
#pragma unroll
    for (int r = 0; r < 4; ++r) {
        const float4 v = *(const float4*)(in + i0 + r * 4);
        unsigned short h0, l0, h1, l1, h2, l2, h3, l3;
        bsplit(v.x, h0, l0); bsplit(v.y, h1, l1);
        bsplit(v.z, h2, l2); bsplit(v.w, h3, l3);
        short4 hh; hh.x = (short)h0; hh.y = (short)h1; hh.z = (short)h2; hh.w = (short)h3;
        short4 ll; ll.x = (short)l0; ll.y = (short)l1; ll.z = (short)l2; ll.w = (short)l3;
        *(short4*)(oh + i0 + r * 4) = hh;
        *(short4*)(ol + i0 + r * 4) = ll;
    }
}

// ---------------------------------------------------------------------------
// transpose + split: in fp32 [Kin][Nin] -> out bf16 hi/lo [Nin][Kin]
// ---------------------------------------------------------------------------
__device__ __forceinline__ void tsplit_body(const float* __restrict__ in,
                                            unsigned short* __restrict__ oh,
                                            unsigned short* __restrict__ ol,
                                            int Nin, int Kin, int bx, int by, int tid) {
    __shared__ float t[64][65];
    const int c4 = (tid & 15) * 4, r0 = tid >> 4;
#pragma unroll
    for (int rep = 0; rep < 4; ++rep) {
        const int r = r0 + rep * 16;
        const float4 v = *(const float4*)(in + (size_t)(by * 64 + r) * Nin + bx * 64 + c4);
        t[r][c4] = v.x; t[r][c4 + 1] = v.y; t[r][c4 + 2] = v.z; t[r][c4 + 3] = v.w;
    }
    __syncthreads();
#pragma unroll
    for (int rep = 0; rep < 4; ++rep) {
        const int n = r0 + rep * 16;
        short4 hh, ll;
        unsigned short h, l;
        bsplit(t[c4 + 0][n], h, l); hh.x = (short)h; ll.x = (short)l;
        bsplit(t[c4 + 1][n], h, l); hh.y = (short)h; ll.y = (short)l;
        bsplit(t[c4 + 2][n], h, l); hh.z = (short)h; ll.z = (short)l;
        bsplit(t[c4 + 3][n], h, l); hh.w = (short)h; ll.w = (short)l;
        const size_t o = (size_t)(bx * 64 + n) * Kin + by * 64 + c4;
        *(short4*)(oh + o) = hh;
        *(short4*)(ol + o) = ll;
    }
}

__global__ void transpose_split(const float* __restrict__ in, unsigned short* __restrict__ oh,
                                unsigned short* __restrict__ ol, int Nin, int Kin) {
    tsplit_body(in, oh, ol, Nin, Kin, blockIdx.x, blockIdx.y, threadIdx.x);
}

struct TS4 { const float* in[4]; unsigned short* oh[4]; unsigned short* ol[4]; };
__global__ void transpose_split4(TS4 p) {
    const int z = blockIdx.z;
    tsplit_body(p.in[z], p.oh[z], p.ol[z], 2048, 2048, blockIdx.x, blockIdx.y, threadIdx.x);
}

// ---------------------------------------------------------------------------
// t-tile transpose x3: in [B][1024][2048] -> out tiled [bh][tblk][cl][8]
// ---------------------------------------------------------------------------
struct T3 { const float* in[3]; float* out[3]; };
__global__ void transpose_tile3(T3 p) {
    __shared__ float tl[8][128];
    const int z = blockIdx.y;
    const float* __restrict__ in = p.in[z];
    float* __restrict__ out = p.out[z];
    const int blk = blockIdx.x;
    const int bh = blk >> 7, tblk = blk & 127;
    const int b = bh >> 4, h = bh & 15;
    const int tid = threadIdx.x;

    const int tt = tid >> 5, c4 = (tid & 31) * 4;
    const float4 v = *(const float4*)(in + ((size_t)(b * 1024 + tblk * 8 + tt)) * 2048 + h * 128 + c4);
    tl[tt][c4] = v.x; tl[tt][c4 + 1] = v.y; tl[tt][c4 + 2] = v.z; tl[tt][c4 + 3] = v.w;
    __syncthreads();

    const int cl = tid >> 1, tj0 = (tid & 1) * 4;
    float4 w4;
    w4.x = tl[tj0 + 0][cl]; w4.y = tl[tj0 + 1][cl];
    w4.z = tl[tj0 + 2][cl]; w4.w = tl[tj0 + 3][cl];
    *(float4*)(out + ((size_t)blk * 128 + cl) * 8 + tj0) = w4;
}

// ---------------------------------------------------------------------------
// Split-precision bf16 MFMA GEMM (verified; occupancy 3 blocks/CU).
// ---------------------------------------------------------------------------
struct GemmArgs {
    const unsigned short* Ah; const unsigned short* Al;
    const unsigned short* Bh[5]; const unsigned short* Bl[5];
    float* C[5];
};

#define AHI 0
#define ALO 8192
#define BHI 16384
#define BLO 24576

#define GL2LDS(g, s) __builtin_amdgcn_global_load_lds( \
    (const __attribute__((address_space(1))) void*)(g), \
    (__attribute__((address_space(3))) void*)(s), 16, 0, 0)

__launch_bounds__(256, 3)
__global__ void gemm_split(GemmArgs p, int fused) {
    __shared__ __attribute__((aligned(16))) char lds[32768];
    const int tid = threadIdx.x;
    const int bx = blockIdx.x, by = blockIdx.y;

    int sel, nloc, ldc;
    if (fused) {
        if (bx < 64) { sel = bx >> 4; nloc = (bx & 15) * 128; ldc = 2048; }
        else         { sel = 4;       nloc = 0;               ldc = 128;  }
    } else { sel = 0; nloc = bx * 128; ldc = 2048; }

    const unsigned short* Asrc_h = p.Ah + (size_t)(by * 128) * 2048;
    const unsigned short* Asrc_l = p.Al + (size_t)(by * 128) * 2048;
    const unsigned short* Bsrc_h = p.Bh[sel] + (size_t)nloc * 2048;
    const unsigned short* Bsrc_l = p.Bl[sel] + (size_t)nloc * 2048;

    const int r0 = tid >> 2, ps0 = tid & 3;
    const int r1 = (tid + 256) >> 2, ps1 = tid & 3;
    const size_t ga0 = (size_t)r0 * 2048 + (size_t)((ps0 ^ ((r0 >> 1) & 3)) * 8);
    const size_t ga1 = (size_t)r1 * 2048 + (size_t)((ps1 ^ ((r1 >> 1) & 3)) * 8);
    const int lb0 = (tid & 192) * 16;
    const int lb1 = (256 + (tid & 192)) * 16;

    const int lane = tid & 63;
    const int l15 = lane & 15, kgrp = lane >> 4;
    const int w = tid >> 6, wm = w >> 1, wn = w & 1;
    const int swz = kgrp ^ ((l15 >> 1) & 3);
    const int fro = l15 * 64 + swz * 16;
    const int aoff = wm * 4096, boff = wn * 4096;

    f32x4 acc[4][4];
#pragma unroll
    for (int i = 0; i < 4; ++i)
#pragma unroll
        for (int j = 0; j < 4; ++j) acc[i][j] = (f32x4){0.f, 0.f, 0.f, 0.f};

    for (int k0 = 0; k0 < 2048; k0 += 32) {
        __syncthreads();
        GL2LDS(Asrc_h + k0 + ga0, lds + AHI + lb0);
        GL2LDS(Asrc_h + k0 + ga1, lds + AHI + lb1);
        GL2LDS(Asrc_l + k0 + ga0, lds + ALO + lb0);
        GL2LDS(Asrc_l + k0 + ga1, lds + ALO + lb1);
        GL2LDS(Bsrc_h + k0 + ga0, lds + BHI + lb0);
        GL2LDS(Bsrc_h + k0 + ga1, lds + BHI + lb1);
        GL2LDS(Bsrc_l + k0 + ga0, lds + BLO + lb0);
        GL2LDS(Bsrc_l + k0 + ga1, lds + BLO + lb1);
        __syncthreads();

        bf16x8 ah[4], al4[4], bh4[4], bl4[4];
#pragma unroll
        for (int f = 0; f < 4; ++f) {
            ah[f]  = *(const bf16x8*)(lds + AHI + aoff + f * 1024 + fro);
            al4[f] = *(const bf16x8*)(lds + ALO + aoff + f * 1024 + fro);
            bh4[f] = *(const bf16x8*)(lds + BHI + boff + f * 1024 + fro);
            bl4[f] = *(const bf16x8*)(lds + BLO + boff + f * 1024 + fro);
        }
#pragma unroll
        for (int i = 0; i < 4; ++i)
#pragma unroll
            for (int j = 0; j < 4; ++j) {
                acc[i][j] = MFMA16(ah[i],  bh4[j], acc[i][j]);
                acc[i][j] = MFMA16(ah[i],  bl4[j], acc[i][j]);
                acc[i][j] = MFMA16(al4[i], bh4[j], acc[i][j]);
            }
    }

    float* cb = p.C[sel];
    const int m0 = by * 128 + wm * 64 + kgrp * 4;
    const int n0 = nloc + wn * 64 + l15;
#pragma unroll
    for (int i = 0; i < 4; ++i)
#pragma unroll
        for (int t = 0; t < 4; ++t) {
            float* cp = cb + (size_t)(m0 + i * 16 + t) * ldc + n0;
#pragma unroll
            for (int j = 0; j < 4; ++j) cp[j * 16] = acc[i][j][t];
        }
}

// ---------------------------------------------------------------------------
// Generic fp32 SGEMM (g1@Wf2 and fallback).
// ---------------------------------------------------------------------------
#define GBM 128
#define GBN 128
#define GBK 16

__launch_bounds__(256)
__global__ void sgemm128(const float* __restrict__ A, const float* __restrict__ B,
                         float* __restrict__ C, int M, int N, int K) {
    __shared__ float As[GBK][GBM + 4];
    __shared__ float Bs[GBK][GBN + 4];

    const int tid = threadIdx.x;
    const int bm = blockIdx.y * GBM;
    const int bn = blockIdx.x * GBN;

    const int arow = tid >> 2;
    const int acol = (tid & 3) << 2;
    const int brow = tid >> 5;
    const int bcol = (tid & 31) << 2;
    const int ty = tid >> 4;
    const int tx = tid & 15;

    float acc[8][8];
#pragma unroll
    for (int i = 0; i < 8; ++i)
#pragma unroll
        for (int j = 0; j < 8; ++j) acc[i][j] = 0.f;

    for (int k0 = 0; k0 < K; k0 += GBK) {
#pragma unroll
        for (int r = 0; r < 2; ++r) {
            const int m = arow + r * 64;
            const float4 av = *(const float4*)(A + (size_t)(bm + m) * K + k0 + acol);
            As[acol + 0][m] = av.x;
            As[acol + 1][m] = av.y;
            As[acol + 2][m] = av.z;
            As[acol + 3][m] = av.w;
        }
#pragma unroll
        for (int r = 0; r < 2; ++r) {
            const int kk = brow + r * 8;
            *(float4*)(&Bs[kk][bcol]) =
                *(const float4*)(B + (size_t)(k0 + kk) * N + bn + bcol);
        }
        __syncthreads();

#pragma unroll
        for (int kk = 0; kk < GBK; ++kk) {
            float a[8], bf[8];
#pragma unroll
            for (int i = 0; i < 8; ++i) a[i] = As[kk][ty * 8 + i];
#pragma unroll
            for (int j = 0; j < 8; ++j) bf[j] = Bs[kk][tx * 8 + j];
#pragma unroll
            for (int i = 0; i < 8; ++i)
#pragma unroll
                for (int j = 0; j < 8; ++j)
                    acc[i][j] = fmaf(a[i], bf[j], acc[i][j]);
        }
        __syncthreads();
    }

#pragma unroll
    for (int i = 0; i < 8; ++i) {
        float* cp = C + (size_t)(bm + ty * 8 + i) * N + bn + tx * 8;
        *(float4*)(cp + 0) = make_float4(acc[i][0], acc[i][1], acc[i][2], acc[i][3]);
        *(float4*)(cp + 4) = make_float4(acc[i][4], acc[i][5], acc[i][6], acc[i][7]);
    }
}

// ---------------------------------------------------------------------------
// conv + silu (+ l2norm), 3-in-1 and single variants.
// ---------------------------------------------------------------------------
struct ConvArgs {
    const float* pre[3]; const float* w[3]; float* out[3];
    float scale[3]; int do_norm[3];
};
__global__ void conv_silu_norm3(ConvArgs p) {
    const int z = blockIdx.y;
    const float* __restrict__ pre = p.pre[z];
    const float* __restrict__ wv = p.w[z];
    float* __restrict__ out = p.out[z];
    const float scale = p.scale[z];
    const int do_norm = p.do_norm[z];

    const int blk = blockIdx.x;
    const int h = blk & 15;
    const int bt = blk >> 4;
    const int t = bt & (TT - 1);
    const int b = bt >> 10;
    const int dk = threadIdx.x;
    const int c = h * 128 + dk;

    const size_t off = ((size_t)(b * TT + t)) * DD + c;
    float acc = 0.f;
#pragma unroll
    for (int j = 0; j < 4; ++j) {
        const int tt = t - 3 + j;
        const float x = (tt >= 0) ? pre[off + (size_t)(j - 3) * DD] : 0.f;
        acc = fmaf(x, wv[c * 4 + j], acc);
    }
    float x = acc / (1.f + expf(-acc));

    if (do_norm) {
        float ss = x * x;
#pragma unroll
        for (int s = 1; s < 64; s <<= 1) ss += __shfl_xor(ss, s, 64);
        __shared__ float red[2];
        if ((threadIdx.x & 63) == 0) red[threadIdx.x >> 6] = ss;
        __syncthreads();
        const float tot = red[0] + red[1];
        x = x * rsqrtf(tot + 1e-6f) * scale;
    }
    out[off] = x;
}

__global__ void conv_silu_norm(const float* __restrict__ pre, const float* __restrict__ w,
                               float* __restrict__ out, float scale, int do_norm) {
    const int blk = blockIdx.x;
    const int h = blk & 15;
    const int bt = blk >> 4;
    const int t = bt & (TT - 1);
    const int b = bt >> 10;
    const int dk = threadIdx.x;
    const int c = h * 128 + dk;

    const size_t off = ((size_t)(b * TT + t)) * DD + c;
    float acc = 0.f;
#pragma unroll
    for (int j = 0; j < 4; ++j) {
        const int tt = t - 3 + j;
        const float x = (tt >= 0) ? pre[off + (size_t)(j - 3) * DD] : 0.f;
        acc = fmaf(x, w[c * 4 + j], acc);
    }
    float x = acc / (1.f + expf(-acc));

    if (do_norm) {
        float ss = x * x;
#pragma unroll
        for (int s = 1; s < 64; s <<= 1) ss += __shfl_xor(ss, s, 64);
        __shared__ float red[2];
        if ((threadIdx.x & 63) == 0) red[threadIdx.x >> 6] = ss;
        __syncthreads();
        const float tot = red[0] + red[1];
        x = x * rsqrtf(tot + 1e-6f) * scale;
    }
    out[off] = x;
}

// ---------------------------------------------------------------------------
__global__ void beta_kernel(const float* __restrict__ hid, const float* __restrict__ Wb,
                            float* __restrict__ beta) {
    const int m = blockIdx.x;
    const int t = threadIdx.x;
    const int h = t & 15;
    const int sl = t >> 4;

    const float* hp = hid + (size_t)m * DD + sl * 128;
    const float* wp = Wb + (size_t)sl * 128 * HH + h;
    float p = 0.f;
#pragma unroll 8
    for (int i = 0; i < 128; ++i) p = fmaf(hp[i], wp[i * HH], p);

    __shared__ float red[256];
    red[t] = p;
    __syncthreads();
    if (t < HH) {
        float s = 0.f;
#pragma unroll
        for (int i = 0; i < 16; ++i) s += red[i * 16 + t];
        beta[(size_t)m * HH + t] = 1.f / (1.f + expf(-s));
    }
}

// ---------------------------------------------------------------------------
// decay (fallback layout [b,t,h,g]): d values
// ---------------------------------------------------------------------------
__global__ void decay_kernel(const float* __restrict__ g2, const float* __restrict__ A_log,
                             const float* __restrict__ dt_bias, float* __restrict__ decay) {
    const int idx = blockIdx.x * 256 + threadIdx.x;
    const int g = idx & (NG - 1);
    const int h = (idx >> 3) & (HH - 1);
    const float x = g2[idx] + dt_bias[h * NG + g];
    const float sp = (x > 20.f) ? x : log1pf(expf(x));
    decay[idx] = expf(-expf(A_log[h]) * sp);
}

// ---------------------------------------------------------------------------
// LOG-decay, t-tiled [bh][tblk][g][8]: ln d = -exp(A_log)*softplus(...)
// ---------------------------------------------------------------------------
__global__ void ldecay_kernel_t(const float* __restrict__ g2, const float* __restrict__ A_log,
                                const float* __restrict__ dt_bias, float* __restrict__ ldtr) {
    const int idx = blockIdx.x * 256 + threadIdx.x;   // (b,t,h,g)
    const int g = idx & 7, h = (idx >> 3) & 15;
    const int t = (idx >> 7) & 1023, b = idx >> 17;
    const float x = g2[idx] + dt_bias[h * NG + g];
    const float sp = (x > 20.f) ? x : log1pf(expf(x));
    const float ld = -expf(A_log[h]) * sp;
    const int bh = b * 16 + h, tblk = t >> 3, tj = t & 7;
    ldtr[((size_t)(bh * 128 + tblk)) * 64 + g * 8 + tj] = ld;
}

// ---------------------------------------------------------------------------
// Chunked UT-transform gated delta-rule recurrence (chunk C=16, MFMA).
// grid: 256 blocks = 32 bh x 8 v-slices (16 cols each); 256 threads (4 waves,
// wave w owns k-rows [32w,32w+32)). S[128x16] fp32 lives in LDS per block.
// Per chunk (exact algebra; bf16-split-3 on matrix products):
//   err_t = w_t.S0 + sum_{r<t} A[t][r] d_r ;  w_t = k_t*exp(L_t)
//   A[t][r] = sum_g exp(L_t[g]-L_r[g]) * Gram_g(k_t,k_r)   (grouped gate!)
//   d_t = beta_t (v_t - err_t)   (16-step forward substitution)
//   o_t = q~_t.S0 + sum_{r<=t} Aq[t][r] d_r
//   S' = exp(L_16) o S0 + kdec^T d ,  kdec_r = k_r*exp(L_16-L_r)
// All exp args <= 0 (log-decay negative, t>=r) -> no overflow.
// MFMA fragment conventions identical to verified gemm_split:
//   A-frag: row=lane&15, k=(lane>>4)*8+j ; B-frag: col=lane&15, k same;
//   C/D: col=lane&15, row=(lane>>4)*4+j.
// ---------------------------------------------------------------------------
__launch_bounds__(256)
__global__ void chunk_recur(const float* __restrict__ qt_g, const float* __restrict__ kt_g,
                            const float* __restrict__ vt_g, const float* __restrict__ ldec,
                            const float* __restrict__ beta, float* __restrict__ o) {
    __shared__ float kt[16][132];
    __shared__ float qtl[16][132];
    __shared__ float Sl[128][17];
    __shared__ float scr0[4][16][16];
    __shared__ float scr1[4][16][16];
    __shared__ float E0r[16][20];
    __shared__ float Oqr[16][20];
    __shared__ float Amat[16][20];
    __shared__ float Aqmat[16][20];
    __shared__ float dl[16][20];
    __shared__ float vb[16][20];
    __shared__ float Lc[17][8];
    __shared__ float wexp[16][8];
    __shared__ float fct[16][8];
    __shared__ float betas[16];

    const int bid = blockIdx.x;
    const int xcd = bid & 7, rr = bid >> 3;
    const int bh = xcd * 4 + (rr >> 3);   // bh grouped per XCD
    const int slice = rr & 7;
    const int b = bh >> 4, h = bh & 15;
    const int tid = threadIdx.x;
    const int w = tid >> 6, lane = tid & 63, l15 = lane & 15, lk = lane >> 4;

    const size_t kbase = (size_t)bh * 131072;
    const size_t obase = ((size_t)b * 1024 * 16 + h) * 128;

    // zero S
    for (int i = tid; i < 128 * 17; i += 256) ((float*)Sl)[i] = 0.f;
    __syncthreads();

    for (int ch = 0; ch < 64; ++ch) {
        const int tb0 = ch * 2, t0 = ch * 16;

        // ---- phase 1: stage k,q,v,beta + cumulative log-decay ----
        {
            const int c = tid & 127, half = tid >> 7;
            const float* src = kt_g + kbase + (size_t)(tb0 + half) * 1024 + c * 8;
            float4 a0 = *(const float4*)(src);
            float4 a1 = *(const float4*)(src + 4);
            kt[half * 8 + 0][c] = a0.x; kt[half * 8 + 1][c] = a0.y;
            kt[half * 8 + 2][c] = a0.z; kt[half * 8 + 3][c] = a0.w;
            kt[half * 8 + 4][c] = a1.x; kt[half * 8 + 5][c] = a1.y;
            kt[half * 8 + 6][c] = a1.z; kt[half * 8 + 7][c] = a1.w;
            const float* srq = qt_g + kbase + (size_t)(tb0 + half) * 1024 + c * 8;
            a0 = *(const float4*)(srq);
            a1 = *(const float4*)(srq + 4);
            qtl[half * 8 + 0][c] = a0.x; qtl[half * 8 + 1][c] = a0.y;
            qtl[half * 8 + 2][c] = a0.z; qtl[half * 8 + 3][c] = a0.w;
            qtl[half * 8 + 4][c] = a1.x; qtl[half * 8 + 5][c] = a1.y;
            qtl[half * 8 + 6][c] = a1.z; qtl[half * 8 + 7][c] = a1.w;

            const int tv = tid >> 4, u = tid & 15;
            vb[tv][u] = vt_g[kbase + (size_t)(tb0 + (tv >> 3)) * 1024 +
                             (size_t)(slice * 16 + u) * 8 + (tv & 7)];
            if (tid < 16) betas[tid] = beta[((size_t)b * 1024 + t0 + tid) * 16 + h];
            if (tid < 8) {
                float run = 0.f;
                Lc[0][tid] = 0.f;
#pragma unroll
                for (int j = 0; j < 16; ++j) {
                    run += ldec[(size_t)bh * 8192 + (size_t)(tb0 + (j >> 3)) * 64 + tid * 8 + (j & 7)];
                    Lc[j + 1][tid] = run;
                }
            }
        }
        __syncthreads();

        // ---- phase 2: exp LUTs ----
        if (tid < 128) {
            const int t = tid >> 3, g = tid & 7;
            wexp[t][g] = expf(Lc[t + 1][g]);
        } else {
            const int q2 = tid - 128;
            const int r = q2 >> 3, g = q2 & 7;
            fct[r][g] = expf(Lc[16][g] - Lc[r + 1][g]);
        }
        __syncthreads();

        // ---- phase 3: E0, Oq partial MFMAs (per wave k-quarter) ----
        {
            const int c0 = w * 32 + lk * 8;
            const int g3 = c0 >> 4;
            const float ex = wexp[l15][g3];  // t = l15 (inclusive L_t)
            float tv8[8];
            float4 a0 = *(const float4*)&kt[l15][c0];
            float4 a1 = *(const float4*)&kt[l15][c0 + 4];
            tv8[0] = a0.x * ex; tv8[1] = a0.y * ex; tv8[2] = a0.z * ex; tv8[3] = a0.w * ex;
            tv8[4] = a1.x * ex; tv8[5] = a1.y * ex; tv8[6] = a1.z * ex; tv8[7] = a1.w * ex;
            bf16x8 wh, wl;
            split8arr(tv8, wh, wl);
            a0 = *(const float4*)&qtl[l15][c0];
            a1 = *(const float4*)&qtl[l15][c0 + 4];
            tv8[0] = a0.x * ex; tv8[1] = a0.y * ex; tv8[2] = a0.z * ex; tv8[3] = a0.w * ex;
            tv8[4] = a1.x * ex; tv8[5] = a1.y * ex; tv8[6] = a1.z * ex; tv8[7] = a1.w * ex;
            bf16x8 qh, ql;
            split8arr(tv8, qh, ql);
#pragma unroll
            for (int j = 0; j < 8; ++j) tv8[j] = Sl[c0 + j][l15];
            bf16x8 sh, sl2;
            split8arr(tv8, sh, sl2);
            f32x4 e = (f32x4){0.f, 0.f, 0.f, 0.f};
            f32x4 oq = (f32x4){0.f, 0.f, 0.f, 0.f};
            e = MFMA16(wh, sh, e); e = MFMA16(wh, sl2, e); e = MFMA16(wl, sh, e);
            oq = MFMA16(qh, sh, oq); oq = MFMA16(qh, sl2, oq); oq = MFMA16(ql, sh, oq);
#pragma unroll
            for (int j = 0; j < 4; ++j) {
                scr0[w][lk * 4 + j][l15] = e[j];
                scr1[w][lk * 4 + j][l15] = oq[j];
            }
        }
        __syncthreads();

        // ---- phase 4: reduce E0r, Oqr ----
        {
            const int t = tid >> 4, u = tid & 15;
            E0r[t][u] = scr0[0][t][u] + scr0[1][t][u] + scr0[2][t][u] + scr0[3][t][u];
            Oqr[t][u] = scr1[0][t][u] + scr1[1][t][u] + scr1[2][t][u] + scr1[3][t][u];
        }
        __syncthreads();

        // ---- phase 5: per-group Gram MFMAs + exp fold ----
        {
            float apart[4] = {0.f, 0.f, 0.f, 0.f};
            float aqpart[4] = {0.f, 0.f, 0.f, 0.f};
#pragma unroll
            for (int gi = 0; gi < 2; ++gi) {
                const int g5 = 2 * w + gi;
                float kv[8], qv[8];
                if (lk < 2) {
                    const float4 a0 = *(const float4*)&kt[l15][g5 * 16 + lk * 8];
                    const float4 a1 = *(const float4*)&kt[l15][g5 * 16 + lk * 8 + 4];
                    kv[0] = a0.x; kv[1] = a0.y; kv[2] = a0.z; kv[3] = a0.w;
                    kv[4] = a1.x; kv[5] = a1.y; kv[6] = a1.z; kv[7] = a1.w;
                    const float4 b0 = *(const float4*)&qtl[l15][g5 * 16 + lk * 8];
                    const float4 b1 = *(const float4*)&qtl[l15][g5 * 16 + lk * 8 + 4];
                    qv[0] = b0.x; qv[1] = b0.y; qv[2] = b0.z; qv[3] = b0.w;
                    qv[4] = b1.x; qv[5] = b1.y; qv[6] = b1.z; qv[7] = b1.w;
                } else {
#pragma unroll
                    for (int j = 0; j < 8; ++j) { kv[j] = 0.f; qv[j] = 0.f; }
                }
                bf16x8 kh, kl2, qh2, ql2;
                split8arr(kv, kh, kl2);
                split8arr(qv, qh2, ql2);
                f32x4 gk = (f32x4){0.f, 0.f, 0.f, 0.f};
                f32x4 gq = (f32x4){0.f, 0.f, 0.f, 0.f};
                gk = MFMA16(kh, kh, gk); gk = MFMA16(kh, kl2, gk); gk = MFMA16(kl2, kh, gk);
                gq = MFMA16(qh2, kh, gq); gq = MFMA16(qh2, kl2, gq); gq = MFMA16(ql2, kh, gq);
#pragma unroll
                for (int j = 0; j < 4; ++j) {
                    const int tt2 = lk * 4 + j, rr2 = l15;
                    const float f = expf(Lc[tt2 + 1][g5] - Lc[rr2 + 1][g5]);
                    apart[j] = fmaf(f, gk[j], apart[j]);
                    aqpart[j] = fmaf(f, gq[j], aqpart[j]);
                }
            }
#pragma unroll
            for (int j = 0; j < 4; ++j) {
                scr0[w][lk * 4 + j][l15] = apart[j];
                scr1[w][lk * 4 + j][l15] = aqpart[j];
            }
        }
        __syncthreads();

        // ---- phase 6: reduce + mask A (r<t), Aq (r<=t) ----
        {
            const int t = tid >> 4, r = tid & 15;
            const float sa = scr0[0][t][r] + scr0[1][t][r] + scr0[2][t][r] + scr0[3][t][r];
            const float sq = scr1[0][t][r] + scr1[1][t][r] + scr1[2][t][r] + scr1[3][t][r];
            Amat[t][r] = (r < t) ? sa : 0.f;
            Aqmat[t][r] = (r <= t) ? sq : 0.f;
        }
        __syncthreads();

        // ---- phase 7: forward substitution (lanes 0..15 of wave 0) ----
        if (tid < 16) {
            const int u = tid;
            float d[16];
#pragma unroll
            for (int t = 0; t < 16; ++t) {
                float acc = vb[t][u] - E0r[t][u];
#pragma unroll
                for (int r = 0; r < 16; ++r)
                    if (r < t) acc = fmaf(-Amat[t][r], d[r], acc);
                d[t] = betas[t] * acc;
                dl[t][u] = d[t];
            }
        }
        __syncthreads();

        // ---- phase 8: o output (wave 0) + S update (all waves) ----
        if (w == 0) {
            float av[8], bv[8];
            if (lk < 2) {
                const float4 a0 = *(const float4*)&Aqmat[l15][lk * 8];
                const float4 a1 = *(const float4*)&Aqmat[l15][lk * 8 + 4];
                av[0] = a0.x; av[1] = a0.y; av[2] = a0.z; av[3] = a0.w;
                av[4] = a1.x; av[5] = a1.y; av[6] = a1.z; av[7] = a1.w;
#pragma unroll
                for (int j = 0; j < 8; ++j) bv[j] = dl[lk * 8 + j][l15];
            } else {
#pragma unroll
                for (int j = 0; j < 8; ++j) { av[j] = 0.f; bv[j] = 0.f; }
            }
            bf16x8 ah2, al2, dh, dlo;
            split8arr(av, ah2, al2);
            split8arr(bv, dh, dlo);
            f32x4 oc;
#pragma unroll
            for (int j = 0; j < 4; ++j) oc[j] = Oqr[lk * 4 + j][l15];
            oc = MFMA16(ah2, dh, oc); oc = MFMA16(ah2, dlo, oc); oc = MFMA16(al2, dh, oc);
#pragma unroll
            for (int j = 0; j < 4; ++j)
                o[obase + (size_t)(t0 + lk * 4 + j) * 2048 + slice * 16 + l15] = oc[j];
        }
#pragma unroll
        for (int tau = 0; tau < 2; ++tau) {
            const int cb = w * 32 + tau * 16;
            const int g8 = cb >> 4;
            float av[8], bv[8];
            if (lk < 2) {
#pragma unroll
                for (int j = 0; j < 8; ++j) {
                    const int r2 = lk * 8 + j;
                    av[j] = kt[r2][cb + l15] * fct[r2][g8];
                    bv[j] = dl[r2][l15];
                }
            } else {
#pragma unroll
                for (int j = 0; j < 8; ++j) { av[j] = 0.f; bv[j] = 0.f; }
            }
            bf16x8 kdh, kdl2, dh2, dlo2;
            split8arr(av, kdh, kdl2);
            split8arr(bv, dh2, dlo2);
            const float w15 = wexp[15][g8];
            f32x4 sc;
#pragma unroll
            for (int j = 0; j < 4; ++j) sc[j] = Sl[cb + lk * 4 + j][l15] * w15;
            sc = MFMA16(kdh, dh2, sc); sc = MFMA16(kdh, dlo2, sc); sc = MFMA16(kdl2, dh2, sc);
#pragma unroll
            for (int j = 0; j < 4; ++j) Sl[cb + lk * 4 + j][l15] = sc[j];
        }
        __syncthreads();
    }
}

// ---------------------------------------------------------------------------
// Old-layout recurrence (fallback path only).
// ---------------------------------------------------------------------------
__launch_bounds__(256, 4)
__global__ void recur_kernel(const float* __restrict__ q, const float* __restrict__ k,
                             const float* __restrict__ vv, const float* __restrict__ decay,
                             const float* __restrict__ beta, float* __restrict__ o) {
    const int blk = blockIdx.x;
    const int vblk = blk & 31;
    const int bh = blk >> 5;
    const int b = bh >> 4, h = bh & 15;
    const int w = threadIdx.x >> 6;
    const int lane = threadIdx.x & 63;
    const int vi = vblk * 4 + w;

    float S0 = 0.f, S1 = 0.f;
    const size_t strideT = (size_t)HH * DV;
    const size_t strideT2 = strideT >> 1;
    const size_t base = ((size_t)b * TT * HH + h) * DV;

    const float2* kp = (const float2*)(k + base) + lane;
    const float2* qp = (const float2*)(q + base) + lane;
    const float* vp = vv + base + vi;
    const float* bp = beta + (size_t)b * TT * HH + h;
    const float* dp = decay + ((size_t)b * TT * HH + h) * NG + (lane >> 3);

    float2 kv = kp[0], qv = qp[0];
    float vtv = vp[0], bt = bp[0], dt = dp[0];

    for (int t = 0; t < TT; ++t) {
        const float2 kc = kv, qc = qv;
        const float vc = vtv, bc = bt, dc = dt;

        const int tn = (t + 1 < TT) ? (t + 1) : t;
        kv = kp[(size_t)tn * strideT2];
        qv = qp[(size_t)tn * strideT2];
        vtv = vp[(size_t)tn * strideT];
        bt = bp[(size_t)tn * HH];
        dt = dp[(size_t)tn * HH * NG];

        S0 *= dc;
        S1 *= dc;
        float e = fmaf(kc.x, S0, kc.y * S1);
        e = dpp_sum64(e);
        const float err = readlanef(e, 63);
        const float delta = bc * (vc - err);
        S0 = fmaf(kc.x, delta, S0);
        S1 = fmaf(kc.y, delta, S1);
        float oo = fmaf(qc.x, S0, qc.y * S1);
        oo = dpp_sum64(oo);
        if (lane == 63) o[base + (size_t)t * strideT + vi] = oo;
    }
}

// ---------------------------------------------------------------------------
// Gated RMSNorm -> fp32 y (fallback)
// ---------------------------------------------------------------------------
__global__ void gated_rmsnorm(const float* __restrict__ o,
                              const float* __restrict__ gpre, const float* __restrict__ bg,
                              const float* __restrict__ norm_w, float* __restrict__ y) {
    const int blk = blockIdx.x;
    const int h = blk & 15;
    const int dv = threadIdx.x;
    const size_t off = (size_t)blk * DV + dv;

    const float ov = o[off];
    const float g = gpre[off] + bg[h * 128 + dv];
    const float yv = ov * (g / (1.f + expf(-g)));

    float ss = yv * yv;
#pragma unroll
    for (int s = 1; s < 64; s <<= 1) ss += __shfl_xor(ss, s, 64);
    __shared__ float red[2];
    if ((threadIdx.x & 63) == 0) red[threadIdx.x >> 6] = ss;
    __syncthreads();
    const float mean = (red[0] + red[1]) * (1.f / 128.f);
    y[off] = yv * rsqrtf(mean + 1e-5f) * norm_w[dv];
}

// ---------------------------------------------------------------------------
// Gated RMSNorm -> bf16 hi/lo split y
// ---------------------------------------------------------------------------
__global__ void gated_rmsnorm_split(const float* __restrict__ o,
                                    const float* __restrict__ gpre, const float* __restrict__ bg,
                                    const float* __restrict__ norm_w,
                                    unsigned short* __restrict__ yh,
                                    unsigned short* __restrict__ yl) {
    const int blk = blockIdx.x;
    const int h = blk & 15;
    const int dv = threadIdx.x;
    const size_t off = (size_t)blk * DV + dv;

    const float ov = o[off];
    const float g = gpre[off] + bg[h * 128 + dv];
    const float yv = ov * (g / (1.f + expf(-g)));

    float ss = yv * yv;
#pragma unroll
    for (int s = 1; s < 64; s <<= 1) ss += __shfl_xor(ss, s, 64);
    __shared__ float red[2];
    if ((threadIdx.x & 63) == 0) red[threadIdx.x >> 6] = ss;
    __syncthreads();
    const float mean = (red[0] + red[1]) * (1.f / 128.f);
    const float y = yv * rsqrtf(mean + 1e-5f) * norm_w[dv];
    unsigned short hh, ll;
    bsplit(y, hh, ll);
    yh[off] = hh;
    yl[off] = ll;
}

// ---------------------------------------------------------------------------
extern "C" void kernel_launch(void* const* d_in, const int* in_sizes, int n_in,
                              void* d_out, int out_size, void* d_ws, size_t ws_size,
                              hipStream_t stream) {
    const float* hid    = (const float*)d_in[0];
    const float* Wq     = (const float*)d_in[1];
    const float* Wk     = (const float*)d_in[2];
    const float* Wv     = (const float*)d_in[3];
    const float* conv_q = (const float*)d_in[4];
    const float* conv_k = (const float*)d_in[5];
    const float* conv_v = (const float*)d_in[6];
    const float* Wf1    = (const float*)d_in[7];
    const float* Wf2    = (const float*)d_in[8];
    const float* Wb     = (const float*)d_in[9];
    const float* A_log  = (const float*)d_in[10];
    const float* dt_bias= (const float*)d_in[11];
    const float* Wg     = (const float*)d_in[12];
    const float* bg     = (const float*)d_in[13];
    const float* norm_w = (const float*)d_in[14];
    const float* Wo     = (const float*)d_in[15];
    float* out = (float*)d_out;

    const size_t N1  = (size_t)2048 * 2048;
    const size_t N1B = N1 * 4;
    const int M = BB * TT;

    const size_t NEED_NEW = 9 * N1B + 4390912;

    if (ws_size >= NEED_NEW) {
        // ---------------- MFMA split-precision path ----------------
        char* W = (char*)d_ws;
        unsigned short* hidh = (unsigned short*)W;
        unsigned short* hidl = hidh + N1;
        float* o = (float*)W;
        char* RB = W + N1B;
        unsigned short* Wqth = (unsigned short*)RB;
        unsigned short* Wqtl = Wqth + N1;
        unsigned short* Wkth = Wqtl + N1;
        unsigned short* Wktl = Wkth + N1;
        unsigned short* Wvth = Wktl + N1;
        unsigned short* Wvtl = Wvth + N1;
        unsigned short* Wgth = Wvtl + N1;
        unsigned short* Wgtl = Wgth + N1;
        float* qn = (float*)RB;
        float* kn = qn + N1;
        float* vn = kn + N1;
        char* RC = W + 5 * N1B;
        float* qpre = (float*)RC;
        float* kpre = qpre + N1;
        float* vpre = kpre + N1;
        float* gpre = vpre + N1;
        float* qn_t = qpre;
        float* kn_t = kpre;
        float* vn_t = vpre;
        unsigned short* Woth = (unsigned short*)RC;
        unsigned short* Wotl = Woth + N1;
        unsigned short* yh = (unsigned short*)(RC + N1B);
        unsigned short* yl = yh + N1;
        char* RD = W + 9 * N1B;
        float* g1b   = (float*)RD;
        float* g2b   = g1b + 262144;
        float* betab = g2b + 262144;
        float* ldecb = betab + 32768;      // 262144 (t-tiled log-decay)
        unsigned short* wf1th = (unsigned short*)(ldecb + 262144);
        unsigned short* wf1tl = wf1th + 262144;

        // 1. splits / transposes
        split_mat<<<1024, 256, 0, stream>>>(hid, hidh, hidl);
        TS4 ts;
        ts.in[0] = Wq; ts.oh[0] = Wqth; ts.ol[0] = Wqtl;
        ts.in[1] = Wk; ts.oh[1] = Wkth; ts.ol[1] = Wktl;
        ts.in[2] = Wv; ts.oh[2] = Wvth; ts.ol[2] = Wvtl;
        ts.in[3] = Wg; ts.oh[3] = Wgth; ts.ol[3] = Wgtl;
        transpose_split4<<<dim3(32, 32, 4), 256, 0, stream>>>(ts);
        transpose_split<<<dim3(2, 32), 256, 0, stream>>>(Wf1, wf1th, wf1tl, 128, 2048);

        // 2. fused input projections
        GemmArgs fa;
        fa.Ah = hidh; fa.Al = hidl;
        fa.Bh[0] = Wqth; fa.Bl[0] = Wqtl; fa.C[0] = qpre;
        fa.Bh[1] = Wkth; fa.Bl[1] = Wktl; fa.C[1] = kpre;
        fa.Bh[2] = Wvth; fa.Bl[2] = Wvtl; fa.C[2] = vpre;
        fa.Bh[3] = Wgth; fa.Bl[3] = Wgtl; fa.C[3] = gpre;
        fa.Bh[4] = wf1th; fa.Bl[4] = wf1tl; fa.C[4] = g1b;
        gemm_split<<<dim3(65, 16), 256, 0, stream>>>(fa, 1);

        // 3. beta, g2, log-decay (t-tiled)
        beta_kernel<<<M, 256, 0, stream>>>(hid, Wb, betab);
        sgemm128<<<dim3(1, 16), 256, 0, stream>>>(g1b, Wf2, g2b, M, 128, 128);
        ldecay_kernel_t<<<(M * HH * NG) / 256, 256, 0, stream>>>(g2b, A_log, dt_bias, ldecb);

        // 4. conv + silu (+ l2norm)
        ConvArgs ca;
        ca.pre[0] = qpre; ca.w[0] = conv_q; ca.out[0] = qn; ca.scale[0] = SCALE_Q; ca.do_norm[0] = 1;
        ca.pre[1] = kpre; ca.w[1] = conv_k; ca.out[1] = kn; ca.scale[1] = 1.f;     ca.do_norm[1] = 1;
        ca.pre[2] = vpre; ca.w[2] = conv_v; ca.out[2] = vn; ca.scale[2] = 1.f;     ca.do_norm[2] = 0;
        conv_silu_norm3<<<dim3(M * HH, 3), 128, 0, stream>>>(ca);

        // 5. t-tile transpose
        T3 tt;
        tt.in[0] = qn; tt.out[0] = qn_t;
        tt.in[1] = kn; tt.out[1] = kn_t;
        tt.in[2] = vn; tt.out[2] = vn_t;
        transpose_tile3<<<dim3(4096, 3), 256, 0, stream>>>(tt);

        // 6. chunked UT-transform recurrence (o over dead hid split)
        chunk_recur<<<256, 256, 0, stream>>>(qn_t, kn_t, vn_t, ldecb, betab, o);

        // 7. transpose Wo (over dead qn_t)
        transpose_split<<<dim3(32, 32), 256, 0, stream>>>(Wo, Woth, Wotl, 2048, 2048);

        // 8. gated rmsnorm -> y split (over dead kn_t)
        gated_rmsnorm_split<<<M * HH, 128, 0, stream>>>(o, gpre, bg, norm_w, yh, yl);

        // 9. output projection
        GemmArgs oa;
        oa.Ah = yh; oa.Al = yl;
        for (int i = 0; i < 5; ++i) { oa.Bh[i] = Woth; oa.Bl[i] = Wotl; oa.C[i] = out; }
        gemm_split<<<dim3(16, 16), 256, 0, stream>>>(oa, 0);
    } else {
        // ---------------- fallback: fp32 path ----------------
        float* ws = (float*)d_ws;
        float* qpre = ws + 0 * N1;
        float* kpre = ws + 1 * N1;
        float* vpre = ws + 2 * N1;
        float* gpre = ws + 3 * N1;
        float* qn   = ws + 4 * N1;
        float* kn   = ws + 5 * N1;
        float* vn   = ws + 6 * N1;
        float* g1b  = ws + 7 * N1;
        float* g2b  = g1b + (size_t)BB * TT * DV;
        float* betab= g2b + (size_t)BB * TT * HH * NG;
        float* decayb = betab + (size_t)BB * TT * HH;
        float* o = qpre;
        float* y = vpre;

        sgemm128<<<dim3(16, 16), 256, 0, stream>>>(hid, Wq, qpre, M, 2048, 2048);
        sgemm128<<<dim3(16, 16), 256, 0, stream>>>(hid, Wk, kpre, M, 2048, 2048);
        sgemm128<<<dim3(16, 16), 256, 0, stream>>>(hid, Wv, vpre, M, 2048, 2048);
        sgemm128<<<dim3(16, 16), 256, 0, stream>>>(hid, Wg, gpre, M, 2048, 2048);
        sgemm128<<<dim3(1, 16), 256, 0, stream>>>(hid, Wf1, g1b, M, 128, 2048);
        sgemm128<<<dim3(1, 16), 256, 0, stream>>>(g1b, Wf2, g2b, M, 128, 128);
        beta_kernel<<<M, 256, 0, stream>>>(hid, Wb, betab);

        conv_silu_norm<<<M * HH, 128, 0, stream>>>(qpre, conv_q, qn, SCALE_Q, 1);
        conv_silu_norm<<<M * HH, 128, 0, stream>>>(kpre, conv_k, kn, 1.f, 1);
        conv_silu_norm<<<M * HH, 128, 0, stream>>>(vpre, conv_v, vn, 1.f, 0);

        decay_kernel<<<(M * HH * NG) / 256, 256, 0, stream>>>(g2b, A_log, dt_bias, decayb);

        recur_kernel<<<BB * HH * (DV / 4), 256, 0, stream>>>(qn, kn, vn, decayb, betab, o);

        gated_rmsnorm<<<M * HH, 128, 0, stream>>>(o, gpre, bg, norm_w, y);

        sgemm128<<<dim3(16, 16), 256, 0, stream>>>(y, Wo, out, M, 2048, 2048);
    }
}

// Round 14
// 815.205 us; speedup vs baseline: 1.2658x; 1.0196x over previous
//
#include <hip/hip_runtime.h>
#include <hip/hip_bf16.h>
#include <math.h>

// Problem constants (fixed by setup_inputs)
#define BB 2
#define TT 1024
#define DD 2048
#define HH 16
#define DK 128
#define DV 128
#define NG 8
#define GG 16
#define SCALE_Q 0.08838834764831845f  // 128^-0.5

typedef __attribute__((ext_vector_type(8))) short bf16x8;
typedef __attribute__((ext_vector_type(4))) float f32x4;

#define MFMA16(a, b, c) __builtin_amdgcn_mfma_f32_16x16x32_bf16((a), (b), (c), 0, 0, 0)

// bf16 split helpers (RNE)
__device__ __forceinline__ unsigned short f2bf(float v) {
    unsigned u = __float_as_uint(v);
    return (unsigned short)((u + 0x7FFFu + ((u >> 16) & 1u)) >> 16);
}
__device__ __forceinline__ float bf2f(unsigned short h) {
    return __uint_as_float(((unsigned)h) << 16);
}
__device__ __forceinline__ void bsplit(float v, unsigned short& h, unsigned short& l) {
    h = f2bf(v);
    l = f2bf(v - bf2f(h));
}
__device__ __forceinline__ void split8arr(const float* v, bf16x8& hi, bf16x8& lo) {
#pragma unroll
    for (int j = 0; j < 8; ++j) {
        unsigned short h, l;
        bsplit(v[j], h, l);
        hi[j] = (short)h;
        lo[j] = (short)l;
    }
}

// ---------------------------------------------------------------------------
// DPP wave64 sum (fallback recurrence only).
// ---------------------------------------------------------------------------
__device__ __forceinline__ float dpp_sum64(float x) {
    x += __int_as_float(__builtin_amdgcn_update_dpp(0, __float_as_int(x), 0x111, 0xf, 0xf, true));
    x += __int_as_float(__builtin_amdgcn_update_dpp(0, __float_as_int(x), 0x112, 0xf, 0xf, true));
    x += __int_as_float(__builtin_amdgcn_update_dpp(0, __float_as_int(x), 0x114, 0xf, 0xf, true));
    x += __int_as_float(__builtin_amdgcn_update_dpp(0, __float_as_int(x), 0x118, 0xf, 0xf, true));
    x += __int_as_float(__builtin_amdgcn_update_dpp(0, __float_as_int(x), 0x142, 0xa, 0xf, false));
    x += __int_as_float(__builtin_amdgcn_update_dpp(0, __float_as_int(x), 0x143, 0xc, 0xf, false));
    return x;
}
__device__ __forceinline__ float readlanef(float x, int l) {
    return __int_as_float(__builtin_amdgcn_readlane(__float_as_int(x), l));
}

// ---------------------------------------------------------------------------
// split: fp32 [n] -> bf16 hi/lo
// ---------------------------------------------------------------------------
__global__ void split_mat(const float* __restrict__ in, unsigned short* __restrict__ oh,
                          unsigned short* __restrict__ ol) {
    const int i0 = (blockIdx.x * 256 + threadIdx.x) * 16;
#pragma unroll
    for (int r = 0; r < 4; ++r) {
        const float4 v = *(const float4*)(in + i0 + r * 4);
        unsigned short h0, l0, h1, l1, h2, l2, h3, l3;
        bsplit(v.x, h0, l0); bsplit(v.y, h1, l1);
        bsplit(v.z, h2, l2); bsplit(v.w, h3, l3);
        short4 hh; hh.x = (short)h0; hh.y = (short)h1; hh.z = (short)h2; hh.w = (short)h3;
        short4 ll; ll.x = (short)l0; ll.y = (short)l1; ll.z = (short)l2; ll.w = (short)l3;
        *(short4*)(oh + i0 + r * 4) = hh;
        *(short4*)(ol + i0 + r * 4) = ll;
    }
}

// ---------------------------------------------------------------------------
// transpose + split: in fp32 [Kin][Nin] -> out bf16 hi/lo [Nin][Kin]
// ---------------------------------------------------------------------------
__device__ __forceinline__ void tsplit_body(const float* __restrict__ in,
                                            unsigned short* __restrict__ oh,
                                            unsigned short* __restrict__ ol,
                                            int Nin, int Kin, int bx, int by, int tid) {
    __shared__ float t[64][65];
    const int c4 = (tid & 15) * 4, r0 = tid >> 4;
#pragma unroll
    for (int rep = 0; rep < 4; ++rep) {
        const int r = r0 + rep * 16;
        const float4 v = *(const float4*)(in + (size_t)(by * 64 + r) * Nin + bx * 64 + c4);
        t[r][c4] = v.x; t[r][c4 + 1] = v.y; t[r][c4 + 2] = v.z; t[r][c4 + 3] = v.w;
    }
    __syncthreads();
#pragma unroll
    for (int rep = 0; rep < 4; ++rep) {
        const int n = r0 + rep * 16;
        short4 hh, ll;
        unsigned short h, l;
        bsplit(t[c4 + 0][n], h, l); hh.x = (short)h; ll.x = (short)l;
        bsplit(t[c4 + 1][n], h, l); hh.y = (short)h; ll.y = (short)l;
        bsplit(t[c4 + 2][n], h, l); hh.z = (short)h; ll.z = (short)l;
        bsplit(t[c4 + 3][n], h, l); hh.w = (short)h; ll.w = (short)l;
        const size_t o = (size_t)(bx * 64 + n) * Kin + by * 64 + c4;
        *(short4*)(oh + o) = hh;
        *(short4*)(ol + o) = ll;
    }
}

__global__ void transpose_split(const float* __restrict__ in, unsigned short* __restrict__ oh,
                                unsigned short* __restrict__ ol, int Nin, int Kin) {
    tsplit_body(in, oh, ol, Nin, Kin, blockIdx.x, blockIdx.y, threadIdx.x);
}

struct TS4 { const float* in[4]; unsigned short* oh[4]; unsigned short* ol[4]; };
__global__ void transpose_split4(TS4 p) {
    const int z = blockIdx.z;
    tsplit_body(p.in[z], p.oh[z], p.ol[z], 2048, 2048, blockIdx.x, blockIdx.y, threadIdx.x);
}

// ---------------------------------------------------------------------------
// t-tile transpose x3: in [B][1024][2048] -> out tiled [bh][tblk][cl][8]
// ---------------------------------------------------------------------------
struct T3 { const float* in[3]; float* out[3]; };
__global__ void transpose_tile3(T3 p) {
    __shared__ float tl[8][128];
    const int z = blockIdx.y;
    const float* __restrict__ in = p.in[z];
    float* __restrict__ out = p.out[z];
    const int blk = blockIdx.x;
    const int bh = blk >> 7, tblk = blk & 127;
    const int b = bh >> 4, h = bh & 15;
    const int tid = threadIdx.x;

    const int tt = tid >> 5, c4 = (tid & 31) * 4;
    const float4 v = *(const float4*)(in + ((size_t)(b * 1024 + tblk * 8 + tt)) * 2048 + h * 128 + c4);
    tl[tt][c4] = v.x; tl[tt][c4 + 1] = v.y; tl[tt][c4 + 2] = v.z; tl[tt][c4 + 3] = v.w;
    __syncthreads();

    const int cl = tid >> 1, tj0 = (tid & 1) * 4;
    float4 w4;
    w4.x = tl[tj0 + 0][cl]; w4.y = tl[tj0 + 1][cl];
    w4.z = tl[tj0 + 2][cl]; w4.w = tl[tj0 + 3][cl];
    *(float4*)(out + ((size_t)blk * 128 + cl) * 8 + tj0) = w4;
}

// ---------------------------------------------------------------------------
// Split-precision bf16 MFMA GEMM (verified).
// ---------------------------------------------------------------------------
struct GemmArgs {
    const unsigned short* Ah; const unsigned short* Al;
    const unsigned short* Bh[5]; const unsigned short* Bl[5];
    float* C[5];
};

#define AHI 0
#define ALO 8192
#define BHI 16384
#define BLO 24576

#define GL2LDS(g, s) __builtin_amdgcn_global_load_lds( \
    (const __attribute__((address_space(1))) void*)(g), \
    (__attribute__((address_space(3))) void*)(s), 16, 0, 0)

__launch_bounds__(256, 3)
__global__ void gemm_split(GemmArgs p, int fused) {
    __shared__ __attribute__((aligned(16))) char lds[32768];
    const int tid = threadIdx.x;
    const int bx = blockIdx.x, by = blockIdx.y;

    int sel, nloc, ldc;
    if (fused) {
        if (bx < 64) { sel = bx >> 4; nloc = (bx & 15) * 128; ldc = 2048; }
        else         { sel = 4;       nloc = 0;               ldc = 128;  }
    } else { sel = 0; nloc = bx * 128; ldc = 2048; }

    const unsigned short* Asrc_h = p.Ah + (size_t)(by * 128) * 2048;
    const unsigned short* Asrc_l = p.Al + (size_t)(by * 128) * 2048;
    const unsigned short* Bsrc_h = p.Bh[sel] + (size_t)nloc * 2048;
    const unsigned short* Bsrc_l = p.Bl[sel] + (size_t)nloc * 2048;

    const int r0 = tid >> 2, ps0 = tid & 3;
    const int r1 = (tid + 256) >> 2, ps1 = tid & 3;
    const size_t ga0 = (size_t)r0 * 2048 + (size_t)((ps0 ^ ((r0 >> 1) & 3)) * 8);
    const size_t ga1 = (size_t)r1 * 2048 + (size_t)((ps1 ^ ((r1 >> 1) & 3)) * 8);
    const int lb0 = (tid & 192) * 16;
    const int lb1 = (256 + (tid & 192)) * 16;

    const int lane = tid & 63;
    const int l15 = lane & 15, kgrp = lane >> 4;
    const int w = tid >> 6, wm = w >> 1, wn = w & 1;
    const int swz = kgrp ^ ((l15 >> 1) & 3);
    const int fro = l15 * 64 + swz * 16;
    const int aoff = wm * 4096, boff = wn * 4096;

    f32x4 acc[4][4];
#pragma unroll
    for (int i = 0; i < 4; ++i)
#pragma unroll
        for (int j = 0; j < 4; ++j) acc[i][j] = (f32x4){0.f, 0.f, 0.f, 0.f};

    for (int k0 = 0; k0 < 2048; k0 += 32) {
        __syncthreads();
        GL2LDS(Asrc_h + k0 + ga0, lds + AHI + lb0);
        GL2LDS(Asrc_h + k0 + ga1, lds + AHI + lb1);
        GL2LDS(Asrc_l + k0 + ga0, lds + ALO + lb0);
        GL2LDS(Asrc_l + k0 + ga1, lds + ALO + lb1);
        GL2LDS(Bsrc_h + k0 + ga0, lds + BHI + lb0);
        GL2LDS(Bsrc_h + k0 + ga1, lds + BHI + lb1);
        GL2LDS(Bsrc_l + k0 + ga0, lds + BLO + lb0);
        GL2LDS(Bsrc_l + k0 + ga1, lds + BLO + lb1);
        __syncthreads();

        bf16x8 ah[4], al4[4], bh4[4], bl4[4];
#pragma unroll
        for (int f = 0; f < 4; ++f) {
            ah[f]  = *(const bf16x8*)(lds + AHI + aoff + f * 1024 + fro);
            al4[f] = *(const bf16x8*)(lds + ALO + aoff + f * 1024 + fro);
            bh4[f] = *(const bf16x8*)(lds + BHI + boff + f * 1024 + fro);
            bl4[f] = *(const bf16x8*)(lds + BLO + boff + f * 1024 + fro);
        }
#pragma unroll
        for (int i = 0; i < 4; ++i)
#pragma unroll
            for (int j = 0; j < 4; ++j) {
                acc[i][j] = MFMA16(ah[i],  bh4[j], acc[i][j]);
                acc[i][j] = MFMA16(ah[i],  bl4[j], acc[i][j]);
                acc[i][j] = MFMA16(al4[i], bh4[j], acc[i][j]);
            }
    }

    float* cb = p.C[sel];
    const int m0 = by * 128 + wm * 64 + kgrp * 4;
    const int n0 = nloc + wn * 64 + l15;
#pragma unroll
    for (int i = 0; i < 4; ++i)
#pragma unroll
        for (int t = 0; t < 4; ++t) {
            float* cp = cb + (size_t)(m0 + i * 16 + t) * ldc + n0;
#pragma unroll
            for (int j = 0; j < 4; ++j) cp[j * 16] = acc[i][j][t];
        }
}

// ---------------------------------------------------------------------------
// Generic fp32 SGEMM (g1@Wf2 and fallback).
// ---------------------------------------------------------------------------
#define GBM 128
#define GBN 128
#define GBK 16

__launch_bounds__(256)
__global__ void sgemm128(const float* __restrict__ A, const float* __restrict__ B,
                         float* __restrict__ C, int M, int N, int K) {
    __shared__ float As[GBK][GBM + 4];
    __shared__ float Bs[GBK][GBN + 4];

    const int tid = threadIdx.x;
    const int bm = blockIdx.y * GBM;
    const int bn = blockIdx.x * GBN;

    const int arow = tid >> 2;
    const int acol = (tid & 3) << 2;
    const int brow = tid >> 5;
    const int bcol = (tid & 31) << 2;
    const int ty = tid >> 4;
    const int tx = tid & 15;

    float acc[8][8];
#pragma unroll
    for (int i = 0; i < 8; ++i)
#pragma unroll
        for (int j = 0; j < 8; ++j) acc[i][j] = 0.f;

    for (int k0 = 0; k0 < K; k0 += GBK) {
#pragma unroll
        for (int r = 0; r < 2; ++r) {
            const int m = arow + r * 64;
            const float4 av = *(const float4*)(A + (size_t)(bm + m) * K + k0 + acol);
            As[acol + 0][m] = av.x;
            As[acol + 1][m] = av.y;
            As[acol + 2][m] = av.z;
            As[acol + 3][m] = av.w;
        }
#pragma unroll
        for (int r = 0; r < 2; ++r) {
            const int kk = brow + r * 8;
            *(float4*)(&Bs[kk][bcol]) =
                *(const float4*)(B + (size_t)(k0 + kk) * N + bn + bcol);
        }
        __syncthreads();

#pragma unroll
        for (int kk = 0; kk < GBK; ++kk) {
            float a[8], bf[8];
#pragma unroll
            for (int i = 0; i < 8; ++i) a[i] = As[kk][ty * 8 + i];
#pragma unroll
            for (int j = 0; j < 8; ++j) bf[j] = Bs[kk][tx * 8 + j];
#pragma unroll
            for (int i = 0; i < 8; ++i)
#pragma unroll
                for (int j = 0; j < 8; ++j)
                    acc[i][j] = fmaf(a[i], bf[j], acc[i][j]);
        }
        __syncthreads();
    }

#pragma unroll
    for (int i = 0; i < 8; ++i) {
        float* cp = C + (size_t)(bm + ty * 8 + i) * N + bn + tx * 8;
        *(float4*)(cp + 0) = make_float4(acc[i][0], acc[i][1], acc[i][2], acc[i][3]);
        *(float4*)(cp + 4) = make_float4(acc[i][4], acc[i][5], acc[i][6], acc[i][7]);
    }
}

// ---------------------------------------------------------------------------
// conv + silu (+ l2norm), 3-in-1 and single variants.
// ---------------------------------------------------------------------------
struct ConvArgs {
    const float* pre[3]; const float* w[3]; float* out[3];
    float scale[3]; int do_norm[3];
};
__global__ void conv_silu_norm3(ConvArgs p) {
    const int z = blockIdx.y;
    const float* __restrict__ pre = p.pre[z];
    const float* __restrict__ wv = p.w[z];
    float* __restrict__ out = p.out[z];
    const float scale = p.scale[z];
    const int do_norm = p.do_norm[z];

    const int blk = blockIdx.x;
    const int h = blk & 15;
    const int bt = blk >> 4;
    const int t = bt & (TT - 1);
    const int b = bt >> 10;
    const int dk = threadIdx.x;
    const int c = h * 128 + dk;

    const size_t off = ((size_t)(b * TT + t)) * DD + c;
    float acc = 0.f;
#pragma unroll
    for (int j = 0; j < 4; ++j) {
        const int tt = t - 3 + j;
        const float x = (tt >= 0) ? pre[off + (size_t)(j - 3) * DD] : 0.f;
        acc = fmaf(x, wv[c * 4 + j], acc);
    }
    float x = acc / (1.f + expf(-acc));

    if (do_norm) {
        float ss = x * x;
#pragma unroll
        for (int s = 1; s < 64; s <<= 1) ss += __shfl_xor(ss, s, 64);
        __shared__ float red[2];
        if ((threadIdx.x & 63) == 0) red[threadIdx.x >> 6] = ss;
        __syncthreads();
        const float tot = red[0] + red[1];
        x = x * rsqrtf(tot + 1e-6f) * scale;
    }
    out[off] = x;
}

__global__ void conv_silu_norm(const float* __restrict__ pre, const float* __restrict__ w,
                               float* __restrict__ out, float scale, int do_norm) {
    const int blk = blockIdx.x;
    const int h = blk & 15;
    const int bt = blk >> 4;
    const int t = bt & (TT - 1);
    const int b = bt >> 10;
    const int dk = threadIdx.x;
    const int c = h * 128 + dk;

    const size_t off = ((size_t)(b * TT + t)) * DD + c;
    float acc = 0.f;
#pragma unroll
    for (int j = 0; j < 4; ++j) {
        const int tt = t - 3 + j;
        const float x = (tt >= 0) ? pre[off + (size_t)(j - 3) * DD] : 0.f;
        acc = fmaf(x, w[c * 4 + j], acc);
    }
    float x = acc / (1.f + expf(-acc));

    if (do_norm) {
        float ss = x * x;
#pragma unroll
        for (int s = 1; s < 64; s <<= 1) ss += __shfl_xor(ss, s, 64);
        __shared__ float red[2];
        if ((threadIdx.x & 63) == 0) red[threadIdx.x >> 6] = ss;
        __syncthreads();
        const float tot = red[0] + red[1];
        x = x * rsqrtf(tot + 1e-6f) * scale;
    }
    out[off] = x;
}

// ---------------------------------------------------------------------------
__global__ void beta_kernel(const float* __restrict__ hid, const float* __restrict__ Wb,
                            float* __restrict__ beta) {
    const int m = blockIdx.x;
    const int t = threadIdx.x;
    const int h = t & 15;
    const int sl = t >> 4;

    const float* hp = hid + (size_t)m * DD + sl * 128;
    const float* wp = Wb + (size_t)sl * 128 * HH + h;
    float p = 0.f;
#pragma unroll 8
    for (int i = 0; i < 128; ++i) p = fmaf(hp[i], wp[i * HH], p);

    __shared__ float red[256];
    red[t] = p;
    __syncthreads();
    if (t < HH) {
        float s = 0.f;
#pragma unroll
        for (int i = 0; i < 16; ++i) s += red[i * 16 + t];
        beta[(size_t)m * HH + t] = 1.f / (1.f + expf(-s));
    }
}

// ---------------------------------------------------------------------------
// decay (fallback layout [b,t,h,g]): d values
// ---------------------------------------------------------------------------
__global__ void decay_kernel(const float* __restrict__ g2, const float* __restrict__ A_log,
                             const float* __restrict__ dt_bias, float* __restrict__ decay) {
    const int idx = blockIdx.x * 256 + threadIdx.x;
    const int g = idx & (NG - 1);
    const int h = (idx >> 3) & (HH - 1);
    const float x = g2[idx] + dt_bias[h * NG + g];
    const float sp = (x > 20.f) ? x : log1pf(expf(x));
    decay[idx] = expf(-expf(A_log[h]) * sp);
}

// ---------------------------------------------------------------------------
// LOG-decay, t-tiled [bh][tblk][g][8]
// ---------------------------------------------------------------------------
__global__ void ldecay_kernel_t(const float* __restrict__ g2, const float* __restrict__ A_log,
                                const float* __restrict__ dt_bias, float* __restrict__ ldtr) {
    const int idx = blockIdx.x * 256 + threadIdx.x;   // (b,t,h,g)
    const int g = idx & 7, h = (idx >> 3) & 15;
    const int t = (idx >> 7) & 1023, b = idx >> 17;
    const float x = g2[idx] + dt_bias[h * NG + g];
    const float sp = (x > 20.f) ? x : log1pf(expf(x));
    const float ld = -expf(A_log[h]) * sp;
    const int bh = b * 16 + h, tblk = t >> 3, tj = t & 7;
    ldtr[((size_t)(bh * 128 + tblk)) * 64 + g * 8 + tj] = ld;
}

// ---------------------------------------------------------------------------
// amat_kernel: per (bh, chunk) tile, fully parallel (2048 blocks):
//   A[t][r]  = sum_g exp(L_t[g]-L_r[g]) Gram_g(k_t,k_r)   (r<t)
//   Aq[t][r] = sum_g exp(L_t[g]-L_r[g]) Gram_g(q_t,k_r)   (r<=t)
//   N = (I + diag(beta) A)^{-1} diag(beta)   (lower-tri 16x16)
// Outputs: Ng[tile][16][16], Aqg[tile][16][16] fp32.
// ---------------------------------------------------------------------------
__launch_bounds__(256)
__global__ void amat_kernel(const float* __restrict__ kt_g, const float* __restrict__ qt_g,
                            const float* __restrict__ ldec, const float* __restrict__ beta,
                            float* __restrict__ Ng, float* __restrict__ Aqg) {
    __shared__ float kt2[128][17];
    __shared__ float qt2[128][17];
    __shared__ float scr0[4][16][16];
    __shared__ float scr1[4][16][16];
    __shared__ float Am[16][21];
    __shared__ float ld16[16][8];
    __shared__ float Lc[17][8];
    __shared__ float betas[16];

    const int bid = blockIdx.x;          // bh*64 + ch
    const int bh = bid >> 6, ch = bid & 63;
    const int b = bh >> 4, h = bh & 15;
    const int tid = threadIdx.x;
    const int w = tid >> 6, lane = tid & 63, l15 = lane & 15, lk = lane >> 4;
    const int tb0 = ch * 2, t0 = ch * 16;
    const size_t kbase = (size_t)bh * 131072;

    // stage k,q ([c][t]), ld16, betas
    {
        const int c = tid & 127, half = tid >> 7;
        const float* srk = kt_g + kbase + (size_t)(tb0 + half) * 1024 + c * 8;
        float4 a0 = *(const float4*)(srk);
        float4 a1 = *(const float4*)(srk + 4);
        kt2[c][half * 8 + 0] = a0.x; kt2[c][half * 8 + 1] = a0.y;
        kt2[c][half * 8 + 2] = a0.z; kt2[c][half * 8 + 3] = a0.w;
        kt2[c][half * 8 + 4] = a1.x; kt2[c][half * 8 + 5] = a1.y;
        kt2[c][half * 8 + 6] = a1.z; kt2[c][half * 8 + 7] = a1.w;
        const float* srq = qt_g + kbase + (size_t)(tb0 + half) * 1024 + c * 8;
        a0 = *(const float4*)(srq);
        a1 = *(const float4*)(srq + 4);
        qt2[c][half * 8 + 0] = a0.x; qt2[c][half * 8 + 1] = a0.y;
        qt2[c][half * 8 + 2] = a0.z; qt2[c][half * 8 + 3] = a0.w;
        qt2[c][half * 8 + 4] = a1.x; qt2[c][half * 8 + 5] = a1.y;
        qt2[c][half * 8 + 6] = a1.z; qt2[c][half * 8 + 7] = a1.w;
        if (tid < 128) {
            const int t = tid >> 3, g = tid & 7;
            ld16[t][g] = ldec[(size_t)bh * 8192 + (size_t)(tb0 + (t >> 3)) * 64 + g * 8 + (t & 7)];
        }
        if (tid < 16) betas[tid] = beta[((size_t)b * 1024 + t0 + tid) * 16 + h];
    }
    __syncthreads();
    if (tid < 8) {
        float run = 0.f;
        Lc[0][tid] = 0.f;
#pragma unroll
        for (int j = 0; j < 16; ++j) { run += ld16[j][tid]; Lc[j + 1][tid] = run; }
    }
    __syncthreads();

    // Gram per group + exp fold (wave w handles groups 2w, 2w+1)
    float apart[4] = {0.f, 0.f, 0.f, 0.f};
    float aqpart[4] = {0.f, 0.f, 0.f, 0.f};
#pragma unroll
    for (int gi = 0; gi < 2; ++gi) {
        const int g = 2 * w + gi;
        float kv[8], qv[8];
        if (lk < 2) {
#pragma unroll
            for (int j = 0; j < 8; ++j) {
                kv[j] = kt2[g * 16 + lk * 8 + j][l15];
                qv[j] = qt2[g * 16 + lk * 8 + j][l15];
            }
        } else {
#pragma unroll
            for (int j = 0; j < 8; ++j) { kv[j] = 0.f; qv[j] = 0.f; }
        }
        bf16x8 kh, kl2, qh2, ql2;
        split8arr(kv, kh, kl2);
        split8arr(qv, qh2, ql2);
        f32x4 gk = (f32x4){0.f, 0.f, 0.f, 0.f};
        f32x4 gq = (f32x4){0.f, 0.f, 0.f, 0.f};
        gk = MFMA16(kh, kh, gk); gk = MFMA16(kh, kl2, gk); gk = MFMA16(kl2, kh, gk);
        gq = MFMA16(qh2, kh, gq); gq = MFMA16(qh2, kl2, gq); gq = MFMA16(ql2, kh, gq);
#pragma unroll
        for (int j = 0; j < 4; ++j) {
            const int t = lk * 4 + j, r = l15;
            const float f = expf(Lc[t + 1][g] - Lc[r + 1][g]);
            apart[j] = fmaf(f, gk[j], apart[j]);
            aqpart[j] = fmaf(f, gq[j], aqpart[j]);
        }
    }
#pragma unroll
    for (int j = 0; j < 4; ++j) {
        scr0[w][lk * 4 + j][l15] = apart[j];
        scr1[w][lk * 4 + j][l15] = aqpart[j];
    }
    __syncthreads();

    // reduce + mask; write Aq to global; keep A in LDS
    {
        const int t = tid >> 4, r = tid & 15;
        const float sa = scr0[0][t][r] + scr0[1][t][r] + scr0[2][t][r] + scr0[3][t][r];
        const float sq = scr1[0][t][r] + scr1[1][t][r] + scr1[2][t][r] + scr1[3][t][r];
        Am[t][r] = (r < t) ? sa : 0.f;
        Aqg[(size_t)bid * 256 + t * 16 + r] = (r <= t) ? sq : 0.f;
    }
    __syncthreads();

    // N = (I + diag(beta) A)^{-1} diag(beta): column col per thread
    if (tid < 16) {
        const int col = tid;
        float x[16];
#pragma unroll
        for (int t = 0; t < 16; ++t) {
            float acc = (t == col) ? betas[col] : 0.f;
#pragma unroll
            for (int r = 0; r < 16; ++r)
                if (r < t) acc = fmaf(-betas[t] * Am[t][r], x[r], acc);
            x[t] = acc;
        }
#pragma unroll
        for (int t = 0; t < 16; ++t) Ng[(size_t)bid * 256 + t * 16 + col] = x[t];
    }
}

// ---------------------------------------------------------------------------
// Chunked recurrence, serial part only (N/Aq precomputed).
// grid: 256 blocks = 32 bh x 8 v-slices; 256 thr (4 waves). S[128][16] in LDS.
// Per chunk (4 barriers): stage -> LUT -> per-wave full-width E0/Oq + d=N(v-E0)
// (+ o by wave0) -> S update. Each wave computes E0/d redundantly (no cross-
// wave reduce); layouts chosen bank-conflict-free (stride 17 / 21).
// ---------------------------------------------------------------------------
__launch_bounds__(256)
__global__ void chunk_recur(const float* __restrict__ qt_g, const float* __restrict__ kt_g,
                            const float* __restrict__ vt_g, const float* __restrict__ ldec,
                            const float* __restrict__ Ng, const float* __restrict__ Aqg,
                            float* __restrict__ o) {
    __shared__ float kt2[128][17];
    __shared__ float qt2[128][17];
    __shared__ float Sl[128][17];
    __shared__ float vb[16][21];
    __shared__ float Nm[16][21];
    __shared__ float Aqm[16][21];
    __shared__ float e0w[4][16][21];
    __shared__ float dlw[4][16][21];
    __shared__ float ld16[16][8];
    __shared__ float Lc[17][8];
    __shared__ float wexp[16][8];
    __shared__ float fct[16][8];

    const int bid = blockIdx.x;
    const int xcd = bid & 7, rr = bid >> 3;
    const int bh = xcd * 4 + (rr >> 3);   // bh grouped per XCD
    const int slice = rr & 7;
    const int b = bh >> 4, h = bh & 15;
    const int tid = threadIdx.x;
    const int w = tid >> 6, lane = tid & 63, l15 = lane & 15, lk = lane >> 4;
    const size_t kbase = (size_t)bh * 131072;
    const size_t obase = ((size_t)b * 1024 * 16 + h) * 128;

    for (int i = tid; i < 128 * 17; i += 256) ((float*)Sl)[i] = 0.f;
    __syncthreads();

    for (int ch = 0; ch < 64; ++ch) {
        const int tb0 = ch * 2, t0 = ch * 16;
        const size_t tile = (size_t)(bh * 64 + ch) * 256;

        // ---- stage ----
        {
            const int c = tid & 127, half = tid >> 7;
            const float* srk = kt_g + kbase + (size_t)(tb0 + half) * 1024 + c * 8;
            float4 a0 = *(const float4*)(srk);
            float4 a1 = *(const float4*)(srk + 4);
            kt2[c][half * 8 + 0] = a0.x; kt2[c][half * 8 + 1] = a0.y;
            kt2[c][half * 8 + 2] = a0.z; kt2[c][half * 8 + 3] = a0.w;
            kt2[c][half * 8 + 4] = a1.x; kt2[c][half * 8 + 5] = a1.y;
            kt2[c][half * 8 + 6] = a1.z; kt2[c][half * 8 + 7] = a1.w;
            const float* srq = qt_g + kbase + (size_t)(tb0 + half) * 1024 + c * 8;
            a0 = *(const float4*)(srq);
            a1 = *(const float4*)(srq + 4);
            qt2[c][half * 8 + 0] = a0.x; qt2[c][half * 8 + 1] = a0.y;
            qt2[c][half * 8 + 2] = a0.z; qt2[c][half * 8 + 3] = a0.w;
            qt2[c][half * 8 + 4] = a1.x; qt2[c][half * 8 + 5] = a1.y;
            qt2[c][half * 8 + 6] = a1.z; qt2[c][half * 8 + 7] = a1.w;

            const int tv = tid >> 4, u = tid & 15;
            vb[tv][u] = vt_g[kbase + (size_t)(tb0 + (tv >> 3)) * 1024 +
                             (size_t)(slice * 16 + u) * 8 + (tv & 7)];
            Nm[tv][u] = Ng[tile + tid];
            Aqm[tv][u] = Aqg[tile + tid];
            if (tid < 128) {
                const int t = tid >> 3, g = tid & 7;
                ld16[t][g] = ldec[(size_t)bh * 8192 + (size_t)(tb0 + (t >> 3)) * 64 + g * 8 + (t & 7)];
            }
        }
        __syncthreads();
        if (tid < 8) {
            float run = 0.f;
            Lc[0][tid] = 0.f;
#pragma unroll
            for (int j = 0; j < 16; ++j) { run += ld16[j][tid]; Lc[j + 1][tid] = run; }
        }
        __syncthreads();
        if (tid < 128) {
            wexp[tid >> 3][tid & 7] = expf(Lc[(tid >> 3) + 1][tid & 7]);
        } else {
            const int r = (tid - 128) >> 3, g = (tid - 128) & 7;
            fct[r][g] = expf(Lc[16][g] - Lc[r + 1][g]);
        }
        __syncthreads();

        // ---- per-wave full-width E0, Oq ----
        f32x4 e0 = (f32x4){0.f, 0.f, 0.f, 0.f};
        f32x4 oq = (f32x4){0.f, 0.f, 0.f, 0.f};
#pragma unroll
        for (int cb = 0; cb < 128; cb += 32) {
            const int c0 = cb + lk * 8;
            const int g3 = c0 >> 4;
            const float ex = wexp[l15][g3];
            float wv8[8], qv8[8], sv8[8];
#pragma unroll
            for (int j = 0; j < 8; ++j) {
                wv8[j] = kt2[c0 + j][l15] * ex;
                qv8[j] = qt2[c0 + j][l15] * ex;
                sv8[j] = Sl[c0 + j][l15];
            }
            bf16x8 wh, wl, qh, ql, sh, sl2;
            split8arr(wv8, wh, wl);
            split8arr(qv8, qh, ql);
            split8arr(sv8, sh, sl2);
            e0 = MFMA16(wh, sh, e0); e0 = MFMA16(wh, sl2, e0); e0 = MFMA16(wl, sh, e0);
            oq = MFMA16(qh, sh, oq); oq = MFMA16(qh, sl2, oq); oq = MFMA16(ql, sh, oq);
        }
#pragma unroll
        for (int j = 0; j < 4; ++j) e0w[w][lk * 4 + j][l15] = e0[j];

        // ---- d = N (v - E0) (per wave) ----
        {
            float xv[8], nv[8];
            if (lk < 2) {
#pragma unroll
                for (int j = 0; j < 8; ++j) {
                    const int r = lk * 8 + j;
                    xv[j] = vb[r][l15] - e0w[w][r][l15];
                    nv[j] = Nm[l15][r];
                }
            } else {
#pragma unroll
                for (int j = 0; j < 8; ++j) { xv[j] = 0.f; nv[j] = 0.f; }
            }
            bf16x8 xh, xl, nh, nl;
            split8arr(xv, xh, xl);
            split8arr(nv, nh, nl);
            f32x4 d = (f32x4){0.f, 0.f, 0.f, 0.f};
            d = MFMA16(nh, xh, d); d = MFMA16(nh, xl, d); d = MFMA16(nl, xh, d);
#pragma unroll
            for (int j = 0; j < 4; ++j) dlw[w][lk * 4 + j][l15] = d[j];
        }

        // ---- o output (wave 0 only) ----
        if (w == 0) {
            float av[8], bv[8];
            if (lk < 2) {
#pragma unroll
                for (int j = 0; j < 8; ++j) {
                    const int r = lk * 8 + j;
                    av[j] = Aqm[l15][r];
                    bv[j] = dlw[0][r][l15];
                }
            } else {
#pragma unroll
                for (int j = 0; j < 8; ++j) { av[j] = 0.f; bv[j] = 0.f; }
            }
            bf16x8 ah2, al2, dh, dlo;
            split8arr(av, ah2, al2);
            split8arr(bv, dh, dlo);
            f32x4 oc = oq;
            oc = MFMA16(ah2, dh, oc); oc = MFMA16(ah2, dlo, oc); oc = MFMA16(al2, dh, oc);
#pragma unroll
            for (int j = 0; j < 4; ++j)
                o[obase + (size_t)(t0 + lk * 4 + j) * 2048 + slice * 16 + l15] = oc[j];
        }
        __syncthreads();   // all Sl reads complete before updates

        // ---- S update (each wave: rows [32w, 32w+32)) ----
        {
            float dv8[8];
            if (lk < 2) {
#pragma unroll
                for (int j = 0; j < 8; ++j) dv8[j] = dlw[w][lk * 8 + j][l15];
            } else {
#pragma unroll
                for (int j = 0; j < 8; ++j) dv8[j] = 0.f;
            }
            bf16x8 dh2, dl2;
            split8arr(dv8, dh2, dl2);
#pragma unroll
            for (int tau = 0; tau < 2; ++tau) {
                const int ctile = w * 32 + tau * 16;
                const int g8 = ctile >> 4;
                const float w15 = wexp[15][g8];
                float av[8];
                if (lk < 2) {
#pragma unroll
                    for (int j = 0; j < 8; ++j) {
                        const int r = lk * 8 + j;
                        av[j] = kt2[ctile + l15][r] * fct[r][g8];
                    }
                } else {
#pragma unroll
                    for (int j = 0; j < 8; ++j) av[j] = 0.f;
                }
                bf16x8 kh2, kl3;
                split8arr(av, kh2, kl3);
                f32x4 sc;
#pragma unroll
                for (int j = 0; j < 4; ++j) sc[j] = Sl[ctile + lk * 4 + j][l15] * w15;
                sc = MFMA16(kh2, dh2, sc); sc = MFMA16(kh2, dl2, sc); sc = MFMA16(kl3, dh2, sc);
#pragma unroll
                for (int j = 0; j < 4; ++j) Sl[ctile + lk * 4 + j][l15] = sc[j];
            }
        }
        __syncthreads();
    }
}

// ---------------------------------------------------------------------------
// Old-layout recurrence (fallback path only).
// ---------------------------------------------------------------------------
__launch_bounds__(256, 4)
__global__ void recur_kernel(const float* __restrict__ q, const float* __restrict__ k,
                             const float* __restrict__ vv, const float* __restrict__ decay,
                             const float* __restrict__ beta, float* __restrict__ o) {
    const int blk = blockIdx.x;
    const int vblk = blk & 31;
    const int bh = blk >> 5;
    const int b = bh >> 4, h = bh & 15;
    const int w = threadIdx.x >> 6;
    const int lane = threadIdx.x & 63;
    const int vi = vblk * 4 + w;

    float S0 = 0.f, S1 = 0.f;
    const size_t strideT = (size_t)HH * DV;
    const size_t strideT2 = strideT >> 1;
    const size_t base = ((size_t)b * TT * HH + h) * DV;

    const float2* kp = (const float2*)(k + base) + lane;
    const float2* qp = (const float2*)(q + base) + lane;
    const float* vp = vv + base + vi;
    const float* bp = beta + (size_t)b * TT * HH + h;
    const float* dp = decay + ((size_t)b * TT * HH + h) * NG + (lane >> 3);

    float2 kv = kp[0], qv = qp[0];
    float vtv = vp[0], bt = bp[0], dt = dp[0];

    for (int t = 0; t < TT; ++t) {
        const float2 kc = kv, qc = qv;
        const float vc = vtv, bc = bt, dc = dt;

        const int tn = (t + 1 < TT) ? (t + 1) : t;
        kv = kp[(size_t)tn * strideT2];
        qv = qp[(size_t)tn * strideT2];
        vtv = vp[(size_t)tn * strideT];
        bt = bp[(size_t)tn * HH];
        dt = dp[(size_t)tn * HH * NG];

        S0 *= dc;
        S1 *= dc;
        float e = fmaf(kc.x, S0, kc.y * S1);
        e = dpp_sum64(e);
        const float err = readlanef(e, 63);
        const float delta = bc * (vc - err);
        S0 = fmaf(kc.x, delta, S0);
        S1 = fmaf(kc.y, delta, S1);
        float oo = fmaf(qc.x, S0, qc.y * S1);
        oo = dpp_sum64(oo);
        if (lane == 63) o[base + (size_t)t * strideT + vi] = oo;
    }
}

// ---------------------------------------------------------------------------
// Gated RMSNorm -> fp32 y (fallback)
// ---------------------------------------------------------------------------
__global__ void gated_rmsnorm(const float* __restrict__ o,
                              const float* __restrict__ gpre, const float* __restrict__ bg,
                              const float* __restrict__ norm_w, float* __restrict__ y) {
    const int blk = blockIdx.x;
    const int h = blk & 15;
    const int dv = threadIdx.x;
    const size_t off = (size_t)blk * DV + dv;

    const float ov = o[off];
    const float g = gpre[off] + bg[h * 128 + dv];
    const float yv = ov * (g / (1.f + expf(-g)));

    float ss = yv * yv;
#pragma unroll
    for (int s = 1; s < 64; s <<= 1) ss += __shfl_xor(ss, s, 64);
    __shared__ float red[2];
    if ((threadIdx.x & 63) == 0) red[threadIdx.x >> 6] = ss;
    __syncthreads();
    const float mean = (red[0] + red[1]) * (1.f / 128.f);
    y[off] = yv * rsqrtf(mean + 1e-5f) * norm_w[dv];
}

// ---------------------------------------------------------------------------
// Gated RMSNorm -> bf16 hi/lo split y
// ---------------------------------------------------------------------------
__global__ void gated_rmsnorm_split(const float* __restrict__ o,
                                    const float* __restrict__ gpre, const float* __restrict__ bg,
                                    const float* __restrict__ norm_w,
                                    unsigned short* __restrict__ yh,
                                    unsigned short* __restrict__ yl) {
    const int blk = blockIdx.x;
    const int h = blk & 15;
    const int dv = threadIdx.x;
    const size_t off = (size_t)blk * DV + dv;

    const float ov = o[off];
    const float g = gpre[off] + bg[h * 128 + dv];
    const float yv = ov * (g / (1.f + expf(-g)));

    float ss = yv * yv;
#pragma unroll
    for (int s = 1; s < 64; s <<= 1) ss += __shfl_xor(ss, s, 64);
    __shared__ float red[2];
    if ((threadIdx.x & 63) == 0) red[threadIdx.x >> 6] = ss;
    __syncthreads();
    const float mean = (red[0] + red[1]) * (1.f / 128.f);
    const float y = yv * rsqrtf(mean + 1e-5f) * norm_w[dv];
    unsigned short hh, ll;
    bsplit(y, hh, ll);
    yh[off] = hh;
    yl[off] = ll;
}

// ---------------------------------------------------------------------------
extern "C" void kernel_launch(void* const* d_in, const int* in_sizes, int n_in,
                              void* d_out, int out_size, void* d_ws, size_t ws_size,
                              hipStream_t stream) {
    const float* hid    = (const float*)d_in[0];
    const float* Wq     = (const float*)d_in[1];
    const float* Wk     = (const float*)d_in[2];
    const float* Wv     = (const float*)d_in[3];
    const float* conv_q = (const float*)d_in[4];
    const float* conv_k = (const float*)d_in[5];
    const float* conv_v = (const float*)d_in[6];
    const float* Wf1    = (const float*)d_in[7];
    const float* Wf2    = (const float*)d_in[8];
    const float* Wb     = (const float*)d_in[9];
    const float* A_log  = (const float*)d_in[10];
    const float* dt_bias= (const float*)d_in[11];
    const float* Wg     = (const float*)d_in[12];
    const float* bg     = (const float*)d_in[13];
    const float* norm_w = (const float*)d_in[14];
    const float* Wo     = (const float*)d_in[15];
    float* out = (float*)d_out;

    const size_t N1  = (size_t)2048 * 2048;
    const size_t N1B = N1 * 4;
    const int M = BB * TT;

    const size_t NEED_NEW = 9 * N1B + 4390912;

    if (ws_size >= NEED_NEW) {
        // ---------------- MFMA split-precision path ----------------
        char* W = (char*)d_ws;
        unsigned short* hidh = (unsigned short*)W;
        unsigned short* hidl = hidh + N1;
        float* o = (float*)W;
        char* RB = W + N1B;
        unsigned short* Wqth = (unsigned short*)RB;
        unsigned short* Wqtl = Wqth + N1;
        unsigned short* Wkth = Wqtl + N1;
        unsigned short* Wktl = Wkth + N1;
        unsigned short* Wvth = Wktl + N1;
        unsigned short* Wvtl = Wvth + N1;
        unsigned short* Wgth = Wvtl + N1;
        unsigned short* Wgtl = Wgth + N1;
        float* qn = (float*)RB;
        float* kn = qn + N1;
        float* vn = kn + N1;
        // Ng/Aqg overlay qn (dead after t-tile transpose): 2048 tiles x 256 f32
        float* Ng  = qn;
        float* Aqg = qn + 524288;
        char* RC = W + 5 * N1B;
        float* qpre = (float*)RC;
        float* kpre = qpre + N1;
        float* vpre = kpre + N1;
        float* gpre = vpre + N1;
        float* qn_t = qpre;
        float* kn_t = kpre;
        float* vn_t = vpre;
        unsigned short* Woth = (unsigned short*)RC;
        unsigned short* Wotl = Woth + N1;
        unsigned short* yh = (unsigned short*)(RC + N1B);
        unsigned short* yl = yh + N1;
        char* RD = W + 9 * N1B;
        float* g1b   = (float*)RD;
        float* g2b   = g1b + 262144;
        float* betab = g2b + 262144;
        float* ldecb = betab + 32768;      // 262144 (t-tiled log-decay)
        unsigned short* wf1th = (unsigned short*)(ldecb + 262144);
        unsigned short* wf1tl = wf1th + 262144;

        // 1. splits / transposes
        split_mat<<<1024, 256, 0, stream>>>(hid, hidh, hidl);
        TS4 ts;
        ts.in[0] = Wq; ts.oh[0] = Wqth; ts.ol[0] = Wqtl;
        ts.in[1] = Wk; ts.oh[1] = Wkth; ts.ol[1] = Wktl;
        ts.in[2] = Wv; ts.oh[2] = Wvth; ts.ol[2] = Wvtl;
        ts.in[3] = Wg; ts.oh[3] = Wgth; ts.ol[3] = Wgtl;
        transpose_split4<<<dim3(32, 32, 4), 256, 0, stream>>>(ts);
        transpose_split<<<dim3(2, 32), 256, 0, stream>>>(Wf1, wf1th, wf1tl, 128, 2048);

        // 2. fused input projections
        GemmArgs fa;
        fa.Ah = hidh; fa.Al = hidl;
        fa.Bh[0] = Wqth; fa.Bl[0] = Wqtl; fa.C[0] = qpre;
        fa.Bh[1] = Wkth; fa.Bl[1] = Wktl; fa.C[1] = kpre;
        fa.Bh[2] = Wvth; fa.Bl[2] = Wvtl; fa.C[2] = vpre;
        fa.Bh[3] = Wgth; fa.Bl[3] = Wgtl; fa.C[3] = gpre;
        fa.Bh[4] = wf1th; fa.Bl[4] = wf1tl; fa.C[4] = g1b;
        gemm_split<<<dim3(65, 16), 256, 0, stream>>>(fa, 1);

        // 3. beta, g2, log-decay (t-tiled)
        beta_kernel<<<M, 256, 0, stream>>>(hid, Wb, betab);
        sgemm128<<<dim3(1, 16), 256, 0, stream>>>(g1b, Wf2, g2b, M, 128, 128);
        ldecay_kernel_t<<<(M * HH * NG) / 256, 256, 0, stream>>>(g2b, A_log, dt_bias, ldecb);

        // 4. conv + silu (+ l2norm)
        ConvArgs ca;
        ca.pre[0] = qpre; ca.w[0] = conv_q; ca.out[0] = qn; ca.scale[0] = SCALE_Q; ca.do_norm[0] = 1;
        ca.pre[1] = kpre; ca.w[1] = conv_k; ca.out[1] = kn; ca.scale[1] = 1.f;     ca.do_norm[1] = 1;
        ca.pre[2] = vpre; ca.w[2] = conv_v; ca.out[2] = vn; ca.scale[2] = 1.f;     ca.do_norm[2] = 0;
        conv_silu_norm3<<<dim3(M * HH, 3), 128, 0, stream>>>(ca);

        // 5. t-tile transpose
        T3 tt;
        tt.in[0] = qn; tt.out[0] = qn_t;
        tt.in[1] = kn; tt.out[1] = kn_t;
        tt.in[2] = vn; tt.out[2] = vn_t;
        transpose_tile3<<<dim3(4096, 3), 256, 0, stream>>>(tt);

        // 6. intra-chunk matrices (parallel) + serial chunked recurrence
        amat_kernel<<<2048, 256, 0, stream>>>(kn_t, qn_t, ldecb, betab, Ng, Aqg);
        chunk_recur<<<256, 256, 0, stream>>>(qn_t, kn_t, vn_t, ldecb, Ng, Aqg, o);

        // 7. transpose Wo (over dead qn_t)
        transpose_split<<<dim3(32, 32), 256, 0, stream>>>(Wo, Woth, Wotl, 2048, 2048);

        // 8. gated rmsnorm -> y split (over dead kn_t)
        gated_rmsnorm_split<<<M * HH, 128, 0, stream>>>(o, gpre, bg, norm_w, yh, yl);

        // 9. output projection
        GemmArgs oa;
        oa.Ah = yh; oa.Al = yl;
        for (int i = 0; i < 5; ++i) { oa.Bh[i] = Woth; oa.Bl[i] = Wotl; oa.C[i] = out; }
        gemm_split<<<dim3(16, 16), 256, 0, stream>>>(oa, 0);
    } else {
        // ---------------- fallback: fp32 path ----------------
        float* ws = (float*)d_ws;
        float* qpre = ws + 0 * N1;
        float* kpre = ws + 1 * N1;
        float* vpre = ws + 2 * N1;
        float* gpre = ws + 3 * N1;
        float* qn   = ws + 4 * N1;
        float* kn   = ws + 5 * N1;
        float* vn   = ws + 6 * N1;
        float* g1b  = ws + 7 * N1;
        float* g2b  = g1b + (size_t)BB * TT * DV;
        float* betab= g2b + (size_t)BB * TT * HH * NG;
        float* decayb = betab + (size_t)BB * TT * HH;
        float* o = qpre;
        float* y = vpre;

        sgemm128<<<dim3(16, 16), 256, 0, stream>>>(hid, Wq, qpre, M, 2048, 2048);
        sgemm128<<<dim3(16, 16), 256, 0, stream>>>(hid, Wk, kpre, M, 2048, 2048);
        sgemm128<<<dim3(16, 16), 256, 0, stream>>>(hid, Wv, vpre, M, 2048, 2048);
        sgemm128<<<dim3(16, 16), 256, 0, stream>>>(hid, Wg, gpre, M, 2048, 2048);
        sgemm128<<<dim3(1, 16), 256, 0, stream>>>(hid, Wf1, g1b, M, 128, 2048);
        sgemm128<<<dim3(1, 16), 256, 0, stream>>>(g1b, Wf2, g2b, M, 128, 128);
        beta_kernel<<<M, 256, 0, stream>>>(hid, Wb, betab);

        conv_silu_norm<<<M * HH, 128, 0, stream>>>(qpre, conv_q, qn, SCALE_Q, 1);
        conv_silu_norm<<<M * HH, 128, 0, stream>>>(kpre, conv_k, kn, 1.f, 1);
        conv_silu_norm<<<M * HH, 128, 0, stream>>>(vpre, conv_v, vn, 1.f, 0);

        decay_kernel<<<(M * HH * NG) / 256, 256, 0, stream>>>(g2b, A_log, dt_bias, decayb);

        recur_kernel<<<BB * HH * (DV / 4), 256, 0, stream>>>(qn, kn, vn, decayb, betab, o);

        gated_rmsnorm<<<M * HH, 128, 0, stream>>>(o, gpre, bg, norm_w, y);

        sgemm128<<<dim3(16, 16), 256, 0, stream>>>(y, Wo, out, M, 2048, 2048);
    }
}

// Round 15
// 627.590 us; speedup vs baseline: 1.6442x; 1.2989x over previous
//
#include <hip/hip_runtime.h>
#include <hip/hip_bf16.h>
#include <math.h>

// Problem constants (fixed by setup_inputs)
#define BB 2
#define TT 1024
#define DD 2048
#define HH 16
#define DK 128
#define DV 128
#define NG 8
#define GG 16
#define SCALE_Q 0.08838834764831845f  // 128^-0.5

typedef __attribute__((ext_vector_type(8))) short bf16x8;
typedef __attribute__((ext_vector_type(4))) float f32x4;

#define MFMA16(a, b, c) __builtin_amdgcn_mfma_f32_16x16x32_bf16((a), (b), (c), 0, 0, 0)

// bf16 split helpers (RNE)
__device__ __forceinline__ unsigned short f2bf(float v) {
    unsigned u = __float_as_uint(v);
    return (unsigned short)((u + 0x7FFFu + ((u >> 16) & 1u)) >> 16);
}
__device__ __forceinline__ float bf2f(unsigned short h) {
    return __uint_as_float(((unsigned)h) << 16);
}
__device__ __forceinline__ void bsplit(float v, unsigned short& h, unsigned short& l) {
    h = f2bf(v);
    l = f2bf(v - bf2f(h));
}
__device__ __forceinline__ void split8arr(const float* v, bf16x8& hi, bf16x8& lo) {
#pragma unroll
    for (int j = 0; j < 8; ++j) {
        unsigned short h, l;
        bsplit(v[j], h, l);
        hi[j] = (short)h;
        lo[j] = (short)l;
    }
}
__device__ __forceinline__ bf16x8 zero8() {
    bf16x8 z;
#pragma unroll
    for (int i = 0; i < 8; ++i) z[i] = 0;
    return z;
}

// ---------------------------------------------------------------------------
// DPP wave64 sum (fallback recurrence only).
// ---------------------------------------------------------------------------
__device__ __forceinline__ float dpp_sum64(float x) {
    x += __int_as_float(__builtin_amdgcn_update_dpp(0, __float_as_int(x), 0x111, 0xf, 0xf, true));
    x += __int_as_float(__builtin_amdgcn_update_dpp(0, __float_as_int(x), 0x112, 0xf, 0xf, true));
    x += __int_as_float(__builtin_amdgcn_update_dpp(0, __float_as_int(x), 0x114, 0xf, 0xf, true));
    x += __int_as_float(__builtin_amdgcn_update_dpp(0, __float_as_int(x), 0x118, 0xf, 0xf, true));
    x += __int_as_float(__builtin_amdgcn_update_dpp(0, __float_as_int(x), 0x142, 0xa, 0xf, false));
    x += __int_as_float(__builtin_amdgcn_update_dpp(0, __float_as_int(x), 0x143, 0xc, 0xf, false));
    return x;
}
__device__ __forceinline__ float readlanef(float x, int l) {
    return __int_as_float(__builtin_amdgcn_readlane(__float_as_int(x), l));
}

// ---------------------------------------------------------------------------
// split: fp32 [n] -> bf16 hi/lo
// ---------------------------------------------------------------------------
__global__ void split_mat(const float* __restrict__ in, unsigned short* __restrict__ oh,
                          unsigned short* __restrict__ ol) {
    const int i0 = (blockIdx.x * 256 + threadIdx.x) * 16;
#pragma unroll
    for (int r = 0; r < 4; ++r) {
        const float4 v = *(const float4*)(in + i0 + r * 4);
        unsigned short h0, l0, h1, l1, h2, l2, h3, l3;
        bsplit(v.x, h0, l0); bsplit(v.y, h1, l1);
        bsplit(v.z, h2, l2); bsplit(v.w, h3, l3);
        short4 hh; hh.x = (short)h0; hh.y = (short)h1; hh.z = (short)h2; hh.w = (short)h3;
        short4 ll; ll.x = (short)l0; ll.y = (short)l1; ll.z = (short)l2; ll.w = (short)l3;
        *(short4*)(oh + i0 + r * 4) = hh;
        *(short4*)(ol + i0 + r * 4) = ll;
    }
}

// ---------------------------------------------------------------------------
// transpose + split: in fp32 [Kin][Nin] -> out bf16 hi/lo [Nin][Kin]
// ---------------------------------------------------------------------------
__device__ __forceinline__ void tsplit_body(const float* __restrict__ in,
                                            unsigned short* __restrict__ oh,
                                            unsigned short* __restrict__ ol,
                                            int Nin, int Kin, int bx, int by, int tid) {
    __shared__ float t[64][65];
    const int c4 = (tid & 15) * 4, r0 = tid >> 4;
#pragma unroll
    for (int rep = 0; rep < 4; ++rep) {
        const int r = r0 + rep * 16;
        const float4 v = *(const float4*)(in + (size_t)(by * 64 + r) * Nin + bx * 64 + c4);
        t[r][c4] = v.x; t[r][c4 + 1] = v.y; t[r][c4 + 2] = v.z; t[r][c4 + 3] = v.w;
    }
    __syncthreads();
#pragma unroll
    for (int rep = 0; rep < 4; ++rep) {
        const int n = r0 + rep * 16;
        short4 hh, ll;
        unsigned short h, l;
        bsplit(t[c4 + 0][n], h, l); hh.x = (short)h; ll.x = (short)l;
        bsplit(t[c4 + 1][n], h, l); hh.y = (short)h; ll.y = (short)l;
        bsplit(t[c4 + 2][n], h, l); hh.z = (short)h; ll.z = (short)l;
        bsplit(t[c4 + 3][n], h, l); hh.w = (short)h; ll.w = (short)l;
        const size_t o = (size_t)(bx * 64 + n) * Kin + by * 64 + c4;
        *(short4*)(oh + o) = hh;
        *(short4*)(ol + o) = ll;
    }
}

__global__ void transpose_split(const float* __restrict__ in, unsigned short* __restrict__ oh,
                                unsigned short* __restrict__ ol, int Nin, int Kin) {
    tsplit_body(in, oh, ol, Nin, Kin, blockIdx.x, blockIdx.y, threadIdx.x);
}

struct TS4 { const float* in[4]; unsigned short* oh[4]; unsigned short* ol[4]; };
__global__ void transpose_split4(TS4 p) {
    const int z = blockIdx.z;
    tsplit_body(p.in[z], p.oh[z], p.ol[z], 2048, 2048, blockIdx.x, blockIdx.y, threadIdx.x);
}

// ---------------------------------------------------------------------------
// t-tile transpose x3: in [B][1024][2048] -> out tiled [bh][tblk][cl][8]
// ---------------------------------------------------------------------------
struct T3 { const float* in[3]; float* out[3]; };
__global__ void transpose_tile3(T3 p) {
    __shared__ float tl[8][128];
    const int z = blockIdx.y;
    const float* __restrict__ in = p.in[z];
    float* __restrict__ out = p.out[z];
    const int blk = blockIdx.x;
    const int bh = blk >> 7, tblk = blk & 127;
    const int b = bh >> 4, h = bh & 15;
    const int tid = threadIdx.x;

    const int tt = tid >> 5, c4 = (tid & 31) * 4;
    const float4 v = *(const float4*)(in + ((size_t)(b * 1024 + tblk * 8 + tt)) * 2048 + h * 128 + c4);
    tl[tt][c4] = v.x; tl[tt][c4 + 1] = v.y; tl[tt][c4 + 2] = v.z; tl[tt][c4 + 3] = v.w;
    __syncthreads();

    const int cl = tid >> 1, tj0 = (tid & 1) * 4;
    float4 w4;
    w4.x = tl[tj0 + 0][cl]; w4.y = tl[tj0 + 1][cl];
    w4.z = tl[tj0 + 2][cl]; w4.w = tl[tj0 + 3][cl];
    *(float4*)(out + ((size_t)blk * 128 + cl) * 8 + tj0) = w4;
}

// ---------------------------------------------------------------------------
// Split-precision bf16 MFMA GEMM (verified) + XCD-aware bijective swizzle:
// each XCD owns a contiguous bx-range (B-panel locality) with by varying
// fastest (A-panel reuse inside the XCD's L2).
// ---------------------------------------------------------------------------
struct GemmArgs {
    const unsigned short* Ah; const unsigned short* Al;
    const unsigned short* Bh[5]; const unsigned short* Bl[5];
    float* C[5];
};

#define AHI 0
#define ALO 8192
#define BHI 16384
#define BLO 24576

#define GL2LDS(g, s) __builtin_amdgcn_global_load_lds( \
    (const __attribute__((address_space(1))) void*)(g), \
    (__attribute__((address_space(3))) void*)(s), 16, 0, 0)

__launch_bounds__(256, 3)
__global__ void gemm_split(GemmArgs p, int fused) {
    __shared__ __attribute__((aligned(16))) char lds[32768];
    const int tid = threadIdx.x;

    // XCD-aware bijective swizzle (gridDim.y == 16 for all launches)
    int bx, by;
    {
        const int gw = gridDim.x;
        const int lin = blockIdx.y * gw + blockIdx.x;
        const int per = (gw * 16) >> 3;         // total/8 (1040->130, 256->32)
        const int swz = (lin & 7) * per + (lin >> 3);
        bx = swz >> 4;
        by = swz & 15;
    }

    int sel, nloc, ldc;
    if (fused) {
        if (bx < 64) { sel = bx >> 4; nloc = (bx & 15) * 128; ldc = 2048; }
        else         { sel = 4;       nloc = 0;               ldc = 128;  }
    } else { sel = 0; nloc = bx * 128; ldc = 2048; }

    const unsigned short* Asrc_h = p.Ah + (size_t)(by * 128) * 2048;
    const unsigned short* Asrc_l = p.Al + (size_t)(by * 128) * 2048;
    const unsigned short* Bsrc_h = p.Bh[sel] + (size_t)nloc * 2048;
    const unsigned short* Bsrc_l = p.Bl[sel] + (size_t)nloc * 2048;

    const int r0 = tid >> 2, ps0 = tid & 3;
    const int r1 = (tid + 256) >> 2, ps1 = tid & 3;
    const size_t ga0 = (size_t)r0 * 2048 + (size_t)((ps0 ^ ((r0 >> 1) & 3)) * 8);
    const size_t ga1 = (size_t)r1 * 2048 + (size_t)((ps1 ^ ((r1 >> 1) & 3)) * 8);
    const int lb0 = (tid & 192) * 16;
    const int lb1 = (256 + (tid & 192)) * 16;

    const int lane = tid & 63;
    const int l15 = lane & 15, kgrp = lane >> 4;
    const int w = tid >> 6, wm = w >> 1, wn = w & 1;
    const int swzf = kgrp ^ ((l15 >> 1) & 3);
    const int fro = l15 * 64 + swzf * 16;
    const int aoff = wm * 4096, boff = wn * 4096;

    f32x4 acc[4][4];
#pragma unroll
    for (int i = 0; i < 4; ++i)
#pragma unroll
        for (int j = 0; j < 4; ++j) acc[i][j] = (f32x4){0.f, 0.f, 0.f, 0.f};

    for (int k0 = 0; k0 < 2048; k0 += 32) {
        __syncthreads();
        GL2LDS(Asrc_h + k0 + ga0, lds + AHI + lb0);
        GL2LDS(Asrc_h + k0 + ga1, lds + AHI + lb1);
        GL2LDS(Asrc_l + k0 + ga0, lds + ALO + lb0);
        GL2LDS(Asrc_l + k0 + ga1, lds + ALO + lb1);
        GL2LDS(Bsrc_h + k0 + ga0, lds + BHI + lb0);
        GL2LDS(Bsrc_h + k0 + ga1, lds + BHI + lb1);
        GL2LDS(Bsrc_l + k0 + ga0, lds + BLO + lb0);
        GL2LDS(Bsrc_l + k0 + ga1, lds + BLO + lb1);
        __syncthreads();

        bf16x8 ah[4], al4[4], bh4[4], bl4[4];
#pragma unroll
        for (int f = 0; f < 4; ++f) {
            ah[f]  = *(const bf16x8*)(lds + AHI + aoff + f * 1024 + fro);
            al4[f] = *(const bf16x8*)(lds + ALO + aoff + f * 1024 + fro);
            bh4[f] = *(const bf16x8*)(lds + BHI + boff + f * 1024 + fro);
            bl4[f] = *(const bf16x8*)(lds + BLO + boff + f * 1024 + fro);
        }
#pragma unroll
        for (int i = 0; i < 4; ++i)
#pragma unroll
            for (int j = 0; j < 4; ++j) {
                acc[i][j] = MFMA16(ah[i],  bh4[j], acc[i][j]);
                acc[i][j] = MFMA16(ah[i],  bl4[j], acc[i][j]);
                acc[i][j] = MFMA16(al4[i], bh4[j], acc[i][j]);
            }
    }

    float* cb = p.C[sel];
    const int m0 = by * 128 + wm * 64 + kgrp * 4;
    const int n0 = nloc + wn * 64 + l15;
#pragma unroll
    for (int i = 0; i < 4; ++i)
#pragma unroll
        for (int t = 0; t < 4; ++t) {
            float* cp = cb + (size_t)(m0 + i * 16 + t) * ldc + n0;
#pragma unroll
            for (int j = 0; j < 4; ++j) cp[j * 16] = acc[i][j][t];
        }
}

// ---------------------------------------------------------------------------
// Generic fp32 SGEMM (g1@Wf2 and fallback).
// ---------------------------------------------------------------------------
#define GBM 128
#define GBN 128
#define GBK 16

__launch_bounds__(256)
__global__ void sgemm128(const float* __restrict__ A, const float* __restrict__ B,
                         float* __restrict__ C, int M, int N, int K) {
    __shared__ float As[GBK][GBM + 4];
    __shared__ float Bs[GBK][GBN + 4];

    const int tid = threadIdx.x;
    const int bm = blockIdx.y * GBM;
    const int bn = blockIdx.x * GBN;

    const int arow = tid >> 2;
    const int acol = (tid & 3) << 2;
    const int brow = tid >> 5;
    const int bcol = (tid & 31) << 2;
    const int ty = tid >> 4;
    const int tx = tid & 15;

    float acc[8][8];
#pragma unroll
    for (int i = 0; i < 8; ++i)
#pragma unroll
        for (int j = 0; j < 8; ++j) acc[i][j] = 0.f;

    for (int k0 = 0; k0 < K; k0 += GBK) {
#pragma unroll
        for (int r = 0; r < 2; ++r) {
            const int m = arow + r * 64;
            const float4 av = *(const float4*)(A + (size_t)(bm + m) * K + k0 + acol);
            As[acol + 0][m] = av.x;
            As[acol + 1][m] = av.y;
            As[acol + 2][m] = av.z;
            As[acol + 3][m] = av.w;
        }
#pragma unroll
        for (int r = 0; r < 2; ++r) {
            const int kk = brow + r * 8;
            *(float4*)(&Bs[kk][bcol]) =
                *(const float4*)(B + (size_t)(k0 + kk) * N + bn + bcol);
        }
        __syncthreads();

#pragma unroll
        for (int kk = 0; kk < GBK; ++kk) {
            float a[8], bf[8];
#pragma unroll
            for (int i = 0; i < 8; ++i) a[i] = As[kk][ty * 8 + i];
#pragma unroll
            for (int j = 0; j < 8; ++j) bf[j] = Bs[kk][tx * 8 + j];
#pragma unroll
            for (int i = 0; i < 8; ++i)
#pragma unroll
                for (int j = 0; j < 8; ++j)
                    acc[i][j] = fmaf(a[i], bf[j], acc[i][j]);
        }
        __syncthreads();
    }

#pragma unroll
    for (int i = 0; i < 8; ++i) {
        float* cp = C + (size_t)(bm + ty * 8 + i) * N + bn + tx * 8;
        *(float4*)(cp + 0) = make_float4(acc[i][0], acc[i][1], acc[i][2], acc[i][3]);
        *(float4*)(cp + 4) = make_float4(acc[i][4], acc[i][5], acc[i][6], acc[i][7]);
    }
}

// ---------------------------------------------------------------------------
// conv + silu (+ l2norm), 3-in-1 and single variants.
// ---------------------------------------------------------------------------
struct ConvArgs {
    const float* pre[3]; const float* w[3]; float* out[3];
    float scale[3]; int do_norm[3];
};
__global__ void conv_silu_norm3(ConvArgs p) {
    const int z = blockIdx.y;
    const float* __restrict__ pre = p.pre[z];
    const float* __restrict__ wv = p.w[z];
    float* __restrict__ out = p.out[z];
    const float scale = p.scale[z];
    const int do_norm = p.do_norm[z];

    const int blk = blockIdx.x;
    const int h = blk & 15;
    const int bt = blk >> 4;
    const int t = bt & (TT - 1);
    const int b = bt >> 10;
    const int dk = threadIdx.x;
    const int c = h * 128 + dk;

    const size_t off = ((size_t)(b * TT + t)) * DD + c;
    float acc = 0.f;
#pragma unroll
    for (int j = 0; j < 4; ++j) {
        const int tt = t - 3 + j;
        const float x = (tt >= 0) ? pre[off + (size_t)(j - 3) * DD] : 0.f;
        acc = fmaf(x, wv[c * 4 + j], acc);
    }
    float x = acc / (1.f + expf(-acc));

    if (do_norm) {
        float ss = x * x;
#pragma unroll
        for (int s = 1; s < 64; s <<= 1) ss += __shfl_xor(ss, s, 64);
        __shared__ float red[2];
        if ((threadIdx.x & 63) == 0) red[threadIdx.x >> 6] = ss;
        __syncthreads();
        const float tot = red[0] + red[1];
        x = x * rsqrtf(tot + 1e-6f) * scale;
    }
    out[off] = x;
}

__global__ void conv_silu_norm(const float* __restrict__ pre, const float* __restrict__ w,
                               float* __restrict__ out, float scale, int do_norm) {
    const int blk = blockIdx.x;
    const int h = blk & 15;
    const int bt = blk >> 4;
    const int t = bt & (TT - 1);
    const int b = bt >> 10;
    const int dk = threadIdx.x;
    const int c = h * 128 + dk;

    const size_t off = ((size_t)(b * TT + t)) * DD + c;
    float acc = 0.f;
#pragma unroll
    for (int j = 0; j < 4; ++j) {
        const int tt = t - 3 + j;
        const float x = (tt >= 0) ? pre[off + (size_t)(j - 3) * DD] : 0.f;
        acc = fmaf(x, w[c * 4 + j], acc);
    }
    float x = acc / (1.f + expf(-acc));

    if (do_norm) {
        float ss = x * x;
#pragma unroll
        for (int s = 1; s < 64; s <<= 1) ss += __shfl_xor(ss, s, 64);
        __shared__ float red[2];
        if ((threadIdx.x & 63) == 0) red[threadIdx.x >> 6] = ss;
        __syncthreads();
        const float tot = red[0] + red[1];
        x = x * rsqrtf(tot + 1e-6f) * scale;
    }
    out[off] = x;
}

// ---------------------------------------------------------------------------
__global__ void beta_kernel(const float* __restrict__ hid, const float* __restrict__ Wb,
                            float* __restrict__ beta) {
    const int m = blockIdx.x;
    const int t = threadIdx.x;
    const int h = t & 15;
    const int sl = t >> 4;

    const float* hp = hid + (size_t)m * DD + sl * 128;
    const float* wp = Wb + (size_t)sl * 128 * HH + h;
    float p = 0.f;
#pragma unroll 8
    for (int i = 0; i < 128; ++i) p = fmaf(hp[i], wp[i * HH], p);

    __shared__ float red[256];
    red[t] = p;
    __syncthreads();
    if (t < HH) {
        float s = 0.f;
#pragma unroll
        for (int i = 0; i < 16; ++i) s += red[i * 16 + t];
        beta[(size_t)m * HH + t] = 1.f / (1.f + expf(-s));
    }
}

// ---------------------------------------------------------------------------
// decay (fallback layout [b,t,h,g]): d values
// ---------------------------------------------------------------------------
__global__ void decay_kernel(const float* __restrict__ g2, const float* __restrict__ A_log,
                             const float* __restrict__ dt_bias, float* __restrict__ decay) {
    const int idx = blockIdx.x * 256 + threadIdx.x;
    const int g = idx & (NG - 1);
    const int h = (idx >> 3) & (HH - 1);
    const float x = g2[idx] + dt_bias[h * NG + g];
    const float sp = (x > 20.f) ? x : log1pf(expf(x));
    decay[idx] = expf(-expf(A_log[h]) * sp);
}

// ---------------------------------------------------------------------------
// LOG-decay, t-tiled [bh][tblk][g][8]
// ---------------------------------------------------------------------------
__global__ void ldecay_kernel_t(const float* __restrict__ g2, const float* __restrict__ A_log,
                                const float* __restrict__ dt_bias, float* __restrict__ ldtr) {
    const int idx = blockIdx.x * 256 + threadIdx.x;   // (b,t,h,g)
    const int g = idx & 7, h = (idx >> 3) & 15;
    const int t = (idx >> 7) & 1023, b = idx >> 17;
    const float x = g2[idx] + dt_bias[h * NG + g];
    const float sp = (x > 20.f) ? x : log1pf(expf(x));
    const float ld = -expf(A_log[h]) * sp;
    const int bh = b * 16 + h, tblk = t >> 3, tj = t & 7;
    ldtr[((size_t)(bh * 128 + tblk)) * 64 + g * 8 + tj] = ld;
}

// ---------------------------------------------------------------------------
// prep_kernel: per (bh, chunk) tile, fully parallel (2048 blocks).
// Computes and stores PRE-SPLIT bf16 operands for the serial kernel:
//   N = (I + diag(beta) A)^{-1} diag(beta)  -> Nh/Nl [tile][t][r]
//   Aq (masked r<=t)                        -> Aqh/Aql [tile][t][r]
//   Kdec[c][t] = k[c][t]*exp(L16-L_t)       -> Kdh/Kdl [tile][c][t]
//   wexpg[tile][t*8+g] = exp(L_t[g])  (t=15 row doubles as exp(L16))
// Math identical to the verified round-14 kernels.
// ---------------------------------------------------------------------------
__launch_bounds__(256)
__global__ void prep_kernel(const float* __restrict__ kt_g, const float* __restrict__ qt_g,
                            const float* __restrict__ ldec, const float* __restrict__ beta,
                            unsigned short* __restrict__ Nh, unsigned short* __restrict__ Nl,
                            unsigned short* __restrict__ Aqh, unsigned short* __restrict__ Aql,
                            unsigned short* __restrict__ Kdh, unsigned short* __restrict__ Kdl,
                            float* __restrict__ wexpg) {
    __shared__ float kt2[128][17];
    __shared__ float qt2[128][17];
    __shared__ float scr0[4][16][17];
    __shared__ float scr1[4][16][17];
    __shared__ float Am[16][21];
    __shared__ float Nm[16][21];
    __shared__ float ld16[16][8];
    __shared__ float Lc[17][8];
    __shared__ float fctl[16][9];
    __shared__ float betas[16];

    const int bid = blockIdx.x;          // bh*64 + ch
    const int bh = bid >> 6, ch = bid & 63;
    const int b = bh >> 4, h = bh & 15;
    const int tid = threadIdx.x;
    const int w = tid >> 6, lane = tid & 63, l15 = lane & 15, lk = lane >> 4;
    const int tb0 = ch * 2, t0 = ch * 16;
    const size_t kbase = (size_t)bh * 131072;
    const size_t tile = (size_t)bid;

    // stage k,q ([c][t]), ld16, betas
    {
        const int c = tid & 127, half = tid >> 7;
        const float* srk = kt_g + kbase + (size_t)(tb0 + half) * 1024 + c * 8;
        float4 a0 = *(const float4*)(srk);
        float4 a1 = *(const float4*)(srk + 4);
        kt2[c][half * 8 + 0] = a0.x; kt2[c][half * 8 + 1] = a0.y;
        kt2[c][half * 8 + 2] = a0.z; kt2[c][half * 8 + 3] = a0.w;
        kt2[c][half * 8 + 4] = a1.x; kt2[c][half * 8 + 5] = a1.y;
        kt2[c][half * 8 + 6] = a1.z; kt2[c][half * 8 + 7] = a1.w;
        const float* srq = qt_g + kbase + (size_t)(tb0 + half) * 1024 + c * 8;
        a0 = *(const float4*)(srq);
        a1 = *(const float4*)(srq + 4);
        qt2[c][half * 8 + 0] = a0.x; qt2[c][half * 8 + 1] = a0.y;
        qt2[c][half * 8 + 2] = a0.z; qt2[c][half * 8 + 3] = a0.w;
        qt2[c][half * 8 + 4] = a1.x; qt2[c][half * 8 + 5] = a1.y;
        qt2[c][half * 8 + 6] = a1.z; qt2[c][half * 8 + 7] = a1.w;
        if (tid < 128) {
            const int t = tid >> 3, g = tid & 7;
            ld16[t][g] = ldec[(size_t)bh * 8192 + (size_t)(tb0 + (t >> 3)) * 64 + g * 8 + (t & 7)];
        }
        if (tid < 16) betas[tid] = beta[((size_t)b * 1024 + t0 + tid) * 16 + h];
    }
    __syncthreads();
    if (tid < 8) {
        float run = 0.f;
        Lc[0][tid] = 0.f;
#pragma unroll
        for (int j = 0; j < 16; ++j) { run += ld16[j][tid]; Lc[j + 1][tid] = run; }
    }
    __syncthreads();

    // Gram per group + exp fold (wave w handles groups 2w, 2w+1)
    float apart[4] = {0.f, 0.f, 0.f, 0.f};
    float aqpart[4] = {0.f, 0.f, 0.f, 0.f};
#pragma unroll
    for (int gi = 0; gi < 2; ++gi) {
        const int g = 2 * w + gi;
        float kv[8], qv[8];
        if (lk < 2) {
#pragma unroll
            for (int j = 0; j < 8; ++j) {
                kv[j] = kt2[g * 16 + lk * 8 + j][l15];
                qv[j] = qt2[g * 16 + lk * 8 + j][l15];
            }
        } else {
#pragma unroll
            for (int j = 0; j < 8; ++j) { kv[j] = 0.f; qv[j] = 0.f; }
        }
        bf16x8 kh, kl2, qh2, ql2;
        split8arr(kv, kh, kl2);
        split8arr(qv, qh2, ql2);
        f32x4 gk = (f32x4){0.f, 0.f, 0.f, 0.f};
        f32x4 gq = (f32x4){0.f, 0.f, 0.f, 0.f};
        gk = MFMA16(kh, kh, gk); gk = MFMA16(kh, kl2, gk); gk = MFMA16(kl2, kh, gk);
        gq = MFMA16(qh2, kh, gq); gq = MFMA16(qh2, kl2, gq); gq = MFMA16(ql2, kh, gq);
#pragma unroll
        for (int j = 0; j < 4; ++j) {
            const int t = lk * 4 + j, r = l15;
            const float f = expf(Lc[t + 1][g] - Lc[r + 1][g]);
            apart[j] = fmaf(f, gk[j], apart[j]);
            aqpart[j] = fmaf(f, gq[j], aqpart[j]);
        }
    }
#pragma unroll
    for (int j = 0; j < 4; ++j) {
        scr0[w][lk * 4 + j][l15] = apart[j];
        scr1[w][lk * 4 + j][l15] = aqpart[j];
    }
    __syncthreads();

    // reduce + mask; store Aq SPLIT; keep A in LDS
    {
        const int t = tid >> 4, r = tid & 15;
        const float sa = scr0[0][t][r] + scr0[1][t][r] + scr0[2][t][r] + scr0[3][t][r];
        const float sq = scr1[0][t][r] + scr1[1][t][r] + scr1[2][t][r] + scr1[3][t][r];
        Am[t][r] = (r < t) ? sa : 0.f;
        const float aqm = (r <= t) ? sq : 0.f;
        unsigned short hh, ll;
        bsplit(aqm, hh, ll);
        Aqh[tile * 256 + t * 16 + r] = hh;
        Aql[tile * 256 + t * 16 + r] = ll;
    }
    __syncthreads();

    // N solve (tid<16) || wexpg + fct (tid in [128,256))
    if (tid < 16) {
        const int col = tid;
        float x[16];
#pragma unroll
        for (int t = 0; t < 16; ++t) {
            float acc = (t == col) ? betas[col] : 0.f;
#pragma unroll
            for (int r = 0; r < 16; ++r)
                if (r < t) acc = fmaf(-betas[t] * Am[t][r], x[r], acc);
            x[t] = acc;
        }
#pragma unroll
        for (int t = 0; t < 16; ++t) Nm[t][col] = x[t];
    } else if (tid >= 128) {
        const int u = tid - 128;
        const int t = u >> 3, g = u & 7;
        wexpg[tile * 128 + u] = expf(Lc[t + 1][g]);
        fctl[t][g] = expf(Lc[16][g] - Lc[t + 1][g]);
    }
    __syncthreads();

    // store N split + Kdec split
    {
        const int t = tid >> 4, r = tid & 15;
        unsigned short hh, ll;
        bsplit(Nm[t][r], hh, ll);
        Nh[tile * 256 + t * 16 + r] = hh;
        Nl[tile * 256 + t * 16 + r] = ll;
    }
    {
        const int c = tid >> 1, t0e = (tid & 1) * 8;
        const int g = c >> 4;
        float vals[8];
#pragma unroll
        for (int j = 0; j < 8; ++j) vals[j] = kt2[c][t0e + j] * fctl[t0e + j][g];
        bf16x8 hi, lo;
        split8arr(vals, hi, lo);
        *(bf16x8*)(Kdh + tile * 2048 + c * 16 + t0e) = hi;
        *(bf16x8*)(Kdl + tile * 2048 + c * 16 + t0e) = lo;
    }
}

// ---------------------------------------------------------------------------
// Serial chunked recurrence (all operands precomputed/pre-split).
// grid: 256 = 32 bh x 8 v-slices (XCD-grouped); 256 thr (4 waves).
// Per chunk (3 barriers):
//   A: wave w computes E0/Oq partials on its K-quarter (W,Q~ gathered+scaled)
//   B: wave0: d = N(v - E0); o = sum(Oq) + Aq@d  -> write o
//   C: all waves: S[rows 32w..] = exp(L16) o S + Kdec^T @ d
// ---------------------------------------------------------------------------
__launch_bounds__(256)
__global__ void chunk_recur(const float* __restrict__ qt_g, const float* __restrict__ kt_g,
                            const float* __restrict__ vt_g,
                            const unsigned short* __restrict__ Nh, const unsigned short* __restrict__ Nl,
                            const unsigned short* __restrict__ Aqh, const unsigned short* __restrict__ Aql,
                            const unsigned short* __restrict__ Kdh, const unsigned short* __restrict__ Kdl,
                            const float* __restrict__ wexpg, float* __restrict__ o) {
    __shared__ float Sl[128][17];
    __shared__ float scr0[4][16][17];
    __shared__ float scr1[4][16][17];
    __shared__ float vb[16][17];
    __shared__ float xb[16][17];
    __shared__ float dl[16][17];

    const int bid = blockIdx.x;
    const int xcd = bid & 7, rr = bid >> 3;
    const int bh = xcd * 4 + (rr >> 3);   // bh grouped per XCD
    const int slice = rr & 7;
    const int b = bh >> 4, h = bh & 15;
    const int tid = threadIdx.x;
    const int w = tid >> 6, lane = tid & 63, l15 = lane & 15, lk = lane >> 4;
    const size_t kbase = (size_t)bh * 131072;
    const size_t obase = ((size_t)b * 1024 * 16 + h) * 128;
    const int cq = w * 32 + lk * 8;       // this lane's 8-channel base
    const int gq2 = cq >> 4;              // its gate group

    for (int i = tid; i < 128 * 17; i += 256) ((float*)Sl)[i] = 0.f;
    __syncthreads();

    for (int ch = 0; ch < 64; ++ch) {
        const size_t tile = (size_t)(bh * 64 + ch);
        const size_t gbase = kbase + (size_t)(ch * 2) * 1024;

        // stage v (all threads; consumed in phase B)
        {
            const int tv = tid >> 4, u = tid & 15;
            vb[tv][u] = vt_g[kbase + (size_t)(ch * 2 + (tv >> 3)) * 1024 +
                             (size_t)(slice * 16 + u) * 8 + (tv & 7)];
        }

        // ---- phase A: per-wave K-quarter E0/Oq partials ----
        {
            const size_t rbase = gbase + (size_t)(l15 >> 3) * 1024 + (size_t)(l15 & 7);
            const float ex = wexpg[tile * 128 + l15 * 8 + gq2];
            float kv[8], qv[8], sv[8];
#pragma unroll
            for (int j = 0; j < 8; ++j) {
                kv[j] = kt_g[rbase + (size_t)(cq + j) * 8] * ex;
                qv[j] = qt_g[rbase + (size_t)(cq + j) * 8] * ex;
                sv[j] = Sl[cq + j][l15];
            }
            bf16x8 wh, wl, qh, ql, sh, sl2;
            split8arr(kv, wh, wl);
            split8arr(qv, qh, ql);
            split8arr(sv, sh, sl2);
            f32x4 e0 = (f32x4){0.f, 0.f, 0.f, 0.f};
            f32x4 oq = (f32x4){0.f, 0.f, 0.f, 0.f};
            e0 = MFMA16(wh, sh, e0); e0 = MFMA16(wh, sl2, e0); e0 = MFMA16(wl, sh, e0);
            oq = MFMA16(qh, sh, oq); oq = MFMA16(qh, sl2, oq); oq = MFMA16(ql, sh, oq);
#pragma unroll
            for (int j = 0; j < 4; ++j) {
                scr0[w][lk * 4 + j][l15] = e0[j];
                scr1[w][lk * 4 + j][l15] = oq[j];
            }
        }
        __syncthreads();

        // ---- phase B: wave0 only ----
        if (w == 0) {
            const int tt = lane >> 2, v0 = (lane & 3) * 4;
#pragma unroll
            for (int u = 0; u < 4; ++u) {
                const int v = v0 + u;
                xb[tt][v] = vb[tt][v] -
                    (scr0[0][tt][v] + scr0[1][tt][v] + scr0[2][tt][v] + scr0[3][tt][v]);
            }
            // d = N @ x
            bf16x8 nh = zero8(), nl = zero8();
            float xv[8];
            if (lk < 2) {
                nh = *(const bf16x8*)(Nh + tile * 256 + l15 * 16 + lk * 8);
                nl = *(const bf16x8*)(Nl + tile * 256 + l15 * 16 + lk * 8);
#pragma unroll
                for (int j = 0; j < 8; ++j) xv[j] = xb[lk * 8 + j][l15];
            } else {
#pragma unroll
                for (int j = 0; j < 8; ++j) xv[j] = 0.f;
            }
            bf16x8 xh, xl;
            split8arr(xv, xh, xl);
            f32x4 d = (f32x4){0.f, 0.f, 0.f, 0.f};
            d = MFMA16(nh, xh, d); d = MFMA16(nh, xl, d); d = MFMA16(nl, xh, d);
#pragma unroll
            for (int j = 0; j < 4; ++j) dl[lk * 4 + j][l15] = d[j];

            // o = sum(Oq) + Aq @ d
            f32x4 oc;
#pragma unroll
            for (int j = 0; j < 4; ++j) {
                const int t = lk * 4 + j;
                oc[j] = scr1[0][t][l15] + scr1[1][t][l15] + scr1[2][t][l15] + scr1[3][t][l15];
            }
            bf16x8 ah = zero8(), al = zero8();
            float dv[8];
            if (lk < 2) {
                ah = *(const bf16x8*)(Aqh + tile * 256 + l15 * 16 + lk * 8);
                al = *(const bf16x8*)(Aql + tile * 256 + l15 * 16 + lk * 8);
#pragma unroll
                for (int j = 0; j < 8; ++j) dv[j] = dl[lk * 8 + j][l15];
            } else {
#pragma unroll
                for (int j = 0; j < 8; ++j) dv[j] = 0.f;
            }
            bf16x8 dh, dlo;
            split8arr(dv, dh, dlo);
            oc = MFMA16(ah, dh, oc); oc = MFMA16(ah, dlo, oc); oc = MFMA16(al, dh, oc);
#pragma unroll
            for (int j = 0; j < 4; ++j)
                o[obase + (size_t)(ch * 16 + lk * 4 + j) * 2048 + slice * 16 + l15] = oc[j];
        }
        __syncthreads();

        // ---- phase C: S update (wave w: rows [32w, 32w+32)) ----
        {
            float dv[8];
            if (lk < 2) {
#pragma unroll
                for (int j = 0; j < 8; ++j) dv[j] = dl[lk * 8 + j][l15];
            } else {
#pragma unroll
                for (int j = 0; j < 8; ++j) dv[j] = 0.f;
            }
            bf16x8 dh2, dl2;
            split8arr(dv, dh2, dl2);
#pragma unroll
            for (int tau = 0; tau < 2; ++tau) {
                const int rt = w * 2 + tau;     // row-tile index = gate group
                const float w16 = wexpg[tile * 128 + 120 + rt];
                bf16x8 kh = zero8(), kl = zero8();
                if (lk < 2) {
                    kh = *(const bf16x8*)(Kdh + tile * 2048 + (size_t)(rt * 16 + l15) * 16 + lk * 8);
                    kl = *(const bf16x8*)(Kdl + tile * 2048 + (size_t)(rt * 16 + l15) * 16 + lk * 8);
                }
                f32x4 sc;
#pragma unroll
                for (int j = 0; j < 4; ++j) sc[j] = Sl[rt * 16 + lk * 4 + j][l15] * w16;
                sc = MFMA16(kh, dh2, sc); sc = MFMA16(kh, dl2, sc); sc = MFMA16(kl, dh2, sc);
#pragma unroll
                for (int j = 0; j < 4; ++j) Sl[rt * 16 + lk * 4 + j][l15] = sc[j];
            }
        }
        __syncthreads();
    }
}

// ---------------------------------------------------------------------------
// Old-layout recurrence (fallback path only).
// ---------------------------------------------------------------------------
__launch_bounds__(256, 4)
__global__ void recur_kernel(const float* __restrict__ q, const float* __restrict__ k,
                             const float* __restrict__ vv, const float* __restrict__ decay,
                             const float* __restrict__ beta, float* __restrict__ o) {
    const int blk = blockIdx.x;
    const int vblk = blk & 31;
    const int bh = blk >> 5;
    const int b = bh >> 4, h = bh & 15;
    const int w = threadIdx.x >> 6;
    const int lane = threadIdx.x & 63;
    const int vi = vblk * 4 + w;

    float S0 = 0.f, S1 = 0.f;
    const size_t strideT = (size_t)HH * DV;
    const size_t strideT2 = strideT >> 1;
    const size_t base = ((size_t)b * TT * HH + h) * DV;

    const float2* kp = (const float2*)(k + base) + lane;
    const float2* qp = (const float2*)(q + base) + lane;
    const float* vp = vv + base + vi;
    const float* bp = beta + (size_t)b * TT * HH + h;
    const float* dp = decay + ((size_t)b * TT * HH + h) * NG + (lane >> 3);

    float2 kv = kp[0], qv = qp[0];
    float vtv = vp[0], bt = bp[0], dt = dp[0];

    for (int t = 0; t < TT; ++t) {
        const float2 kc = kv, qc = qv;
        const float vc = vtv, bc = bt, dc = dt;

        const int tn = (t + 1 < TT) ? (t + 1) : t;
        kv = kp[(size_t)tn * strideT2];
        qv = qp[(size_t)tn * strideT2];
        vtv = vp[(size_t)tn * strideT];
        bt = bp[(size_t)tn * HH];
        dt = dp[(size_t)tn * HH * NG];

        S0 *= dc;
        S1 *= dc;
        float e = fmaf(kc.x, S0, kc.y * S1);
        e = dpp_sum64(e);
        const float err = readlanef(e, 63);
        const float delta = bc * (vc - err);
        S0 = fmaf(kc.x, delta, S0);
        S1 = fmaf(kc.y, delta, S1);
        float oo = fmaf(qc.x, S0, qc.y * S1);
        oo = dpp_sum64(oo);
        if (lane == 63) o[base + (size_t)t * strideT + vi] = oo;
    }
}

// ---------------------------------------------------------------------------
// Gated RMSNorm -> fp32 y (fallback)
// ---------------------------------------------------------------------------
__global__ void gated_rmsnorm(const float* __restrict__ o,
                              const float* __restrict__ gpre, const float* __restrict__ bg,
                              const float* __restrict__ norm_w, float* __restrict__ y) {
    const int blk = blockIdx.x;
    const int h = blk & 15;
    const int dv = threadIdx.x;
    const size_t off = (size_t)blk * DV + dv;

    const float ov = o[off];
    const float g = gpre[off] + bg[h * 128 + dv];
    const float yv = ov * (g / (1.f + expf(-g)));

    float ss = yv * yv;
#pragma unroll
    for (int s = 1; s < 64; s <<= 1) ss += __shfl_xor(ss, s, 64);
    __shared__ float red[2];
    if ((threadIdx.x & 63) == 0) red[threadIdx.x >> 6] = ss;
    __syncthreads();
    const float mean = (red[0] + red[1]) * (1.f / 128.f);
    y[off] = yv * rsqrtf(mean + 1e-5f) * norm_w[dv];
}

// ---------------------------------------------------------------------------
// Gated RMSNorm -> bf16 hi/lo split y
// ---------------------------------------------------------------------------
__global__ void gated_rmsnorm_split(const float* __restrict__ o,
                                    const float* __restrict__ gpre, const float* __restrict__ bg,
                                    const float* __restrict__ norm_w,
                                    unsigned short* __restrict__ yh,
                                    unsigned short* __restrict__ yl) {
    const int blk = blockIdx.x;
    const int h = blk & 15;
    const int dv = threadIdx.x;
    const size_t off = (size_t)blk * DV + dv;

    const float ov = o[off];
    const float g = gpre[off] + bg[h * 128 + dv];
    const float yv = ov * (g / (1.f + expf(-g)));

    float ss = yv * yv;
#pragma unroll
    for (int s = 1; s < 64; s <<= 1) ss += __shfl_xor(ss, s, 64);
    __shared__ float red[2];
    if ((threadIdx.x & 63) == 0) red[threadIdx.x >> 6] = ss;
    __syncthreads();
    const float mean = (red[0] + red[1]) * (1.f / 128.f);
    const float y = yv * rsqrtf(mean + 1e-5f) * norm_w[dv];
    unsigned short hh, ll;
    bsplit(y, hh, ll);
    yh[off] = hh;
    yl[off] = ll;
}

// ---------------------------------------------------------------------------
extern "C" void kernel_launch(void* const* d_in, const int* in_sizes, int n_in,
                              void* d_out, int out_size, void* d_ws, size_t ws_size,
                              hipStream_t stream) {
    const float* hid    = (const float*)d_in[0];
    const float* Wq     = (const float*)d_in[1];
    const float* Wk     = (const float*)d_in[2];
    const float* Wv     = (const float*)d_in[3];
    const float* conv_q = (const float*)d_in[4];
    const float* conv_k = (const float*)d_in[5];
    const float* conv_v = (const float*)d_in[6];
    const float* Wf1    = (const float*)d_in[7];
    const float* Wf2    = (const float*)d_in[8];
    const float* Wb     = (const float*)d_in[9];
    const float* A_log  = (const float*)d_in[10];
    const float* dt_bias= (const float*)d_in[11];
    const float* Wg     = (const float*)d_in[12];
    const float* bg     = (const float*)d_in[13];
    const float* norm_w = (const float*)d_in[14];
    const float* Wo     = (const float*)d_in[15];
    float* out = (float*)d_out;

    const size_t N1  = (size_t)2048 * 2048;
    const size_t N1B = N1 * 4;
    const int M = BB * TT;

    const size_t NEED_NEW = 9 * N1B + 4390912;

    if (ws_size >= NEED_NEW) {
        // ---------------- MFMA split-precision path ----------------
        char* W = (char*)d_ws;
        unsigned short* hidh = (unsigned short*)W;
        unsigned short* hidl = hidh + N1;
        float* o = (float*)W;
        char* RB = W + N1B;
        unsigned short* Wqth = (unsigned short*)RB;
        unsigned short* Wqtl = Wqth + N1;
        unsigned short* Wkth = Wqtl + N1;
        unsigned short* Wktl = Wkth + N1;
        unsigned short* Wvth = Wktl + N1;
        unsigned short* Wvtl = Wvth + N1;
        unsigned short* Wgth = Wvtl + N1;
        unsigned short* Wgtl = Wgth + N1;
        float* qn = (float*)RB;
        float* kn = qn + N1;
        float* vn = kn + N1;
        // prep outputs overlay qn/kn slots (dead after t-tile transpose):
        unsigned short* Nh  = (unsigned short*)qn;           // 2048*256
        unsigned short* Nl  = Nh + 524288;
        unsigned short* Aqh = Nl + 524288;
        unsigned short* Aql = Aqh + 524288;
        float* wexpg = (float*)(Aql + 524288);               // 2048*128 f32
        unsigned short* Kdh = (unsigned short*)kn;           // 2048*2048
        unsigned short* Kdl = Kdh + 4194304;
        char* RC = W + 5 * N1B;
        float* qpre = (float*)RC;
        float* kpre = qpre + N1;
        float* vpre = kpre + N1;
        float* gpre = vpre + N1;
        float* qn_t = qpre;
        float* kn_t = kpre;
        float* vn_t = vpre;
        unsigned short* Woth = (unsigned short*)RC;
        unsigned short* Wotl = Woth + N1;
        unsigned short* yh = (unsigned short*)(RC + N1B);
        unsigned short* yl = yh + N1;
        char* RD = W + 9 * N1B;
        float* g1b   = (float*)RD;
        float* g2b   = g1b + 262144;
        float* betab = g2b + 262144;
        float* ldecb = betab + 32768;      // 262144 (t-tiled log-decay)
        unsigned short* wf1th = (unsigned short*)(ldecb + 262144);
        unsigned short* wf1tl = wf1th + 262144;

        // 1. splits / transposes
        split_mat<<<1024, 256, 0, stream>>>(hid, hidh, hidl);
        TS4 ts;
        ts.in[0] = Wq; ts.oh[0] = Wqth; ts.ol[0] = Wqtl;
        ts.in[1] = Wk; ts.oh[1] = Wkth; ts.ol[1] = Wktl;
        ts.in[2] = Wv; ts.oh[2] = Wvth; ts.ol[2] = Wvtl;
        ts.in[3] = Wg; ts.oh[3] = Wgth; ts.ol[3] = Wgtl;
        transpose_split4<<<dim3(32, 32, 4), 256, 0, stream>>>(ts);
        transpose_split<<<dim3(2, 32), 256, 0, stream>>>(Wf1, wf1th, wf1tl, 128, 2048);

        // 2. fused input projections
        GemmArgs fa;
        fa.Ah = hidh; fa.Al = hidl;
        fa.Bh[0] = Wqth; fa.Bl[0] = Wqtl; fa.C[0] = qpre;
        fa.Bh[1] = Wkth; fa.Bl[1] = Wktl; fa.C[1] = kpre;
        fa.Bh[2] = Wvth; fa.Bl[2] = Wvtl; fa.C[2] = vpre;
        fa.Bh[3] = Wgth; fa.Bl[3] = Wgtl; fa.C[3] = gpre;
        fa.Bh[4] = wf1th; fa.Bl[4] = wf1tl; fa.C[4] = g1b;
        gemm_split<<<dim3(65, 16), 256, 0, stream>>>(fa, 1);

        // 3. beta, g2, log-decay (t-tiled)
        beta_kernel<<<M, 256, 0, stream>>>(hid, Wb, betab);
        sgemm128<<<dim3(1, 16), 256, 0, stream>>>(g1b, Wf2, g2b, M, 128, 128);
        ldecay_kernel_t<<<(M * HH * NG) / 256, 256, 0, stream>>>(g2b, A_log, dt_bias, ldecb);

        // 4. conv + silu (+ l2norm)
        ConvArgs ca;
        ca.pre[0] = qpre; ca.w[0] = conv_q; ca.out[0] = qn; ca.scale[0] = SCALE_Q; ca.do_norm[0] = 1;
        ca.pre[1] = kpre; ca.w[1] = conv_k; ca.out[1] = kn; ca.scale[1] = 1.f;     ca.do_norm[1] = 1;
        ca.pre[2] = vpre; ca.w[2] = conv_v; ca.out[2] = vn; ca.scale[2] = 1.f;     ca.do_norm[2] = 0;
        conv_silu_norm3<<<dim3(M * HH, 3), 128, 0, stream>>>(ca);

        // 5. t-tile transpose (qn/kn/vn -> region C; qn/kn slots then reused by prep)
        T3 tt;
        tt.in[0] = qn; tt.out[0] = qn_t;
        tt.in[1] = kn; tt.out[1] = kn_t;
        tt.in[2] = vn; tt.out[2] = vn_t;
        transpose_tile3<<<dim3(4096, 3), 256, 0, stream>>>(tt);

        // 6. prep (parallel) + serial chunked recurrence
        prep_kernel<<<2048, 256, 0, stream>>>(kn_t, qn_t, ldecb, betab,
                                              Nh, Nl, Aqh, Aql, Kdh, Kdl, wexpg);
        chunk_recur<<<256, 256, 0, stream>>>(qn_t, kn_t, vn_t,
                                             Nh, Nl, Aqh, Aql, Kdh, Kdl, wexpg, o);

        // 7. transpose Wo (over dead qn_t)
        transpose_split<<<dim3(32, 32), 256, 0, stream>>>(Wo, Woth, Wotl, 2048, 2048);

        // 8. gated rmsnorm -> y split (over dead kn_t)
        gated_rmsnorm_split<<<M * HH, 128, 0, stream>>>(o, gpre, bg, norm_w, yh, yl);

        // 9. output projection
        GemmArgs oa;
        oa.Ah = yh; oa.Al = yl;
        for (int i = 0; i < 5; ++i) { oa.Bh[i] = Woth; oa.Bl[i] = Wotl; oa.C[i] = out; }
        gemm_split<<<dim3(16, 16), 256, 0, stream>>>(oa, 0);
    } else {
        // ---------------- fallback: fp32 path ----------------
        float* ws = (float*)d_ws;
        float* qpre = ws + 0 * N1;
        float* kpre = ws + 1 * N1;
        float* vpre = ws + 2 * N1;
        float* gpre = ws + 3 * N1;
        float* qn   = ws + 4 * N1;
        float* kn   = ws + 5 * N1;
        float* vn   = ws + 6 * N1;
        float* g1b  = ws + 7 * N1;
        float* g2b  = g1b + (size_t)BB * TT * DV;
        float* betab= g2b + (size_t)BB * TT * HH * NG;
        float* decayb = betab + (size_t)BB * TT * HH;
        float* o = qpre;
        float* y = vpre;

        sgemm128<<<dim3(16, 16), 256, 0, stream>>>(hid, Wq, qpre, M, 2048, 2048);
        sgemm128<<<dim3(16, 16), 256, 0, stream>>>(hid, Wk, kpre, M, 2048, 2048);
        sgemm128<<<dim3(16, 16), 256, 0, stream>>>(hid, Wv, vpre, M, 2048, 2048);
        sgemm128<<<dim3(16, 16), 256, 0, stream>>>(hid, Wg, gpre, M, 2048, 2048);
        sgemm128<<<dim3(1, 16), 256, 0, stream>>>(hid, Wf1, g1b, M, 128, 2048);
        sgemm128<<<dim3(1, 16), 256, 0, stream>>>(g1b, Wf2, g2b, M, 128, 128);
        beta_kernel<<<M, 256, 0, stream>>>(hid, Wb, betab);

        conv_silu_norm<<<M * HH, 128, 0, stream>>>(qpre, conv_q, qn, SCALE_Q, 1);
        conv_silu_norm<<<M * HH, 128, 0, stream>>>(kpre, conv_k, kn, 1.f, 1);
        conv_silu_norm<<<M * HH, 128, 0, stream>>>(vpre, conv_v, vn, 1.f, 0);

        decay_kernel<<<(M * HH * NG) / 256, 256, 0, stream>>>(g2b, A_log, dt_bias, decayb);

        recur_kernel<<<BB * HH * (DV / 4), 256, 0, stream>>>(qn, kn, vn, decayb, betab, o);

        gated_rmsnorm<<<M * HH, 128, 0, stream>>>(o, gpre, bg, norm_w, y);

        sgemm128<<<dim3(16, 16), 256, 0, stream>>>(y, Wo, out, M, 2048, 2048);
    }
}